// Round 2
// baseline (4006.608 us; speedup 1.0000x reference)
//
#include <hip/hip_runtime.h>
#include <hip/hip_bf16.h>

typedef __hip_bfloat16 bf16;

#define DEV __device__ __forceinline__

DEV float b2f(bf16 v){ return __bfloat162float(v); }
DEV bf16 f2b(float v){ return __float2bfloat16(v); }
DEV float blo(unsigned int u){ return __uint_as_float(u << 16); }
DEV float bhi(unsigned int u){ return __uint_as_float(u & 0xffff0000u); }
DEV float sigf(float x){ return 1.0f/(1.0f + __expf(-x)); }
DEV float tanhfast(float x){
  x = fminf(fmaxf(x, -15.0f), 15.0f);
  float e = __expf(2.0f*x);
  return (e - 1.0f)/(e + 1.0f);
}

// LayerNorm across 128 threads (block=128, 2 waves). red = shared float[4].
DEV float ln128(float s, int tid, const bf16* g, const bf16* b, float* red){
  float sum = s, sq = s*s;
  #pragma unroll
  for (int off = 32; off; off >>= 1){
    sum += __shfl_down(sum, off);
    sq  += __shfl_down(sq,  off);
  }
  if ((tid & 63) == 0){ red[(tid>>6)*2] = sum; red[(tid>>6)*2+1] = sq; }
  __syncthreads();
  float S = red[0] + red[2], Q = red[1] + red[3];
  float m  = S * (1.0f/128.0f);
  float var = fmaxf(Q * (1.0f/128.0f) - m*m, 0.0f);
  float rs = rsqrtf(var + 1e-5f);
  float y = (s - m)*rs*b2f(g[tid]) + b2f(b[tid]);
  __syncthreads();
  return y;
}

// ---------------------------------------------------------------------------
// K0a: dtype detector. Inspect low-16 exponent field of first 4096 words of x.
// bf16 data (~N(0,1)): low half is a bf16 code, exponent field < 0x90 always.
// fp32 data: low half is random mantissa bits, exponent field >= 0x90 w.p. .44
// flag[0] = 1 -> inputs are bf16; 0 -> inputs are fp32.
// ---------------------------------------------------------------------------
__global__ void k_detect(const unsigned int* __restrict__ xw, int* __restrict__ flag){
  __shared__ int found;
  if (threadIdx.x == 0) found = 0;
  __syncthreads();
  int local = 0;
  for (int i = threadIdx.x; i < 4096; i += 256){
    unsigned int u = xw[i];
    unsigned int e = (u >> 7) & 0xFF;
    if (e >= 0x90) local = 1;
  }
  if (local) atomicOr(&found, 1);
  __syncthreads();
  if (threadIdx.x == 0) flag[0] = found ? 0 : 1;
}

// ---------------------------------------------------------------------------
// K0b: canonicalize all float inputs into a bf16 region in ws.
// blockIdx.y selects the input; grid-stride within it.
// ---------------------------------------------------------------------------
struct CArgs {
  const void* src[44];
  int n[44];
  int off[44];
};

__global__ void k_canon(CArgs a, const int* __restrict__ flag, bf16* __restrict__ dst){
  int id = blockIdx.y;
  int n = a.n[id];
  const void* s = a.src[id];
  bf16* d = dst + a.off[id];
  int stride = gridDim.x * blockDim.x;
  int i0 = blockIdx.x * blockDim.x + threadIdx.x;
  if (flag[0]){
    const bf16* sb = (const bf16*)s;
    for (int i = i0; i < n; i += stride) d[i] = sb[i];
  } else {
    const float* sf = (const float*)s;
    for (int i = i0; i < n; i += stride) d[i] = f2b(sf[i]);
  }
}

// ---------------------------------------------------------------------------
// K1: input projection + LN + relu.  grid = BN*T = 153600, block = 128
// ---------------------------------------------------------------------------
__global__ void k_inproj(const bf16* __restrict__ x, const bf16* __restrict__ Wp,
                         const bf16* __restrict__ bp, const bf16* __restrict__ gp,
                         const bf16* __restrict__ bbp, bf16* __restrict__ h0){
  int row = blockIdx.x, tid = threadIdx.x;
  __shared__ float xs[26];
  __shared__ float red[4];
  if (tid < 26) xs[tid] = b2f(x[row*26 + tid]);
  __syncthreads();
  float s = b2f(bp[tid]);
  const bf16* wr = Wp + tid*26;
  #pragma unroll
  for (int f = 0; f < 26; ++f) s += xs[f]*b2f(wr[f]);
  float y = fmaxf(ln128(s, tid, gp, bbp, red), 0.0f);
  h0[row*128 + tid] = f2b(y);
}

// ---------------------------------------------------------------------------
// K2: attention per (bn, head).  grid = 1600*4, block = 256
// ---------------------------------------------------------------------------
__global__ __launch_bounds__(256) void k_attn(const bf16* __restrict__ h0,
    const bf16* __restrict__ Wqkv, const bf16* __restrict__ bqkv,
    bf16* __restrict__ attno){
  int bn = blockIdx.x >> 2;
  int hd = blockIdx.x & 3;
  int tid = threadIdx.x;
  __shared__ __align__(16) unsigned int h0s[96*64];   // 96x128 bf16 (24576 B)
  __shared__ float q [96*33];
  __shared__ float kk[96*33];
  __shared__ float vv[96*33];
  __shared__ float pl[192];
  {
    const uint4* src = (const uint4*)(h0 + bn*12288);
    uint4* dst = (uint4*)h0s;
    for (int u = tid; u < 1536; u += 256) dst[u] = src[u];
  }
  __syncthreads();
  for (int o = tid; o < 3072; o += 256){
    int i = o >> 5, c = o & 31;
    int rq = hd*32 + c;
    const unsigned int* wq = (const unsigned int*)(Wqkv + rq*128);
    const unsigned int* wk = (const unsigned int*)(Wqkv + (128 + rq)*128);
    const unsigned int* wv = (const unsigned int*)(Wqkv + (256 + rq)*128);
    const unsigned int* hr = h0s + i*64;
    float aq = b2f(bqkv[rq]);
    float ak = b2f(bqkv[128 + rq]);
    float av = b2f(bqkv[256 + rq]);
    #pragma unroll 8
    for (int kp = 0; kp < 64; ++kp){
      unsigned int hu = hr[kp];
      float x0 = blo(hu), x1 = bhi(hu);
      unsigned int u;
      u = wq[kp]; aq += x0*blo(u) + x1*bhi(u);
      u = wk[kp]; ak += x0*blo(u) + x1*bhi(u);
      u = wv[kp]; av += x0*blo(u) + x1*bhi(u);
    }
    q [i*33 + c] = aq;
    kk[i*33 + c] = ak;
    vv[i*33 + c] = av;
  }
  __syncthreads();
  float acc[32];
  #pragma unroll
  for (int d = 0; d < 32; ++d) acc[d] = 0.0f;
  float l = 0.0f;
  int i = tid >> 1, jh = tid & 1;
  float* pout = (float*)h0s;           // reuse (h0s dead after qkv)
  const float scl = 0.17677669529663687f;  // 1/sqrt(32)
  if (tid < 192){
    float qreg[32];
    const float* qi = q + i*33;
    #pragma unroll
    for (int c = 0; c < 32; ++c) qreg[c] = qi[c];
    for (int j = jh*48; j < jh*48 + 48; ++j){
      const float* kj = kk + j*33;
      float s = 0.0f;
      #pragma unroll
      for (int c = 0; c < 32; ++c) s += qreg[c]*kj[c];
      float p = __expf(s*scl);
      l += p;
      const float* vj = vv + j*33;
      #pragma unroll
      for (int d = 0; d < 32; ++d) acc[d] += p*vj[d];
    }
    pl[tid] = l;
    if (jh){
      float* po = pout + i*33;
      #pragma unroll
      for (int d = 0; d < 32; ++d) po[d] = acc[d];
    }
  }
  __syncthreads();
  if (tid < 192 && jh == 0){
    float inv = 1.0f/(pl[tid] + pl[tid+1]);
    const float* po = pout + i*33;
    bf16* orow = attno + (bn*96 + i)*128 + hd*32;
    #pragma unroll
    for (int d = 0; d < 32; ++d) orow[d] = f2b((acc[d] + po[d])*inv);
  }
}

// ---------------------------------------------------------------------------
// K3: out-proj + residual + LN.  grid = 153600/8, block = 128 (8 rows/block)
// ---------------------------------------------------------------------------
__global__ void k_oproj(const bf16* __restrict__ attno, const bf16* __restrict__ h0,
                        const bf16* __restrict__ Wo, const bf16* __restrict__ bo,
                        const bf16* __restrict__ ga, const bf16* __restrict__ ba_,
                        bf16* __restrict__ h1){
  int tid = threadIdx.x;
  __shared__ unsigned int wp[128*65];    // Wo, padded pairs (33280 B)
  __shared__ __align__(16) float asv[128];
  __shared__ float red[4];
  const unsigned int* wg = (const unsigned int*)Wo;
  for (int u = tid; u < 8192; u += 128) wp[(u>>6)*65 + (u&63)] = wg[u];
  int row0 = blockIdx.x * 8;
  float bov = b2f(bo[tid]);
  for (int r = 0; r < 8; ++r){
    int row = row0 + r;
    __syncthreads();
    asv[tid] = b2f(attno[row*128 + tid]);
    __syncthreads();
    const float2* af2 = (const float2*)asv;
    const unsigned int* w = wp + tid*65;
    float s = bov;
    #pragma unroll 8
    for (int kp = 0; kp < 64; ++kp){
      float2 a = af2[kp]; unsigned int u = w[kp];
      s += a.x*blo(u) + a.y*bhi(u);
    }
    s += b2f(h0[row*128 + tid]);
    float y = ln128(s, tid, ga, ba_, red);
    h1[row*128 + tid] = f2b(y);
  }
}

// ---------------------------------------------------------------------------
// K4: LSTM x-part GEMM.  grid = (153600/32)*4 gate-tiles, block = 256
// ---------------------------------------------------------------------------
__global__ __launch_bounds__(256) void k_xpart(const bf16* __restrict__ h1,
    const bf16* __restrict__ Wih, const bf16* __restrict__ bih,
    const bf16* __restrict__ bhh, bf16* __restrict__ xpart){
  int rt = blockIdx.x >> 2;
  int gt = blockIdx.x & 3;
  int tid = threadIdx.x;
  __shared__ __align__(16) float hs[32*128];
  __shared__ unsigned int wpd[128*65];
  const unsigned int* hg = (const unsigned int*)h1 + rt*2048;
  float2* hsF2 = (float2*)hs;
  for (int u = tid; u < 2048; u += 256){
    unsigned int xx = hg[u];
    hsF2[u] = make_float2(blo(xx), bhi(xx));
  }
  const unsigned int* wg = (const unsigned int*)Wih + gt*8192;
  for (int u = tid; u < 8192; u += 256) wpd[(u>>6)*65 + (u&63)] = wg[u];
  __syncthreads();
  int gr = tid >> 5;
  int gc = tid & 31;
  float acc[4][4];
  #pragma unroll
  for (int a = 0; a < 4; ++a)
    #pragma unroll
    for (int b = 0; b < 4; ++b) acc[a][b] = 0.0f;
  #pragma unroll 4
  for (int kp = 0; kp < 64; ++kp){
    float2 h2[4];
    #pragma unroll
    for (int a = 0; a < 4; ++a) h2[a] = hsF2[(gr*4 + a)*64 + kp];
    #pragma unroll
    for (int b = 0; b < 4; ++b){
      unsigned int u = wpd[(gc + 32*b)*65 + kp];
      float w0 = blo(u), w1 = bhi(u);
      #pragma unroll
      for (int a = 0; a < 4; ++a) acc[a][b] += h2[a].x*w0 + h2[a].y*w1;
    }
  }
  #pragma unroll
  for (int b = 0; b < 4; ++b){
    int G = gt*128 + gc + 32*b;
    float bias = b2f(bih[G]) + b2f(bhh[G]);
    #pragma unroll
    for (int a = 0; a < 4; ++a){
      int row = rt*32 + gr*4 + a;
      xpart[row*512 + G] = f2b(acc[a][b] + bias);
    }
  }
}

// ---------------------------------------------------------------------------
// K5: forward LSTM recurrence. grid = 200 (8 bn-rows/block), block = 256.
// ---------------------------------------------------------------------------
__global__ __launch_bounds__(256) void k_lstm(const bf16* __restrict__ Whh,
    const bf16* __restrict__ xpart, float* __restrict__ y_f){
  int bn0 = blockIdx.x * 8;
  int tid = threadIdx.x;
  __shared__ __align__(16) float hsb[8*128];
  __shared__ __align__(16) float csb[8*128];
  __shared__ __align__(16) float gb[8*512];
  unsigned int wA[64], wB[64];
  const unsigned int* W = (const unsigned int*)Whh;
  #pragma unroll
  for (int j = 0; j < 64; ++j){
    wA[j] = W[tid*128 + j];
    wB[j] = W[tid*128 + 64 + j];
  }
  for (int idx = tid; idx < 1024; idx += 256){ hsb[idx] = 0.0f; csb[idx] = 0.0f; }
  __syncthreads();
  const float2* hsF2 = (const float2*)hsb;
  for (int t = 0; t < 96; ++t){
    float xg[4][4];
    #pragma unroll
    for (int i = 0; i < 4; ++i){
      int idx = i*256 + tid;
      int r = idx >> 7, d = idx & 127;
      const bf16* xp = xpart + ((bn0 + r)*96 + t)*512 + d;
      xg[i][0] = b2f(xp[0]);
      xg[i][1] = b2f(xp[128]);
      xg[i][2] = b2f(xp[256]);
      xg[i][3] = b2f(xp[384]);
    }
    float a0[8], a1[8];
    #pragma unroll
    for (int r = 0; r < 8; ++r){ a0[r] = 0.0f; a1[r] = 0.0f; }
    #pragma unroll
    for (int kp = 0; kp < 64; ++kp){
      float wa0 = blo(wA[kp]), wa1 = bhi(wA[kp]);
      float wb0 = blo(wB[kp]), wb1 = bhi(wB[kp]);
      #pragma unroll
      for (int r = 0; r < 8; ++r){
        float2 h2 = hsF2[r*64 + kp];
        a0[r] += h2.x*wa0 + h2.y*wa1;
        a1[r] += h2.x*wb0 + h2.y*wb1;
      }
    }
    #pragma unroll
    for (int r = 0; r < 8; ++r)
      ((float2*)(gb + r*512))[tid] = make_float2(a0[r], a1[r]);
    __syncthreads();
    #pragma unroll
    for (int i = 0; i < 4; ++i){
      int idx = i*256 + tid;
      int r = idx >> 7, d = idx & 127;
      float ii = gb[r*512 + d]       + xg[i][0];
      float ff = gb[r*512 + 128 + d] + xg[i][1];
      float gg = gb[r*512 + 256 + d] + xg[i][2];
      float oo = gb[r*512 + 384 + d] + xg[i][3];
      float c  = sigf(ff)*csb[r*128 + d] + sigf(ii)*tanhfast(gg);
      float hn = sigf(oo)*tanhfast(c);
      csb[r*128 + d] = c;
      hsb[r*128 + d] = hn;
    }
    __syncthreads();
  }
  #pragma unroll
  for (int i = 0; i < 4; ++i){
    int idx = i*256 + tid;
    int r = idx >> 7, d = idx & 127;
    y_f[(bn0 + r)*128 + d] = hsb[r*128 + d];
  }
}

// ---------------------------------------------------------------------------
// K6: backward LSTM (single step at t=T-1, zero state) + temporal proj Wtp.
// ---------------------------------------------------------------------------
__global__ void k_bwdtp(const bf16* __restrict__ h1, const bf16* __restrict__ Wihb,
                        const bf16* __restrict__ bihb, const bf16* __restrict__ bhhb,
                        const float* __restrict__ y_f, const bf16* __restrict__ Wtp,
                        const bf16* __restrict__ btp, float* __restrict__ ht,
                        const int* __restrict__ flag, bf16* __restrict__ outb,
                        float* __restrict__ outf){
  int bn = blockIdx.x, tid = threadIdx.x;
  __shared__ __align__(16) float xr[128];
  __shared__ float gates[512];
  __shared__ __align__(16) float ycat[256];
  xr[tid] = b2f(h1[(bn*96 + 95)*128 + tid]);
  __syncthreads();
  const float2* xf2 = (const float2*)xr;
  for (int g = tid; g < 512; g += 128){
    const unsigned int* w = (const unsigned int*)(Wihb + g*128);
    float s = b2f(bihb[g]) + b2f(bhhb[g]);
    #pragma unroll 8
    for (int kp = 0; kp < 64; ++kp){
      float2 a = xf2[kp]; unsigned int u = w[kp];
      s += a.x*blo(u) + a.y*bhi(u);
    }
    gates[g] = s;
  }
  __syncthreads();
  float ii = gates[tid], gg = gates[256 + tid], oo = gates[384 + tid];
  float c  = sigf(ii)*tanhfast(gg);
  float yb = sigf(oo)*tanhfast(c);
  ycat[tid]       = y_f[bn*128 + tid];
  ycat[128 + tid] = yb;
  __syncthreads();
  const float2* yf2 = (const float2*)ycat;
  const unsigned int* w = (const unsigned int*)(Wtp + tid*256);
  float s = b2f(btp[tid]);
  #pragma unroll 8
  for (int kp = 0; kp < 128; ++kp){
    float2 a = yf2[kp]; unsigned int u = w[kp];
    s += a.x*blo(u) + a.y*bhi(u);
  }
  ht[bn*128 + tid] = s;
  int oi = 206400 + bn*128 + tid;
  if (flag[0]) outb[oi] = f2b(s); else outf[oi] = s;
}

// ---------------------------------------------------------------------------
// K7: npj = h_temporal @ Wn.T + bn
// ---------------------------------------------------------------------------
__global__ void k_npj(const float* __restrict__ ht, const bf16* __restrict__ Wn,
                      const bf16* __restrict__ bn_, float* __restrict__ npj){
  int bn = blockIdx.x, tid = threadIdx.x;
  __shared__ __align__(16) float row[128];
  row[tid] = ht[bn*128 + tid];
  __syncthreads();
  const float2* rf2 = (const float2*)row;
  const unsigned int* w = (const unsigned int*)(Wn + tid*128);
  float s = b2f(bn_[tid]);
  #pragma unroll 8
  for (int kp = 0; kp < 64; ++kp){
    float2 a = rf2[kp]; unsigned int u = w[kp];
    s += a.x*blo(u) + a.y*bhi(u);
  }
  npj[bn*128 + tid] = s;
}

// ---------------------------------------------------------------------------
// K8: hyperedge features + attention logits.  grid = B*E = 256, block = 128
// ---------------------------------------------------------------------------
__global__ void k_edge(const float* __restrict__ npj, const bf16* __restrict__ Hinc,
                       const bf16* __restrict__ We, const bf16* __restrict__ be,
                       const bf16* __restrict__ Wa, const bf16* __restrict__ ba,
                       float* __restrict__ ee, float* __restrict__ scE){
  int b = blockIdx.x >> 4, e = blockIdx.x & 15, tid = threadIdx.x;
  float acc = 0.0f, deg = 0.0f;
  for (int n = 0; n < 100; ++n){
    float w = b2f(Hinc[n*16 + e]);
    deg += w;
    acc += w * npj[(b*100 + n)*128 + tid];
  }
  __shared__ __align__(16) float eep[128];
  eep[tid] = acc/(deg + 1e-8f);
  __syncthreads();
  const float2* ef2 = (const float2*)eep;
  const unsigned int* w = (const unsigned int*)(We + tid*128);
  float s = b2f(be[tid]);
  #pragma unroll 8
  for (int kp = 0; kp < 64; ++kp){
    float2 a = ef2[kp]; unsigned int u = w[kp];
    s += a.x*blo(u) + a.y*bhi(u);
  }
  ee[(b*16 + e)*128 + tid] = s;
  float p = s * b2f(Wa[tid]);
  #pragma unroll
  for (int off = 32; off; off >>= 1) p += __shfl_down(p, off);
  __shared__ float r2[2];
  if ((tid & 63) == 0) r2[tid>>6] = p;
  __syncthreads();
  if (tid == 0) scE[b*16 + e] = r2[0] + r2[1] + b2f(ba[0]);
}

// ---------------------------------------------------------------------------
// K9: per-node segment softmax over edges + aggregate + residual + LN
// ---------------------------------------------------------------------------
__global__ void k_node(const float* __restrict__ ht, const float* __restrict__ ee,
                       const float* __restrict__ scE, const bf16* __restrict__ Hinc,
                       const bf16* __restrict__ gg_, const bf16* __restrict__ bg_,
                       float* __restrict__ hb2){
  int blk = blockIdx.x; int b = blk/100, n = blk%100; int tid = threadIdx.x;
  __shared__ float wts[16];
  __shared__ float red[4];
  if (tid == 0){
    float sc[16]; float mx = -1e30f;
    for (int e = 0; e < 16; ++e){
      float m_ = b2f(Hinc[n*16 + e]);
      sc[e] = (m_ > 0.0f) ? scE[b*16 + e] : -1e30f;
      mx = fmaxf(mx, sc[e]);
    }
    float tmp[16]; float sum = 0.0f;
    for (int e = 0; e < 16; ++e){
      tmp[e] = (sc[e] > -1e29f) ? __expf(sc[e] - mx) : 0.0f;
      sum += tmp[e];
    }
    float inv = (sum > 0.0f) ? 1.0f/sum : 0.0f;
    for (int e = 0; e < 16; ++e) wts[e] = tmp[e]*inv;
  }
  __syncthreads();
  float s = ht[(b*100 + n)*128 + tid];
  for (int e = 0; e < 16; ++e) s += wts[e] * ee[(b*16 + e)*128 + tid];
  float y = ln128(s, tid, gg_, bg_, red);
  hb2[(b*100 + n)*128 + tid] = y;
}

// ---------------------------------------------------------------------------
// K10: GCN pass + region embedding; writes h_spatial
// ---------------------------------------------------------------------------
__global__ void k_gcn(const float* __restrict__ hb2, const bf16* __restrict__ An,
                      const bf16* __restrict__ Wg, const bf16* __restrict__ bg_,
                      const bf16* __restrict__ Remb, const int* __restrict__ mem,
                      float* __restrict__ hsp, const int* __restrict__ flag,
                      bf16* __restrict__ outb, float* __restrict__ outf){
  int blk = blockIdx.x; int b = blk/100, n = blk%100; int tid = threadIdx.x;
  float acc = 0.0f;
  for (int m = 0; m < 100; ++m){
    float a = b2f(An[n*100 + m]);
    acc += a * hb2[(b*100 + m)*128 + tid];
  }
  __shared__ __align__(16) float as_[128];
  as_[tid] = acc;
  __syncthreads();
  const float2* af2 = (const float2*)as_;
  const unsigned int* w = (const unsigned int*)(Wg + tid*128);
  float s = b2f(bg_[tid]);
  #pragma unroll 8
  for (int kp = 0; kp < 64; ++kp){
    float2 a = af2[kp]; unsigned int u = w[kp];
    s += a.x*blo(u) + a.y*bhi(u);
  }
  s = fmaxf(s, 0.0f);
  float out = hb2[(b*100 + n)*128 + tid] + s + b2f(Remb[mem[n]*128 + tid]);
  hsp[(b*100 + n)*128 + tid] = out;
  int oi = 1600 + (b*100 + n)*128 + tid;
  if (flag[0]) outb[oi] = f2b(out); else outf[oi] = out;
}

// ---------------------------------------------------------------------------
// K11: fusion + LN + relu + MLP head -> pred.  grid = 1600, block = 128
// ---------------------------------------------------------------------------
__global__ void k_fuse(const float* __restrict__ ht, const float* __restrict__ hsp,
                       const bf16* __restrict__ Wf, const bf16* __restrict__ bf_,
                       const bf16* __restrict__ gf, const bf16* __restrict__ b_f,
                       const bf16* __restrict__ W1, const bf16* __restrict__ b1,
                       const bf16* __restrict__ W2, const bf16* __restrict__ b2,
                       const int* __restrict__ flag, bf16* __restrict__ outb,
                       float* __restrict__ outf){
  int bn = blockIdx.x, tid = threadIdx.x;
  __shared__ __align__(16) float cat[256];
  __shared__ __align__(16) float hf[128];
  __shared__ float red[4];
  cat[tid]       = ht[bn*128 + tid];
  cat[128 + tid] = hsp[bn*128 + tid];
  __syncthreads();
  const float2* cf2 = (const float2*)cat;
  const unsigned int* w = (const unsigned int*)(Wf + tid*256);
  float s = b2f(bf_[tid]);
  #pragma unroll 8
  for (int kp = 0; kp < 128; ++kp){
    float2 a = cf2[kp]; unsigned int u = w[kp];
    s += a.x*blo(u) + a.y*bhi(u);
  }
  float y = fmaxf(ln128(s, tid, gf, b_f, red), 0.0f);
  hf[tid] = y;
  __syncthreads();
  if (tid < 64){
    const float2* hf2 = (const float2*)hf;
    const unsigned int* w1 = (const unsigned int*)(W1 + tid*128);
    float z = b2f(b1[tid]);
    #pragma unroll 8
    for (int kp = 0; kp < 64; ++kp){
      float2 a = hf2[kp]; unsigned int u = w1[kp];
      z += a.x*blo(u) + a.y*bhi(u);
    }
    z = fmaxf(z, 0.0f);
    float p = z * b2f(W2[tid]);
    #pragma unroll
    for (int off = 32; off; off >>= 1) p += __shfl_down(p, off);
    if (tid == 0){
      float pr = p + b2f(b2[0]);
      if (flag[0]) outb[bn] = f2b(pr); else outf[bn] = pr;
    }
  }
}

// ---------------------------------------------------------------------------

extern "C" void kernel_launch(void* const* d_in, const int* in_sizes, int n_in,
                              void* d_out, int out_size, void* d_ws, size_t ws_size,
                              hipStream_t stream){
  (void)n_in; (void)out_size; (void)ws_size;
  const int* mem = (const int*)d_in[3];

  // ---- canonical bf16 region layout (element offsets, 8-elem aligned) ----
  CArgs ca;
  int coff[43];
  int nf = 0;
  long long off = 0;
  for (int i = 0; i < 43; ++i){
    if (i == 3){ coff[i] = -1; continue; }
    coff[i] = (int)off;
    ca.src[nf] = d_in[i];
    ca.n[nf]   = in_sizes[i];
    ca.off[nf] = (int)off;
    ++nf;
    off += (long long)((in_sizes[i] + 7) & ~7);
  }
  char* ws = (char*)d_ws;
  bf16* canon = (bf16*)ws;
  long long canonBytes = ((off*2 + 255)/256)*256;
  int* flag = (int*)(ws + canonBytes);
  long long base = canonBytes + 256;

  // canonical input pointers
  #define C(i) (canon + coff[i])
  const bf16* A_norm = C(1);
  const bf16* Hinc   = C(2);
  const bf16* Wp  = C(4);  const bf16* bp  = C(5);
  const bf16* g_p = C(6);  const bf16* b_p = C(7);
  const bf16* Wqkv= C(8);  const bf16* bqkv= C(9);
  const bf16* Wo  = C(10); const bf16* bo  = C(11);
  const bf16* g_a = C(12); const bf16* b_a = C(13);
  const bf16* Wih_f = C(14); const bf16* Whh_f = C(15);
  const bf16* bih_f = C(16); const bf16* bhh_f = C(17);
  const bf16* Wih_b = C(18);
  const bf16* bih_b = C(20); const bf16* bhh_b = C(21);
  const bf16* Wtp = C(22); const bf16* btp = C(23);
  const bf16* Wn  = C(24); const bf16* bn_ = C(25);
  const bf16* We  = C(26); const bf16* be  = C(27);
  const bf16* Wa  = C(28); const bf16* ba  = C(29);
  const bf16* g_g = C(30); const bf16* b_g = C(31);
  const bf16* Remb= C(32);
  const bf16* Wg  = C(33); const bf16* bg  = C(34);
  const bf16* Wf  = C(35); const bf16* bff = C(36);
  const bf16* g_f = C(37); const bf16* b_f = C(38);
  const bf16* W1  = C(39); const bf16* b1  = C(40);
  const bf16* W2  = C(41); const bf16* b2  = C(42);
  const bf16* xc  = C(0);
  #undef C

  bf16*  outb = (bf16*)d_out;
  float* outf = (float*)d_out;
  // pipeline scratch (all offsets multiples of 256)
  bf16*  h1    = (bf16*)(ws + base);
  bf16*  h0    = (bf16*)(ws + base + 39321600LL);
  bf16*  attno = (bf16*)(ws + base + 78643200LL);
  bf16*  xpart = (bf16*)(ws + base + 39321600LL);   // overlaps h0+attno (phase 2)
  float* y_f   = (float*)(ws + base + 196608000LL);
  float* htb   = (float*)(ws + base + 197427200LL);
  float* npj   = (float*)(ws + base + 198246400LL);
  float* ee    = (float*)(ws + base + 199065600LL);
  float* scE   = (float*)(ws + base + 199196672LL);
  float* hb2   = (float*)(ws + base + 199197696LL);
  float* hsp   = (float*)(ws + base + 200016896LL);

  k_detect<<<1, 256, 0, stream>>>((const unsigned int*)d_in[0], flag);
  k_canon <<<dim3(64, nf), 256, 0, stream>>>(ca, flag, canon);
  k_inproj<<<153600, 128, 0, stream>>>(xc, Wp, bp, g_p, b_p, h0);
  k_attn  <<<6400,   256, 0, stream>>>(h0, Wqkv, bqkv, attno);
  k_oproj <<<19200,  128, 0, stream>>>(attno, h0, Wo, bo, g_a, b_a, h1);
  k_xpart <<<19200,  256, 0, stream>>>(h1, Wih_f, bih_f, bhh_f, xpart);
  k_lstm  <<<200,    256, 0, stream>>>(Whh_f, xpart, y_f);
  k_bwdtp <<<1600,   128, 0, stream>>>(h1, Wih_b, bih_b, bhh_b, y_f, Wtp, btp, htb,
                                       flag, outb, outf);
  k_npj   <<<1600,   128, 0, stream>>>(htb, Wn, bn_, npj);
  k_edge  <<<256,    128, 0, stream>>>(npj, Hinc, We, be, Wa, ba, ee, scE);
  k_node  <<<1600,   128, 0, stream>>>(htb, ee, scE, Hinc, g_g, b_g, hb2);
  k_gcn   <<<1600,   128, 0, stream>>>(hb2, A_norm, Wg, bg, Remb, mem, hsp,
                                       flag, outb, outf);
  k_fuse  <<<1600,   128, 0, stream>>>(htb, hsp, Wf, bff, g_f, b_f, W1, b1, W2, b2,
                                       flag, outb, outf);
}

// Round 4
// 1808.694 us; speedup vs baseline: 2.2152x; 2.2152x over previous
//
#include <hip/hip_runtime.h>
#include <hip/hip_bf16.h>

typedef __hip_bfloat16 bf16;
typedef __attribute__((ext_vector_type(8))) short bf8v;   // 8 bf16 (4 VGPRs)
typedef __attribute__((ext_vector_type(4))) short s4v;
typedef __attribute__((ext_vector_type(4))) float f4v;

#define DEV __device__ __forceinline__

DEV float b2f(bf16 v){ return __bfloat162float(v); }
DEV bf16 f2b(float v){ return __float2bfloat16(v); }
DEV short f2bs(float v){ bf16 t = __float2bfloat16(v); return *reinterpret_cast<short*>(&t); }
DEV float blo(unsigned int u){ return __uint_as_float(u << 16); }
DEV float bhi(unsigned int u){ return __uint_as_float(u & 0xffff0000u); }
DEV float sigf(float x){ return 1.0f/(1.0f + __expf(-x)); }
DEV float tanhfast(float x){
  x = fminf(fmaxf(x, -15.0f), 15.0f);
  float e = __expf(2.0f*x);
  return (e - 1.0f)/(e + 1.0f);
}

DEV f4v mfma16(bf8v a, bf8v b, f4v c){
  return __builtin_amdgcn_mfma_f32_16x16x32_bf16(a, b, c, 0, 0, 0);
}

// LayerNorm across 128 threads (block=128, 2 waves). red = shared float[4].
DEV float ln128(float s, int tid, const bf16* g, const bf16* b, float* red){
  float sum = s, sq = s*s;
  #pragma unroll
  for (int off = 32; off; off >>= 1){
    sum += __shfl_down(sum, off);
    sq  += __shfl_down(sq,  off);
  }
  if ((tid & 63) == 0){ red[(tid>>6)*2] = sum; red[(tid>>6)*2+1] = sq; }
  __syncthreads();
  float S = red[0] + red[2], Q = red[1] + red[3];
  float m  = S * (1.0f/128.0f);
  float var = fmaxf(Q * (1.0f/128.0f) - m*m, 0.0f);
  float rs = rsqrtf(var + 1e-5f);
  float y = (s - m)*rs*b2f(g[tid]) + b2f(b[tid]);
  __syncthreads();
  return y;
}

// ---------------------------------------------------------------------------
// K0a: dtype detector (fp32 vs bf16 inputs). flag[0]=1 -> bf16, 0 -> fp32.
// ---------------------------------------------------------------------------
__global__ void k_detect(const unsigned int* __restrict__ xw, int* __restrict__ flag){
  __shared__ int found;
  if (threadIdx.x == 0) found = 0;
  __syncthreads();
  int local = 0;
  for (int i = threadIdx.x; i < 4096; i += 256){
    unsigned int u = xw[i];
    unsigned int e = (u >> 7) & 0xFF;
    if (e >= 0x90) local = 1;
  }
  if (local) atomicOr(&found, 1);
  __syncthreads();
  if (threadIdx.x == 0) flag[0] = found ? 0 : 1;
}

// ---------------------------------------------------------------------------
// K0b: canonicalize all float inputs into a bf16 region in ws.
// ---------------------------------------------------------------------------
struct CArgs {
  const void* src[44];
  int n[44];
  int off[44];
};

__global__ void k_canon(CArgs a, const int* __restrict__ flag, bf16* __restrict__ dst){
  int id = blockIdx.y;
  int n = a.n[id];
  const void* s = a.src[id];
  bf16* d = dst + a.off[id];
  int stride = gridDim.x * blockDim.x;
  int i0 = blockIdx.x * blockDim.x + threadIdx.x;
  if (flag[0]){
    const bf16* sb = (const bf16*)s;
    for (int i = i0; i < n; i += stride) d[i] = sb[i];
  } else {
    const float* sf = (const float*)s;
    for (int i = i0; i < n; i += stride) d[i] = f2b(sf[i]);
  }
}

// ---------------------------------------------------------------------------
// K1: input projection + LN + relu.  grid = BN*T = 153600, block = 128
// ---------------------------------------------------------------------------
__global__ void k_inproj(const bf16* __restrict__ x, const bf16* __restrict__ Wp,
                         const bf16* __restrict__ bp, const bf16* __restrict__ gp,
                         const bf16* __restrict__ bbp, bf16* __restrict__ h0){
  int row = blockIdx.x, tid = threadIdx.x;
  __shared__ float xs[26];
  __shared__ float red[4];
  if (tid < 26) xs[tid] = b2f(x[row*26 + tid]);
  __syncthreads();
  float s = b2f(bp[tid]);
  const bf16* wr = Wp + tid*26;
  #pragma unroll
  for (int f = 0; f < 26; ++f) s += xs[f]*b2f(wr[f]);
  float y = fmaxf(ln128(s, tid, gp, bbp, red), 0.0f);
  h0[row*128 + tid] = f2b(y);
}

// ---------------------------------------------------------------------------
// K2: attention, MFMA flash-style. grid = 1600 (one block per bn), block=256.
// Wave w handles head w. LDS strides padded for 2-way-max bank aliasing.
// ---------------------------------------------------------------------------
__global__ __launch_bounds__(256,1) void k_attn(const bf16* __restrict__ h0,
    const bf16* __restrict__ Wqkv, const bf16* __restrict__ bqkv,
    bf16* __restrict__ attno){
  int bn = blockIdx.x;
  int tid = threadIdx.x;
  int w = tid >> 6;            // wave = head
  int lane = tid & 63;
  int l15 = lane & 15, quad = lane >> 4;

  __shared__ __align__(16) short h0s[96*136];    // 26112 B; reused as P panels
  __shared__ __align__(16) short q_sh[4][96*40]; // per-head Q (scaled), 7680 B each
  __shared__ __align__(16) short k_sh[4][96*40];
  __shared__ __align__(16) short v_sh[4][32*104];// per-head V^T (32 rows x 96 k)

  // stage h0 tile (96x128 bf16) into padded LDS (stride 136 = 17 uint4)
  {
    const uint4* src = (const uint4*)(h0 + bn*12288);
    uint4* dst = (uint4*)h0s;
    for (int u = tid; u < 1536; u += 256){
      int r = u >> 4, c = u & 15;
      dst[r*17 + c] = src[u];
    }
  }
  __syncthreads();

  short* qp = q_sh[w];
  short* kp = k_sh[w];
  short* vp = v_sh[w];
  const float scl = 0.17677669529663687f;  // 1/sqrt(32), folded into Q

  // Phase 1: q,k,v for this head via MFMA.  M=96, N=32, K=128.
  #pragma unroll
  for (int pan = 0; pan < 3; ++pan){
    for (int n0 = 0; n0 < 32; n0 += 16){
      int rq = pan*128 + w*32 + n0 + l15;
      bf8v b[4];
      #pragma unroll
      for (int ksi = 0; ksi < 4; ++ksi)
        b[ksi] = *reinterpret_cast<const bf8v*>(Wqkv + rq*128 + ksi*32 + quad*8);
      float bias = b2f(bqkv[rq]);
      for (int m = 0; m < 6; ++m){
        f4v acc = {0.f,0.f,0.f,0.f};
        #pragma unroll
        for (int ksi = 0; ksi < 4; ++ksi){
          bf8v a = *reinterpret_cast<const bf8v*>(h0s + (m*16 + l15)*136 + ksi*32 + quad*8);
          acc = mfma16(a, b[ksi], acc);
        }
        if (pan == 0){
          #pragma unroll
          for (int r = 0; r < 4; ++r)
            qp[(m*16 + quad*4 + r)*40 + n0 + l15] = f2bs((acc[r] + bias)*scl);
        } else if (pan == 1){
          #pragma unroll
          for (int r = 0; r < 4; ++r)
            kp[(m*16 + quad*4 + r)*40 + n0 + l15] = f2bs(acc[r] + bias);
        } else {
          s4v vs;
          #pragma unroll
          for (int r = 0; r < 4; ++r) vs[r] = f2bs(acc[r] + bias);
          *reinterpret_cast<s4v*>(vp + (n0 + l15)*104 + m*16 + quad*4) = vs;
        }
      }
    }
  }
  __syncthreads();   // h0s now dead -> reuse as per-wave P panels

  short* pp = h0s + w*1664;   // 16 x 104 bf16 P panel per wave

  // Phase 2: per m-tile: S = Q K^T (6 MFMA), softmax, P V (6 MFMA)
  for (int m = 0; m < 6; ++m){
    bf8v aq = *reinterpret_cast<const bf8v*>(qp + (m*16 + l15)*40 + quad*8);
    f4v s[6];
    #pragma unroll
    for (int n = 0; n < 6; ++n){
      bf8v bk = *reinterpret_cast<const bf8v*>(kp + (n*16 + l15)*40 + quad*8);
      f4v z = {0.f,0.f,0.f,0.f};
      s[n] = mfma16(aq, bk, z);
    }
    // row max + exp + row sum (rows quad*4+r, cols spread over 16 lanes)
    float mr[4], sr[4];
    #pragma unroll
    for (int r = 0; r < 4; ++r){
      float m0 = fmaxf(fmaxf(s[0][r], s[1][r]), fmaxf(s[2][r], s[3][r]));
      mr[r] = fmaxf(m0, fmaxf(s[4][r], s[5][r]));
    }
    #pragma unroll
    for (int mask = 1; mask < 16; mask <<= 1)
      #pragma unroll
      for (int r = 0; r < 4; ++r) mr[r] = fmaxf(mr[r], __shfl_xor(mr[r], mask));
    #pragma unroll
    for (int r = 0; r < 4; ++r) sr[r] = 0.0f;
    #pragma unroll
    for (int n = 0; n < 6; ++n)
      #pragma unroll
      for (int r = 0; r < 4; ++r){
        float p = __expf(s[n][r] - mr[r]);
        s[n][r] = p;
        sr[r] += p;
      }
    #pragma unroll
    for (int mask = 1; mask < 16; mask <<= 1)
      #pragma unroll
      for (int r = 0; r < 4; ++r) sr[r] += __shfl_xor(sr[r], mask);
    // write P (bf16) to this wave's panel
    #pragma unroll
    for (int n = 0; n < 6; ++n)
      #pragma unroll
      for (int r = 0; r < 4; ++r)
        pp[(quad*4 + r)*104 + n*16 + l15] = f2bs(s[n][r]);
    asm volatile("s_waitcnt lgkmcnt(0)" ::: "memory");
    // O = P V  (K=96 -> 3 k-steps; 2 n-tiles of 16)
    f4v o0 = {0.f,0.f,0.f,0.f}, o1 = {0.f,0.f,0.f,0.f};
    #pragma unroll
    for (int ksi = 0; ksi < 3; ++ksi){
      bf8v ap  = *reinterpret_cast<const bf8v*>(pp + l15*104 + ksi*32 + quad*8);
      bf8v bv0 = *reinterpret_cast<const bf8v*>(vp + l15*104 + ksi*32 + quad*8);
      bf8v bv1 = *reinterpret_cast<const bf8v*>(vp + (16 + l15)*104 + ksi*32 + quad*8);
      o0 = mfma16(ap, bv0, o0);
      o1 = mfma16(ap, bv1, o1);
    }
    #pragma unroll
    for (int r = 0; r < 4; ++r){
      float inv = 1.0f/sr[r];
      int row = bn*96 + m*16 + quad*4 + r;
      attno[row*128 + w*32 + l15]      = f2b(o0[r]*inv);
      attno[row*128 + w*32 + 16 + l15] = f2b(o1[r]*inv);
    }
  }
}

// ---------------------------------------------------------------------------
// K3: out-proj + residual + LN, MFMA. grid = 1200 (128 rows each), block=256.
// Wave w: rows w*32..w*32+31, all 128 cols, K=128.
// ---------------------------------------------------------------------------
__global__ __launch_bounds__(256,1) void k_oproj(const bf16* __restrict__ attno,
    const bf16* __restrict__ h0, const bf16* __restrict__ Wo,
    const bf16* __restrict__ bo, const bf16* __restrict__ ga,
    const bf16* __restrict__ ba_, bf16* __restrict__ h1){
  int rt = blockIdx.x;
  int tid = threadIdx.x;
  int w = tid >> 6, lane = tid & 63;
  int l15 = lane & 15, quad = lane >> 4;
  __shared__ __align__(16) short atile[128*136];
  {
    const uint4* src = (const uint4*)(attno + rt*16384);
    uint4* dst = (uint4*)atile;
    for (int u = tid; u < 2048; u += 256){
      int r = u >> 4, c = u & 15;
      dst[r*17 + c] = src[u];
    }
  }
  __syncthreads();
  int m0 = w*32;
  bf8v a[2][4];
  #pragma unroll
  for (int m = 0; m < 2; ++m)
    #pragma unroll
    for (int ksi = 0; ksi < 4; ++ksi)
      a[m][ksi] = *reinterpret_cast<const bf8v*>(atile + (m0 + m*16 + l15)*136 + ksi*32 + quad*8);
  f4v acc[2][8];
  #pragma unroll
  for (int m = 0; m < 2; ++m)
    #pragma unroll
    for (int n = 0; n < 8; ++n) acc[m][n] = (f4v){0.f,0.f,0.f,0.f};
  for (int n = 0; n < 8; ++n){
    int G = n*16 + l15;
    bf8v b[4];
    #pragma unroll
    for (int ksi = 0; ksi < 4; ++ksi)
      b[ksi] = *reinterpret_cast<const bf8v*>(Wo + G*128 + ksi*32 + quad*8);
    #pragma unroll
    for (int m = 0; m < 2; ++m)
      #pragma unroll
      for (int ksi = 0; ksi < 4; ++ksi)
        acc[m][n] = mfma16(a[m][ksi], b[ksi], acc[m][n]);
  }
  // epilogue: bias + residual + LN per row, write h1
  #pragma unroll
  for (int m = 0; m < 2; ++m){
    int rowbase = rt*128 + m0 + m*16;
    #pragma unroll
    for (int n = 0; n < 8; ++n){
      int col = n*16 + l15;
      float bia = b2f(bo[col]);
      #pragma unroll
      for (int r = 0; r < 4; ++r)
        acc[m][n][r] += bia + b2f(h0[(rowbase + quad*4 + r)*128 + col]);
    }
    float sm[4], sq[4];
    #pragma unroll
    for (int r = 0; r < 4; ++r){ sm[r] = 0.f; sq[r] = 0.f; }
    #pragma unroll
    for (int n = 0; n < 8; ++n)
      #pragma unroll
      for (int r = 0; r < 4; ++r){
        float v = acc[m][n][r];
        sm[r] += v; sq[r] += v*v;
      }
    #pragma unroll
    for (int mask = 1; mask < 16; mask <<= 1)
      #pragma unroll
      for (int r = 0; r < 4; ++r){
        sm[r] += __shfl_xor(sm[r], mask);
        sq[r] += __shfl_xor(sq[r], mask);
      }
    float mean[4], rs[4];
    #pragma unroll
    for (int r = 0; r < 4; ++r){
      mean[r] = sm[r]*(1.0f/128.0f);
      float var = fmaxf(sq[r]*(1.0f/128.0f) - mean[r]*mean[r], 0.0f);
      rs[r] = rsqrtf(var + 1e-5f);
    }
    #pragma unroll
    for (int n = 0; n < 8; ++n){
      int col = n*16 + l15;
      float gv = b2f(ga[col]), bv = b2f(ba_[col]);
      #pragma unroll
      for (int r = 0; r < 4; ++r){
        float y = (acc[m][n][r] - mean[r])*rs[r]*gv + bv;
        h1[(rowbase + quad*4 + r)*128 + col] = f2b(y);
      }
    }
  }
}

// ---------------------------------------------------------------------------
// K4: LSTM x-part GEMM, MFMA. grid = 1200*4 (128 rows x 128 gates), block=256.
// ---------------------------------------------------------------------------
__global__ __launch_bounds__(256,1) void k_xpart(const bf16* __restrict__ h1,
    const bf16* __restrict__ Wih, const bf16* __restrict__ bih,
    const bf16* __restrict__ bhh, bf16* __restrict__ xpart){
  int rt = blockIdx.x >> 2;
  int gt = blockIdx.x & 3;
  int tid = threadIdx.x;
  int w = tid >> 6, lane = tid & 63;
  int l15 = lane & 15, quad = lane >> 4;
  __shared__ __align__(16) short htile[128*136];
  {
    const uint4* src = (const uint4*)(h1 + rt*16384);
    uint4* dst = (uint4*)htile;
    for (int u = tid; u < 2048; u += 256){
      int r = u >> 4, c = u & 15;
      dst[r*17 + c] = src[u];
    }
  }
  __syncthreads();
  int m0 = w*32;
  bf8v a[2][4];
  #pragma unroll
  for (int m = 0; m < 2; ++m)
    #pragma unroll
    for (int ksi = 0; ksi < 4; ++ksi)
      a[m][ksi] = *reinterpret_cast<const bf8v*>(htile + (m0 + m*16 + l15)*136 + ksi*32 + quad*8);
  for (int n = 0; n < 8; ++n){
    int G = gt*128 + n*16 + l15;
    bf8v b[4];
    #pragma unroll
    for (int ksi = 0; ksi < 4; ++ksi)
      b[ksi] = *reinterpret_cast<const bf8v*>(Wih + G*128 + ksi*32 + quad*8);
    float bias = b2f(bih[G]) + b2f(bhh[G]);
    #pragma unroll
    for (int m = 0; m < 2; ++m){
      f4v acc = {0.f,0.f,0.f,0.f};
      #pragma unroll
      for (int ksi = 0; ksi < 4; ++ksi)
        acc = mfma16(a[m][ksi], b[ksi], acc);
      #pragma unroll
      for (int r = 0; r < 4; ++r)
        xpart[(rt*128 + m0 + m*16 + quad*4 + r)*512 + G] = f2b(acc[r] + bias);
    }
  }
}

// ---------------------------------------------------------------------------
// K5: forward LSTM recurrence. grid = 800 (2 bn-rows/block), block = 256.
// Whh rows (2 per thread) cached in registers for all 96 steps.
// ---------------------------------------------------------------------------
__global__ __launch_bounds__(256) void k_lstm(const bf16* __restrict__ Whh,
    const bf16* __restrict__ xpart, float* __restrict__ y_f){
  int bn0 = blockIdx.x * 2;
  int tid = threadIdx.x;
  __shared__ __align__(16) float hsb[2*128];
  __shared__ __align__(16) float csb[2*128];
  __shared__ __align__(16) float gb[2*512];
  unsigned int wA[64], wB[64];   // gate rows 2*tid, 2*tid+1 (bf16 pairs)
  const unsigned int* W = (const unsigned int*)Whh;
  #pragma unroll
  for (int j = 0; j < 64; ++j){
    wA[j] = W[tid*128 + j];
    wB[j] = W[tid*128 + 64 + j];
  }
  if (tid < 256){ hsb[tid & 255] = 0.0f; csb[tid & 255] = 0.0f; }
  __syncthreads();
  const float2* hsF2 = (const float2*)hsb;
  int rr = tid >> 7, dd = tid & 127;
  for (int t = 0; t < 96; ++t){
    // prefetch x-part gates (hidden under the dot loop)
    const bf16* xp = xpart + ((bn0 + rr)*96 + t)*512 + dd;
    float xg0 = b2f(xp[0]);
    float xg1 = b2f(xp[128]);
    float xg2 = b2f(xp[256]);
    float xg3 = b2f(xp[384]);
    float a0[2], a1[2];
    a0[0]=a0[1]=a1[0]=a1[1]=0.0f;
    #pragma unroll
    for (int kp = 0; kp < 64; ++kp){
      float wa0 = blo(wA[kp]), wa1 = bhi(wA[kp]);
      float wb0 = blo(wB[kp]), wb1 = bhi(wB[kp]);
      #pragma unroll
      for (int r = 0; r < 2; ++r){
        float2 h2 = hsF2[r*64 + kp];
        a0[r] += h2.x*wa0 + h2.y*wa1;
        a1[r] += h2.x*wb0 + h2.y*wb1;
      }
    }
    #pragma unroll
    for (int r = 0; r < 2; ++r)
      ((float2*)(gb + r*512))[tid] = make_float2(a0[r], a1[r]);
    __syncthreads();
    {
      float ii = gb[rr*512 + dd]       + xg0;
      float ff = gb[rr*512 + 128 + dd] + xg1;
      float gg = gb[rr*512 + 256 + dd] + xg2;
      float oo = gb[rr*512 + 384 + dd] + xg3;
      float c  = sigf(ff)*csb[rr*128 + dd] + sigf(ii)*tanhfast(gg);
      float hn = sigf(oo)*tanhfast(c);
      csb[rr*128 + dd] = c;
      hsb[rr*128 + dd] = hn;
    }
    __syncthreads();
  }
  y_f[(bn0 + rr)*128 + dd] = hsb[rr*128 + dd];
}

// ---------------------------------------------------------------------------
// K6: backward LSTM (single step at t=T-1, zero state) + temporal proj Wtp.
// ---------------------------------------------------------------------------
__global__ void k_bwdtp(const bf16* __restrict__ h1, const bf16* __restrict__ Wihb,
                        const bf16* __restrict__ bihb, const bf16* __restrict__ bhhb,
                        const float* __restrict__ y_f, const bf16* __restrict__ Wtp,
                        const bf16* __restrict__ btp, float* __restrict__ ht,
                        const int* __restrict__ flag, bf16* __restrict__ outb,
                        float* __restrict__ outf){
  int bn = blockIdx.x, tid = threadIdx.x;
  __shared__ __align__(16) float xr[128];
  __shared__ float gates[512];
  __shared__ __align__(16) float ycat[256];
  xr[tid] = b2f(h1[(bn*96 + 95)*128 + tid]);
  __syncthreads();
  const float2* xf2 = (const float2*)xr;
  for (int g = tid; g < 512; g += 128){
    const unsigned int* w = (const unsigned int*)(Wihb + g*128);
    float s = b2f(bihb[g]) + b2f(bhhb[g]);
    #pragma unroll 8
    for (int kp = 0; kp < 64; ++kp){
      float2 a = xf2[kp]; unsigned int u = w[kp];
      s += a.x*blo(u) + a.y*bhi(u);
    }
    gates[g] = s;
  }
  __syncthreads();
  float ii = gates[tid], gg = gates[256 + tid], oo = gates[384 + tid];
  float c  = sigf(ii)*tanhfast(gg);
  float yb = sigf(oo)*tanhfast(c);
  ycat[tid]       = y_f[bn*128 + tid];
  ycat[128 + tid] = yb;
  __syncthreads();
  const float2* yf2 = (const float2*)ycat;
  const unsigned int* w = (const unsigned int*)(Wtp + tid*256);
  float s = b2f(btp[tid]);
  #pragma unroll 8
  for (int kp = 0; kp < 128; ++kp){
    float2 a = yf2[kp]; unsigned int u = w[kp];
    s += a.x*blo(u) + a.y*bhi(u);
  }
  ht[bn*128 + tid] = s;
  int oi = 206400 + bn*128 + tid;
  if (flag[0]) outb[oi] = f2b(s); else outf[oi] = s;
}

// ---------------------------------------------------------------------------
// K7: npj = h_temporal @ Wn.T + bn
// ---------------------------------------------------------------------------
__global__ void k_npj(const float* __restrict__ ht, const bf16* __restrict__ Wn,
                      const bf16* __restrict__ bn_, float* __restrict__ npj){
  int bn = blockIdx.x, tid = threadIdx.x;
  __shared__ __align__(16) float row[128];
  row[tid] = ht[bn*128 + tid];
  __syncthreads();
  const float2* rf2 = (const float2*)row;
  const unsigned int* w = (const unsigned int*)(Wn + tid*128);
  float s = b2f(bn_[tid]);
  #pragma unroll 8
  for (int kp = 0; kp < 64; ++kp){
    float2 a = rf2[kp]; unsigned int u = w[kp];
    s += a.x*blo(u) + a.y*bhi(u);
  }
  npj[bn*128 + tid] = s;
}

// ---------------------------------------------------------------------------
// K8: hyperedge features + attention logits.  grid = B*E = 256, block = 128
// ---------------------------------------------------------------------------
__global__ void k_edge(const float* __restrict__ npj, const bf16* __restrict__ Hinc,
                       const bf16* __restrict__ We, const bf16* __restrict__ be,
                       const bf16* __restrict__ Wa, const bf16* __restrict__ ba,
                       float* __restrict__ ee, float* __restrict__ scE){
  int b = blockIdx.x >> 4, e = blockIdx.x & 15, tid = threadIdx.x;
  float acc = 0.0f, deg = 0.0f;
  for (int n = 0; n < 100; ++n){
    float w = b2f(Hinc[n*16 + e]);
    deg += w;
    acc += w * npj[(b*100 + n)*128 + tid];
  }
  __shared__ __align__(16) float eep[128];
  eep[tid] = acc/(deg + 1e-8f);
  __syncthreads();
  const float2* ef2 = (const float2*)eep;
  const unsigned int* w = (const unsigned int*)(We + tid*128);
  float s = b2f(be[tid]);
  #pragma unroll 8
  for (int kp = 0; kp < 64; ++kp){
    float2 a = ef2[kp]; unsigned int u = w[kp];
    s += a.x*blo(u) + a.y*bhi(u);
  }
  ee[(b*16 + e)*128 + tid] = s;
  float p = s * b2f(Wa[tid]);
  #pragma unroll
  for (int off = 32; off; off >>= 1) p += __shfl_down(p, off);
  __shared__ float r2[2];
  if ((tid & 63) == 0) r2[tid>>6] = p;
  __syncthreads();
  if (tid == 0) scE[b*16 + e] = r2[0] + r2[1] + b2f(ba[0]);
}

// ---------------------------------------------------------------------------
// K9: per-node segment softmax over edges + aggregate + residual + LN
// ---------------------------------------------------------------------------
__global__ void k_node(const float* __restrict__ ht, const float* __restrict__ ee,
                       const float* __restrict__ scE, const bf16* __restrict__ Hinc,
                       const bf16* __restrict__ gg_, const bf16* __restrict__ bg_,
                       float* __restrict__ hb2){
  int blk = blockIdx.x; int b = blk/100, n = blk%100; int tid = threadIdx.x;
  __shared__ float wts[16];
  __shared__ float red[4];
  if (tid == 0){
    float sc[16]; float mx = -1e30f;
    for (int e = 0; e < 16; ++e){
      float m_ = b2f(Hinc[n*16 + e]);
      sc[e] = (m_ > 0.0f) ? scE[b*16 + e] : -1e30f;
      mx = fmaxf(mx, sc[e]);
    }
    float tmp[16]; float sum = 0.0f;
    for (int e = 0; e < 16; ++e){
      tmp[e] = (sc[e] > -1e29f) ? __expf(sc[e] - mx) : 0.0f;
      sum += tmp[e];
    }
    float inv = (sum > 0.0f) ? 1.0f/sum : 0.0f;
    for (int e = 0; e < 16; ++e) wts[e] = tmp[e]*inv;
  }
  __syncthreads();
  float s = ht[(b*100 + n)*128 + tid];
  for (int e = 0; e < 16; ++e) s += wts[e] * ee[(b*16 + e)*128 + tid];
  float y = ln128(s, tid, gg_, bg_, red);
  hb2[(b*100 + n)*128 + tid] = y;
}

// ---------------------------------------------------------------------------
// K10: GCN pass + region embedding; writes h_spatial
// ---------------------------------------------------------------------------
__global__ void k_gcn(const float* __restrict__ hb2, const bf16* __restrict__ An,
                      const bf16* __restrict__ Wg, const bf16* __restrict__ bg_,
                      const bf16* __restrict__ Remb, const int* __restrict__ mem,
                      float* __restrict__ hsp, const int* __restrict__ flag,
                      bf16* __restrict__ outb, float* __restrict__ outf){
  int blk = blockIdx.x; int b = blk/100, n = blk%100; int tid = threadIdx.x;
  float acc = 0.0f;
  for (int m = 0; m < 100; ++m){
    float a = b2f(An[n*100 + m]);
    acc += a * hb2[(b*100 + m)*128 + tid];
  }
  __shared__ __align__(16) float as_[128];
  as_[tid] = acc;
  __syncthreads();
  const float2* af2 = (const float2*)as_;
  const unsigned int* w = (const unsigned int*)(Wg + tid*128);
  float s = b2f(bg_[tid]);
  #pragma unroll 8
  for (int kp = 0; kp < 64; ++kp){
    float2 a = af2[kp]; unsigned int u = w[kp];
    s += a.x*blo(u) + a.y*bhi(u);
  }
  s = fmaxf(s, 0.0f);
  float out = hb2[(b*100 + n)*128 + tid] + s + b2f(Remb[mem[n]*128 + tid]);
  hsp[(b*100 + n)*128 + tid] = out;
  int oi = 1600 + (b*100 + n)*128 + tid;
  if (flag[0]) outb[oi] = f2b(out); else outf[oi] = out;
}

// ---------------------------------------------------------------------------
// K11: fusion + LN + relu + MLP head -> pred.  grid = 1600, block = 128
// ---------------------------------------------------------------------------
__global__ void k_fuse(const float* __restrict__ ht, const float* __restrict__ hsp,
                       const bf16* __restrict__ Wf, const bf16* __restrict__ bf_,
                       const bf16* __restrict__ gf, const bf16* __restrict__ b_f,
                       const bf16* __restrict__ W1, const bf16* __restrict__ b1,
                       const bf16* __restrict__ W2, const bf16* __restrict__ b2,
                       const int* __restrict__ flag, bf16* __restrict__ outb,
                       float* __restrict__ outf){
  int bn = blockIdx.x, tid = threadIdx.x;
  __shared__ __align__(16) float cat[256];
  __shared__ __align__(16) float hf[128];
  __shared__ float red[4];
  cat[tid]       = ht[bn*128 + tid];
  cat[128 + tid] = hsp[bn*128 + tid];
  __syncthreads();
  const float2* cf2 = (const float2*)cat;
  const unsigned int* w = (const unsigned int*)(Wf + tid*256);
  float s = b2f(bf_[tid]);
  #pragma unroll 8
  for (int kp = 0; kp < 128; ++kp){
    float2 a = cf2[kp]; unsigned int u = w[kp];
    s += a.x*blo(u) + a.y*bhi(u);
  }
  float y = fmaxf(ln128(s, tid, gf, b_f, red), 0.0f);
  hf[tid] = y;
  __syncthreads();
  if (tid < 64){
    const float2* hf2 = (const float2*)hf;
    const unsigned int* w1 = (const unsigned int*)(W1 + tid*128);
    float z = b2f(b1[tid]);
    #pragma unroll 8
    for (int kp = 0; kp < 64; ++kp){
      float2 a = hf2[kp]; unsigned int u = w1[kp];
      z += a.x*blo(u) + a.y*bhi(u);
    }
    z = fmaxf(z, 0.0f);
    float p = z * b2f(W2[tid]);
    #pragma unroll
    for (int off = 32; off; off >>= 1) p += __shfl_down(p, off);
    if (tid == 0){
      float pr = p + b2f(b2[0]);
      if (flag[0]) outb[bn] = f2b(pr); else outf[bn] = pr;
    }
  }
}

// ---------------------------------------------------------------------------

extern "C" void kernel_launch(void* const* d_in, const int* in_sizes, int n_in,
                              void* d_out, int out_size, void* d_ws, size_t ws_size,
                              hipStream_t stream){
  (void)n_in; (void)out_size; (void)ws_size;
  const int* mem = (const int*)d_in[3];

  // ---- canonical bf16 region layout (element offsets, 8-elem aligned) ----
  CArgs ca;
  int coff[43];
  int nf = 0;
  long long off = 0;
  for (int i = 0; i < 43; ++i){
    if (i == 3){ coff[i] = -1; continue; }
    coff[i] = (int)off;
    ca.src[nf] = d_in[i];
    ca.n[nf]   = in_sizes[i];
    ca.off[nf] = (int)off;
    ++nf;
    off += (long long)((in_sizes[i] + 7) & ~7);
  }
  char* ws = (char*)d_ws;
  bf16* canon = (bf16*)ws;
  long long canonBytes = ((off*2 + 255)/256)*256;
  int* flag = (int*)(ws + canonBytes);
  long long base = canonBytes + 256;

  #define C(i) (canon + coff[i])
  const bf16* A_norm = C(1);
  const bf16* Hinc   = C(2);
  const bf16* Wp  = C(4);  const bf16* bp  = C(5);
  const bf16* g_p = C(6);  const bf16* b_p = C(7);
  const bf16* Wqkv= C(8);  const bf16* bqkv= C(9);
  const bf16* Wo  = C(10); const bf16* bo  = C(11);
  const bf16* g_a = C(12); const bf16* b_a = C(13);
  const bf16* Wih_f = C(14); const bf16* Whh_f = C(15);
  const bf16* bih_f = C(16); const bf16* bhh_f = C(17);
  const bf16* Wih_b = C(18);
  const bf16* bih_b = C(20); const bf16* bhh_b = C(21);
  const bf16* Wtp = C(22); const bf16* btp = C(23);
  const bf16* Wn  = C(24); const bf16* bn_ = C(25);
  const bf16* We  = C(26); const bf16* be  = C(27);
  const bf16* Wa  = C(28); const bf16* ba  = C(29);
  const bf16* g_g = C(30); const bf16* b_g = C(31);
  const bf16* Remb= C(32);
  const bf16* Wg  = C(33); const bf16* bg  = C(34);
  const bf16* Wf  = C(35); const bf16* bff = C(36);
  const bf16* g_f = C(37); const bf16* b_f = C(38);
  const bf16* W1  = C(39); const bf16* b1  = C(40);
  const bf16* W2  = C(41); const bf16* b2  = C(42);
  const bf16* xc  = C(0);
  #undef C

  bf16*  outb = (bf16*)d_out;
  float* outf = (float*)d_out;
  bf16*  h1    = (bf16*)(ws + base);
  bf16*  h0    = (bf16*)(ws + base + 39321600LL);
  bf16*  attno = (bf16*)(ws + base + 78643200LL);
  bf16*  xpart = (bf16*)(ws + base + 39321600LL);   // overlaps h0+attno (phase 2)
  float* y_f   = (float*)(ws + base + 196608000LL);
  float* htb   = (float*)(ws + base + 197427200LL);
  float* npj   = (float*)(ws + base + 198246400LL);
  float* ee    = (float*)(ws + base + 199065600LL);
  float* scE   = (float*)(ws + base + 199196672LL);
  float* hb2   = (float*)(ws + base + 199197696LL);
  float* hsp   = (float*)(ws + base + 200016896LL);

  k_detect<<<1, 256, 0, stream>>>((const unsigned int*)d_in[0], flag);
  k_canon <<<dim3(64, nf), 256, 0, stream>>>(ca, flag, canon);
  k_inproj<<<153600, 128, 0, stream>>>(xc, Wp, bp, g_p, b_p, h0);
  k_attn  <<<1600,   256, 0, stream>>>(h0, Wqkv, bqkv, attno);
  k_oproj <<<1200,   256, 0, stream>>>(attno, h0, Wo, bo, g_a, b_a, h1);
  k_xpart <<<4800,   256, 0, stream>>>(h1, Wih_f, bih_f, bhh_f, xpart);
  k_lstm  <<<800,    256, 0, stream>>>(Whh_f, xpart, y_f);
  k_bwdtp <<<1600,   128, 0, stream>>>(h1, Wih_b, bih_b, bhh_b, y_f, Wtp, btp, htb,
                                       flag, outb, outf);
  k_npj   <<<1600,   128, 0, stream>>>(htb, Wn, bn_, npj);
  k_edge  <<<256,    128, 0, stream>>>(npj, Hinc, We, be, Wa, ba, ee, scE);
  k_node  <<<1600,   128, 0, stream>>>(htb, ee, scE, Hinc, g_g, b_g, hb2);
  k_gcn   <<<1600,   128, 0, stream>>>(hb2, A_norm, Wg, bg, Remb, mem, hsp,
                                       flag, outb, outf);
  k_fuse  <<<1600,   128, 0, stream>>>(htb, hsp, Wf, bff, g_f, b_f, W1, b1, W2, b2,
                                       flag, outb, outf);
}

// Round 5
// 781.152 us; speedup vs baseline: 5.1291x; 2.3154x over previous
//
#include <hip/hip_runtime.h>
#include <hip/hip_bf16.h>

typedef __hip_bfloat16 bf16;
typedef __attribute__((ext_vector_type(8))) short bf8v;   // 8 bf16 (4 VGPRs)
typedef __attribute__((ext_vector_type(4))) short s4v;
typedef __attribute__((ext_vector_type(4))) float f4v;

#define DEV __device__ __forceinline__

DEV float b2f(bf16 v){ return __bfloat162float(v); }
DEV bf16 f2b(float v){ return __float2bfloat16(v); }
DEV short f2bs(float v){ bf16 t = __float2bfloat16(v); return *reinterpret_cast<short*>(&t); }
DEV float s2f(short s){ return __uint_as_float(((unsigned int)(unsigned short)s) << 16); }
DEV float blo(unsigned int u){ return __uint_as_float(u << 16); }
DEV float bhi(unsigned int u){ return __uint_as_float(u & 0xffff0000u); }
DEV float sigf(float x){ return 1.0f/(1.0f + __expf(-x)); }
DEV float tanhfast(float x){
  x = fminf(fmaxf(x, -15.0f), 15.0f);
  float e = __expf(2.0f*x);
  return (e - 1.0f)/(e + 1.0f);
}

DEV f4v mfma16(bf8v a, bf8v b, f4v c){
  return __builtin_amdgcn_mfma_f32_16x16x32_bf16(a, b, c, 0, 0, 0);
}

// LayerNorm across 128 threads (block=128, 2 waves). red = shared float[4].
DEV float ln128(float s, int tid, const bf16* g, const bf16* b, float* red){
  float sum = s, sq = s*s;
  #pragma unroll
  for (int off = 32; off; off >>= 1){
    sum += __shfl_down(sum, off);
    sq  += __shfl_down(sq,  off);
  }
  if ((tid & 63) == 0){ red[(tid>>6)*2] = sum; red[(tid>>6)*2+1] = sq; }
  __syncthreads();
  float S = red[0] + red[2], Q = red[1] + red[3];
  float m  = S * (1.0f/128.0f);
  float var = fmaxf(Q * (1.0f/128.0f) - m*m, 0.0f);
  float rs = rsqrtf(var + 1e-5f);
  float y = (s - m)*rs*b2f(g[tid]) + b2f(b[tid]);
  __syncthreads();
  return y;
}

// ---------------------------------------------------------------------------
// K0a: dtype detector (fp32 vs bf16 inputs). flag[0]=1 -> bf16, 0 -> fp32.
// ---------------------------------------------------------------------------
__global__ void k_detect(const unsigned int* __restrict__ xw, int* __restrict__ flag){
  __shared__ int found;
  if (threadIdx.x == 0) found = 0;
  __syncthreads();
  int local = 0;
  for (int i = threadIdx.x; i < 4096; i += 256){
    unsigned int u = xw[i];
    unsigned int e = (u >> 7) & 0xFF;
    if (e >= 0x90) local = 1;
  }
  if (local) atomicOr(&found, 1);
  __syncthreads();
  if (threadIdx.x == 0) flag[0] = found ? 0 : 1;
}

// ---------------------------------------------------------------------------
// K0b: canonicalize all float inputs into a bf16 region in ws.
// ---------------------------------------------------------------------------
struct CArgs {
  const void* src[44];
  int n[44];
  int off[44];
};

__global__ void k_canon(CArgs a, const int* __restrict__ flag, bf16* __restrict__ dst){
  int id = blockIdx.y;
  int n = a.n[id];
  const void* s = a.src[id];
  bf16* d = dst + a.off[id];
  int stride = gridDim.x * blockDim.x;
  int i0 = blockIdx.x * blockDim.x + threadIdx.x;
  if (flag[0]){
    const bf16* sb = (const bf16*)s;
    for (int i = i0; i < n; i += stride) d[i] = sb[i];
  } else {
    const float* sf = (const float*)s;
    for (int i = i0; i < n; i += stride) d[i] = f2b(sf[i]);
  }
}

// ---------------------------------------------------------------------------
// K1: input projection + LN + relu.  grid = 19200 (8 rows/block), block = 128
// ---------------------------------------------------------------------------
__global__ void k_inproj(const bf16* __restrict__ x, const bf16* __restrict__ Wp,
                         const bf16* __restrict__ bp, const bf16* __restrict__ gp,
                         const bf16* __restrict__ bbp, bf16* __restrict__ h0){
  int row0 = blockIdx.x*8, tid = threadIdx.x;
  __shared__ float xs[8*26];
  __shared__ float red[4];
  float wreg[26];
  #pragma unroll
  for (int f = 0; f < 26; ++f) wreg[f] = b2f(Wp[tid*26 + f]);
  float bias = b2f(bp[tid]);
  for (int i = tid; i < 208; i += 128) xs[i] = b2f(x[row0*26 + i]);
  __syncthreads();
  for (int r = 0; r < 8; ++r){
    float s = bias;
    #pragma unroll
    for (int f = 0; f < 26; ++f) s += xs[r*26 + f]*wreg[f];
    float y = fmaxf(ln128(s, tid, gp, bbp, red), 0.0f);
    h0[(row0 + r)*128 + tid] = f2b(y);
  }
}

// ---------------------------------------------------------------------------
// K2: attention, MFMA flash-style. grid = 1600 (one block per bn), block=256.
// ---------------------------------------------------------------------------
__global__ __launch_bounds__(256,1) void k_attn(const bf16* __restrict__ h0,
    const bf16* __restrict__ Wqkv, const bf16* __restrict__ bqkv,
    bf16* __restrict__ attno){
  int bn = blockIdx.x;
  int tid = threadIdx.x;
  int w = tid >> 6;            // wave = head
  int lane = tid & 63;
  int l15 = lane & 15, quad = lane >> 4;

  __shared__ __align__(16) short h0s[96*136];    // 26112 B; reused as P panels
  __shared__ __align__(16) short q_sh[4][96*40];
  __shared__ __align__(16) short k_sh[4][96*40];
  __shared__ __align__(16) short v_sh[4][32*104];

  {
    const uint4* src = (const uint4*)(h0 + bn*12288);
    uint4* dst = (uint4*)h0s;
    for (int u = tid; u < 1536; u += 256){
      int r = u >> 4, c = u & 15;
      dst[r*17 + c] = src[u];
    }
  }
  __syncthreads();

  short* qp = q_sh[w];
  short* kp = k_sh[w];
  short* vp = v_sh[w];
  const float scl = 0.17677669529663687f;  // 1/sqrt(32), folded into Q

  #pragma unroll
  for (int pan = 0; pan < 3; ++pan){
    for (int n0 = 0; n0 < 32; n0 += 16){
      int rq = pan*128 + w*32 + n0 + l15;
      bf8v b[4];
      #pragma unroll
      for (int ksi = 0; ksi < 4; ++ksi)
        b[ksi] = *reinterpret_cast<const bf8v*>(Wqkv + rq*128 + ksi*32 + quad*8);
      float bias = b2f(bqkv[rq]);
      for (int m = 0; m < 6; ++m){
        f4v acc = {0.f,0.f,0.f,0.f};
        #pragma unroll
        for (int ksi = 0; ksi < 4; ++ksi){
          bf8v a = *reinterpret_cast<const bf8v*>(h0s + (m*16 + l15)*136 + ksi*32 + quad*8);
          acc = mfma16(a, b[ksi], acc);
        }
        if (pan == 0){
          #pragma unroll
          for (int r = 0; r < 4; ++r)
            qp[(m*16 + quad*4 + r)*40 + n0 + l15] = f2bs((acc[r] + bias)*scl);
        } else if (pan == 1){
          #pragma unroll
          for (int r = 0; r < 4; ++r)
            kp[(m*16 + quad*4 + r)*40 + n0 + l15] = f2bs(acc[r] + bias);
        } else {
          s4v vs;
          #pragma unroll
          for (int r = 0; r < 4; ++r) vs[r] = f2bs(acc[r] + bias);
          *reinterpret_cast<s4v*>(vp + (n0 + l15)*104 + m*16 + quad*4) = vs;
        }
      }
    }
  }
  __syncthreads();   // h0s now dead -> reuse as per-wave P panels

  short* pp = h0s + w*1664;   // 16 x 104 bf16 P panel per wave

  for (int m = 0; m < 6; ++m){
    bf8v aq = *reinterpret_cast<const bf8v*>(qp + (m*16 + l15)*40 + quad*8);
    f4v s[6];
    #pragma unroll
    for (int n = 0; n < 6; ++n){
      bf8v bk = *reinterpret_cast<const bf8v*>(kp + (n*16 + l15)*40 + quad*8);
      f4v z = {0.f,0.f,0.f,0.f};
      s[n] = mfma16(aq, bk, z);
    }
    float mr[4], sr[4];
    #pragma unroll
    for (int r = 0; r < 4; ++r){
      float m0 = fmaxf(fmaxf(s[0][r], s[1][r]), fmaxf(s[2][r], s[3][r]));
      mr[r] = fmaxf(m0, fmaxf(s[4][r], s[5][r]));
    }
    #pragma unroll
    for (int mask = 1; mask < 16; mask <<= 1)
      #pragma unroll
      for (int r = 0; r < 4; ++r) mr[r] = fmaxf(mr[r], __shfl_xor(mr[r], mask));
    #pragma unroll
    for (int r = 0; r < 4; ++r) sr[r] = 0.0f;
    #pragma unroll
    for (int n = 0; n < 6; ++n)
      #pragma unroll
      for (int r = 0; r < 4; ++r){
        float p = __expf(s[n][r] - mr[r]);
        s[n][r] = p;
        sr[r] += p;
      }
    #pragma unroll
    for (int mask = 1; mask < 16; mask <<= 1)
      #pragma unroll
      for (int r = 0; r < 4; ++r) sr[r] += __shfl_xor(sr[r], mask);
    #pragma unroll
    for (int n = 0; n < 6; ++n)
      #pragma unroll
      for (int r = 0; r < 4; ++r)
        pp[(quad*4 + r)*104 + n*16 + l15] = f2bs(s[n][r]);
    asm volatile("s_waitcnt lgkmcnt(0)" ::: "memory");
    f4v o0 = {0.f,0.f,0.f,0.f}, o1 = {0.f,0.f,0.f,0.f};
    #pragma unroll
    for (int ksi = 0; ksi < 3; ++ksi){
      bf8v ap  = *reinterpret_cast<const bf8v*>(pp + l15*104 + ksi*32 + quad*8);
      bf8v bv0 = *reinterpret_cast<const bf8v*>(vp + l15*104 + ksi*32 + quad*8);
      bf8v bv1 = *reinterpret_cast<const bf8v*>(vp + (16 + l15)*104 + ksi*32 + quad*8);
      o0 = mfma16(ap, bv0, o0);
      o1 = mfma16(ap, bv1, o1);
    }
    #pragma unroll
    for (int r = 0; r < 4; ++r){
      float inv = 1.0f/sr[r];
      int row = bn*96 + m*16 + quad*4 + r;
      attno[row*128 + w*32 + l15]      = f2b(o0[r]*inv);
      attno[row*128 + w*32 + 16 + l15] = f2b(o1[r]*inv);
    }
  }
}

// ---------------------------------------------------------------------------
// K3: out-proj + residual + LN, MFMA. grid = 1200 (128 rows each), block=256.
// ---------------------------------------------------------------------------
__global__ __launch_bounds__(256,1) void k_oproj(const bf16* __restrict__ attno,
    const bf16* __restrict__ h0, const bf16* __restrict__ Wo,
    const bf16* __restrict__ bo, const bf16* __restrict__ ga,
    const bf16* __restrict__ ba_, bf16* __restrict__ h1){
  int rt = blockIdx.x;
  int tid = threadIdx.x;
  int w = tid >> 6, lane = tid & 63;
  int l15 = lane & 15, quad = lane >> 4;
  __shared__ __align__(16) short atile[128*136];
  {
    const uint4* src = (const uint4*)(attno + rt*16384);
    uint4* dst = (uint4*)atile;
    for (int u = tid; u < 2048; u += 256){
      int r = u >> 4, c = u & 15;
      dst[r*17 + c] = src[u];
    }
  }
  __syncthreads();
  int m0 = w*32;
  bf8v a[2][4];
  #pragma unroll
  for (int m = 0; m < 2; ++m)
    #pragma unroll
    for (int ksi = 0; ksi < 4; ++ksi)
      a[m][ksi] = *reinterpret_cast<const bf8v*>(atile + (m0 + m*16 + l15)*136 + ksi*32 + quad*8);
  f4v acc[2][8];
  #pragma unroll
  for (int m = 0; m < 2; ++m)
    #pragma unroll
    for (int n = 0; n < 8; ++n) acc[m][n] = (f4v){0.f,0.f,0.f,0.f};
  for (int n = 0; n < 8; ++n){
    int G = n*16 + l15;
    bf8v b[4];
    #pragma unroll
    for (int ksi = 0; ksi < 4; ++ksi)
      b[ksi] = *reinterpret_cast<const bf8v*>(Wo + G*128 + ksi*32 + quad*8);
    #pragma unroll
    for (int m = 0; m < 2; ++m)
      #pragma unroll
      for (int ksi = 0; ksi < 4; ++ksi)
        acc[m][n] = mfma16(a[m][ksi], b[ksi], acc[m][n]);
  }
  #pragma unroll
  for (int m = 0; m < 2; ++m){
    int rowbase = rt*128 + m0 + m*16;
    #pragma unroll
    for (int n = 0; n < 8; ++n){
      int col = n*16 + l15;
      float bia = b2f(bo[col]);
      #pragma unroll
      for (int r = 0; r < 4; ++r)
        acc[m][n][r] += bia + b2f(h0[(rowbase + quad*4 + r)*128 + col]);
    }
    float sm[4], sq[4];
    #pragma unroll
    for (int r = 0; r < 4; ++r){ sm[r] = 0.f; sq[r] = 0.f; }
    #pragma unroll
    for (int n = 0; n < 8; ++n)
      #pragma unroll
      for (int r = 0; r < 4; ++r){
        float v = acc[m][n][r];
        sm[r] += v; sq[r] += v*v;
      }
    #pragma unroll
    for (int mask = 1; mask < 16; mask <<= 1)
      #pragma unroll
      for (int r = 0; r < 4; ++r){
        sm[r] += __shfl_xor(sm[r], mask);
        sq[r] += __shfl_xor(sq[r], mask);
      }
    float mean[4], rs[4];
    #pragma unroll
    for (int r = 0; r < 4; ++r){
      mean[r] = sm[r]*(1.0f/128.0f);
      float var = fmaxf(sq[r]*(1.0f/128.0f) - mean[r]*mean[r], 0.0f);
      rs[r] = rsqrtf(var + 1e-5f);
    }
    #pragma unroll
    for (int n = 0; n < 8; ++n){
      int col = n*16 + l15;
      float gv = b2f(ga[col]), bv = b2f(ba_[col]);
      #pragma unroll
      for (int r = 0; r < 4; ++r){
        float y = (acc[m][n][r] - mean[r])*rs[r]*gv + bv;
        h1[(rowbase + quad*4 + r)*128 + col] = f2b(y);
      }
    }
  }
}

// ---------------------------------------------------------------------------
// K4: LSTM x-part GEMM, MFMA. grid = 1200*4 (128 rows x 128 gates), block=256.
// ---------------------------------------------------------------------------
__global__ __launch_bounds__(256,1) void k_xpart(const bf16* __restrict__ h1,
    const bf16* __restrict__ Wih, const bf16* __restrict__ bih,
    const bf16* __restrict__ bhh, bf16* __restrict__ xpart){
  int rt = blockIdx.x >> 2;
  int gt = blockIdx.x & 3;
  int tid = threadIdx.x;
  int w = tid >> 6, lane = tid & 63;
  int l15 = lane & 15, quad = lane >> 4;
  __shared__ __align__(16) short htile[128*136];
  {
    const uint4* src = (const uint4*)(h1 + rt*16384);
    uint4* dst = (uint4*)htile;
    for (int u = tid; u < 2048; u += 256){
      int r = u >> 4, c = u & 15;
      dst[r*17 + c] = src[u];
    }
  }
  __syncthreads();
  int m0 = w*32;
  bf8v a[2][4];
  #pragma unroll
  for (int m = 0; m < 2; ++m)
    #pragma unroll
    for (int ksi = 0; ksi < 4; ++ksi)
      a[m][ksi] = *reinterpret_cast<const bf8v*>(htile + (m0 + m*16 + l15)*136 + ksi*32 + quad*8);
  for (int n = 0; n < 8; ++n){
    int G = gt*128 + n*16 + l15;
    bf8v b[4];
    #pragma unroll
    for (int ksi = 0; ksi < 4; ++ksi)
      b[ksi] = *reinterpret_cast<const bf8v*>(Wih + G*128 + ksi*32 + quad*8);
    float bias = b2f(bih[G]) + b2f(bhh[G]);
    #pragma unroll
    for (int m = 0; m < 2; ++m){
      f4v acc = {0.f,0.f,0.f,0.f};
      #pragma unroll
      for (int ksi = 0; ksi < 4; ++ksi)
        acc = mfma16(a[m][ksi], b[ksi], acc);
      #pragma unroll
      for (int r = 0; r < 4; ++r)
        xpart[(rt*128 + m0 + m*16 + quad*4 + r)*512 + G] = f2b(acc[r] + bias);
    }
  }
}

// ---------------------------------------------------------------------------
// K5: forward LSTM recurrence, MFMA. grid = 100 (16 bn-rows/block), block=256.
// Whh B-fragments in registers for all 96 steps; wave w owns gate columns
// d in [32w,32w+32) for ALL four gate types (n-tiles {role*8 + 2w+db}) so the
// activation is wave-local. c-state fp32 in registers (C-layout); h round-
// trips through LDS (C-layout write -> A-frag read, verified mapping).
// ---------------------------------------------------------------------------
__global__ __launch_bounds__(256,1) void k_lstm(const bf16* __restrict__ Whh,
    const bf16* __restrict__ xpart, float* __restrict__ y_f){
  int bn0 = blockIdx.x * 16;
  int tid = threadIdx.x;
  int w = tid >> 6, lane = tid & 63;
  int l15 = lane & 15, quad = lane >> 4;
  __shared__ __align__(16) short h_lds[16*136];

  // B fragments: [role][db][ktile], n-tile = role*8 + 2w + db
  bf8v bfrag[4][2][4];
  #pragma unroll
  for (int role = 0; role < 4; ++role)
    #pragma unroll
    for (int db = 0; db < 2; ++db){
      int G = role*128 + (2*w + db)*16 + l15;
      #pragma unroll
      for (int kt = 0; kt < 4; ++kt)
        bfrag[role][db][kt] = *reinterpret_cast<const bf8v*>(Whh + G*128 + kt*32 + quad*8);
    }
  for (int i = tid; i < 16*136; i += 256) h_lds[i] = 0;
  f4v c0 = {0.f,0.f,0.f,0.f}, c1 = {0.f,0.f,0.f,0.f};

  // prefetch xpart gates for t = 0
  short xg[2][4][4], xgn[2][4][4];   // [db][role][r]
  const short* xp_s = reinterpret_cast<const short*>(xpart);
  #pragma unroll
  for (int db = 0; db < 2; ++db)
    #pragma unroll
    for (int r = 0; r < 4; ++r){
      int base = ((bn0 + quad*4 + r)*96 + 0)*512 + (2*w + db)*16 + l15;
      #pragma unroll
      for (int role = 0; role < 4; ++role)
        xg[db][role][r] = xp_s[base + role*128];
    }
  __syncthreads();

  for (int t = 0; t < 96; ++t){
    // prefetch next step's gates (completes during this step's work)
    int tn = (t < 95) ? t + 1 : 95;
    #pragma unroll
    for (int db = 0; db < 2; ++db)
      #pragma unroll
      for (int r = 0; r < 4; ++r){
        int base = ((bn0 + quad*4 + r)*96 + tn)*512 + (2*w + db)*16 + l15;
        #pragma unroll
        for (int role = 0; role < 4; ++role)
          xgn[db][role][r] = xp_s[base + role*128];
      }
    // A fragments of h_{t-1}
    bf8v a[4];
    #pragma unroll
    for (int kt = 0; kt < 4; ++kt)
      a[kt] = *reinterpret_cast<const bf8v*>(h_lds + l15*136 + kt*32 + quad*8);
    // gates += h_{t-1} @ Whh^T
    f4v acc[4][2];
    #pragma unroll
    for (int role = 0; role < 4; ++role)
      #pragma unroll
      for (int db = 0; db < 2; ++db){
        f4v z = {0.f,0.f,0.f,0.f};
        #pragma unroll
        for (int kt = 0; kt < 4; ++kt)
          z = mfma16(a[kt], bfrag[role][db][kt], z);
        acc[role][db] = z;
      }
    // activation (wave-local: i,f,g,o all present for this wave's columns)
    float hreg[2][4];
    #pragma unroll
    for (int db = 0; db < 2; ++db)
      #pragma unroll
      for (int r = 0; r < 4; ++r){
        float i_ = acc[0][db][r] + s2f(xg[db][0][r]);
        float f_ = acc[1][db][r] + s2f(xg[db][1][r]);
        float g_ = acc[2][db][r] + s2f(xg[db][2][r]);
        float o_ = acc[3][db][r] + s2f(xg[db][3][r]);
        float cs = (db == 0) ? c0[r] : c1[r];
        float c  = sigf(f_)*cs + sigf(i_)*tanhfast(g_);
        float h  = sigf(o_)*tanhfast(c);
        if (db == 0) c0[r] = c; else c1[r] = c;
        hreg[db][r] = h;
      }
    __syncthreads();   // everyone done reading h_{t-1}
    #pragma unroll
    for (int db = 0; db < 2; ++db)
      #pragma unroll
      for (int r = 0; r < 4; ++r)
        h_lds[(quad*4 + r)*136 + (2*w + db)*16 + l15] = f2bs(hreg[db][r]);
    #pragma unroll
    for (int db = 0; db < 2; ++db)
      #pragma unroll
      for (int role = 0; role < 4; ++role)
        #pragma unroll
        for (int r = 0; r < 4; ++r)
          xg[db][role][r] = xgn[db][role][r];
    __syncthreads();   // h_t visible
  }
  // write y_f = h_{95}
  for (int idx = tid; idx < 2048; idx += 256){
    int r = idx >> 7, d = idx & 127;
    y_f[(bn0 + r)*128 + d] = s2f(h_lds[r*136 + d]);
  }
}

// ---------------------------------------------------------------------------
// K6: backward LSTM (single step at t=T-1, zero state) + temporal proj Wtp.
// ---------------------------------------------------------------------------
__global__ void k_bwdtp(const bf16* __restrict__ h1, const bf16* __restrict__ Wihb,
                        const bf16* __restrict__ bihb, const bf16* __restrict__ bhhb,
                        const float* __restrict__ y_f, const bf16* __restrict__ Wtp,
                        const bf16* __restrict__ btp, float* __restrict__ ht,
                        const int* __restrict__ flag, bf16* __restrict__ outb,
                        float* __restrict__ outf){
  int bn = blockIdx.x, tid = threadIdx.x;
  __shared__ __align__(16) float xr[128];
  __shared__ float gates[512];
  __shared__ __align__(16) float ycat[256];
  xr[tid] = b2f(h1[(bn*96 + 95)*128 + tid]);
  __syncthreads();
  const float2* xf2 = (const float2*)xr;
  for (int g = tid; g < 512; g += 128){
    const unsigned int* w = (const unsigned int*)(Wihb + g*128);
    float s = b2f(bihb[g]) + b2f(bhhb[g]);
    #pragma unroll 8
    for (int kp = 0; kp < 64; ++kp){
      float2 a = xf2[kp]; unsigned int u = w[kp];
      s += a.x*blo(u) + a.y*bhi(u);
    }
    gates[g] = s;
  }
  __syncthreads();
  float ii = gates[tid], gg = gates[256 + tid], oo = gates[384 + tid];
  float c  = sigf(ii)*tanhfast(gg);
  float yb = sigf(oo)*tanhfast(c);
  ycat[tid]       = y_f[bn*128 + tid];
  ycat[128 + tid] = yb;
  __syncthreads();
  const float2* yf2 = (const float2*)ycat;
  const unsigned int* w = (const unsigned int*)(Wtp + tid*256);
  float s = b2f(btp[tid]);
  #pragma unroll 8
  for (int kp = 0; kp < 128; ++kp){
    float2 a = yf2[kp]; unsigned int u = w[kp];
    s += a.x*blo(u) + a.y*bhi(u);
  }
  ht[bn*128 + tid] = s;
  int oi = 206400 + bn*128 + tid;
  if (flag[0]) outb[oi] = f2b(s); else outf[oi] = s;
}

// ---------------------------------------------------------------------------
// K7: npj = h_temporal @ Wn.T + bn
// ---------------------------------------------------------------------------
__global__ void k_npj(const float* __restrict__ ht, const bf16* __restrict__ Wn,
                      const bf16* __restrict__ bn_, float* __restrict__ npj){
  int bn = blockIdx.x, tid = threadIdx.x;
  __shared__ __align__(16) float row[128];
  row[tid] = ht[bn*128 + tid];
  __syncthreads();
  const float2* rf2 = (const float2*)row;
  const unsigned int* w = (const unsigned int*)(Wn + tid*128);
  float s = b2f(bn_[tid]);
  #pragma unroll 8
  for (int kp = 0; kp < 64; ++kp){
    float2 a = rf2[kp]; unsigned int u = w[kp];
    s += a.x*blo(u) + a.y*bhi(u);
  }
  npj[bn*128 + tid] = s;
}

// ---------------------------------------------------------------------------
// K8: hyperedge features + attention logits.  grid = B*E = 256, block = 128
// ---------------------------------------------------------------------------
__global__ void k_edge(const float* __restrict__ npj, const bf16* __restrict__ Hinc,
                       const bf16* __restrict__ We, const bf16* __restrict__ be,
                       const bf16* __restrict__ Wa, const bf16* __restrict__ ba,
                       float* __restrict__ ee, float* __restrict__ scE){
  int b = blockIdx.x >> 4, e = blockIdx.x & 15, tid = threadIdx.x;
  float acc = 0.0f, deg = 0.0f;
  for (int n = 0; n < 100; ++n){
    float w = b2f(Hinc[n*16 + e]);
    deg += w;
    acc += w * npj[(b*100 + n)*128 + tid];
  }
  __shared__ __align__(16) float eep[128];
  eep[tid] = acc/(deg + 1e-8f);
  __syncthreads();
  const float2* ef2 = (const float2*)eep;
  const unsigned int* w = (const unsigned int*)(We + tid*128);
  float s = b2f(be[tid]);
  #pragma unroll 8
  for (int kp = 0; kp < 64; ++kp){
    float2 a = ef2[kp]; unsigned int u = w[kp];
    s += a.x*blo(u) + a.y*bhi(u);
  }
  ee[(b*16 + e)*128 + tid] = s;
  float p = s * b2f(Wa[tid]);
  #pragma unroll
  for (int off = 32; off; off >>= 1) p += __shfl_down(p, off);
  __shared__ float r2[2];
  if ((tid & 63) == 0) r2[tid>>6] = p;
  __syncthreads();
  if (tid == 0) scE[b*16 + e] = r2[0] + r2[1] + b2f(ba[0]);
}

// ---------------------------------------------------------------------------
// K9: per-node segment softmax over edges + aggregate + residual + LN
// ---------------------------------------------------------------------------
__global__ void k_node(const float* __restrict__ ht, const float* __restrict__ ee,
                       const float* __restrict__ scE, const bf16* __restrict__ Hinc,
                       const bf16* __restrict__ gg_, const bf16* __restrict__ bg_,
                       float* __restrict__ hb2){
  int blk = blockIdx.x; int b = blk/100, n = blk%100; int tid = threadIdx.x;
  __shared__ float wts[16];
  __shared__ float red[4];
  if (tid == 0){
    float sc[16]; float mx = -1e30f;
    for (int e = 0; e < 16; ++e){
      float m_ = b2f(Hinc[n*16 + e]);
      sc[e] = (m_ > 0.0f) ? scE[b*16 + e] : -1e30f;
      mx = fmaxf(mx, sc[e]);
    }
    float tmp[16]; float sum = 0.0f;
    for (int e = 0; e < 16; ++e){
      tmp[e] = (sc[e] > -1e29f) ? __expf(sc[e] - mx) : 0.0f;
      sum += tmp[e];
    }
    float inv = (sum > 0.0f) ? 1.0f/sum : 0.0f;
    for (int e = 0; e < 16; ++e) wts[e] = tmp[e]*inv;
  }
  __syncthreads();
  float s = ht[(b*100 + n)*128 + tid];
  for (int e = 0; e < 16; ++e) s += wts[e] * ee[(b*16 + e)*128 + tid];
  float y = ln128(s, tid, gg_, bg_, red);
  hb2[(b*100 + n)*128 + tid] = y;
}

// ---------------------------------------------------------------------------
// K10: GCN pass + region embedding; writes h_spatial
// ---------------------------------------------------------------------------
__global__ void k_gcn(const float* __restrict__ hb2, const bf16* __restrict__ An,
                      const bf16* __restrict__ Wg, const bf16* __restrict__ bg_,
                      const bf16* __restrict__ Remb, const int* __restrict__ mem,
                      float* __restrict__ hsp, const int* __restrict__ flag,
                      bf16* __restrict__ outb, float* __restrict__ outf){
  int blk = blockIdx.x; int b = blk/100, n = blk%100; int tid = threadIdx.x;
  float acc = 0.0f;
  for (int m = 0; m < 100; ++m){
    float a = b2f(An[n*100 + m]);
    acc += a * hb2[(b*100 + m)*128 + tid];
  }
  __shared__ __align__(16) float as_[128];
  as_[tid] = acc;
  __syncthreads();
  const float2* af2 = (const float2*)as_;
  const unsigned int* w = (const unsigned int*)(Wg + tid*128);
  float s = b2f(bg_[tid]);
  #pragma unroll 8
  for (int kp = 0; kp < 64; ++kp){
    float2 a = af2[kp]; unsigned int u = w[kp];
    s += a.x*blo(u) + a.y*bhi(u);
  }
  s = fmaxf(s, 0.0f);
  float out = hb2[(b*100 + n)*128 + tid] + s + b2f(Remb[mem[n]*128 + tid]);
  hsp[(b*100 + n)*128 + tid] = out;
  int oi = 1600 + (b*100 + n)*128 + tid;
  if (flag[0]) outb[oi] = f2b(out); else outf[oi] = out;
}

// ---------------------------------------------------------------------------
// K11: fusion + LN + relu + MLP head -> pred.  grid = 1600, block = 128
// ---------------------------------------------------------------------------
__global__ void k_fuse(const float* __restrict__ ht, const float* __restrict__ hsp,
                       const bf16* __restrict__ Wf, const bf16* __restrict__ bf_,
                       const bf16* __restrict__ gf, const bf16* __restrict__ b_f,
                       const bf16* __restrict__ W1, const bf16* __restrict__ b1,
                       const bf16* __restrict__ W2, const bf16* __restrict__ b2,
                       const int* __restrict__ flag, bf16* __restrict__ outb,
                       float* __restrict__ outf){
  int bn = blockIdx.x, tid = threadIdx.x;
  __shared__ __align__(16) float cat[256];
  __shared__ __align__(16) float hf[128];
  __shared__ float red[4];
  cat[tid]       = ht[bn*128 + tid];
  cat[128 + tid] = hsp[bn*128 + tid];
  __syncthreads();
  const float2* cf2 = (const float2*)cat;
  const unsigned int* w = (const unsigned int*)(Wf + tid*256);
  float s = b2f(bf_[tid]);
  #pragma unroll 8
  for (int kp = 0; kp < 128; ++kp){
    float2 a = cf2[kp]; unsigned int u = w[kp];
    s += a.x*blo(u) + a.y*bhi(u);
  }
  float y = fmaxf(ln128(s, tid, gf, b_f, red), 0.0f);
  hf[tid] = y;
  __syncthreads();
  if (tid < 64){
    const float2* hf2 = (const float2*)hf;
    const unsigned int* w1 = (const unsigned int*)(W1 + tid*128);
    float z = b2f(b1[tid]);
    #pragma unroll 8
    for (int kp = 0; kp < 64; ++kp){
      float2 a = hf2[kp]; unsigned int u = w1[kp];
      z += a.x*blo(u) + a.y*bhi(u);
    }
    z = fmaxf(z, 0.0f);
    float p = z * b2f(W2[tid]);
    #pragma unroll
    for (int off = 32; off; off >>= 1) p += __shfl_down(p, off);
    if (tid == 0){
      float pr = p + b2f(b2[0]);
      if (flag[0]) outb[bn] = f2b(pr); else outf[bn] = pr;
    }
  }
}

// ---------------------------------------------------------------------------

extern "C" void kernel_launch(void* const* d_in, const int* in_sizes, int n_in,
                              void* d_out, int out_size, void* d_ws, size_t ws_size,
                              hipStream_t stream){
  (void)n_in; (void)out_size; (void)ws_size;
  const int* mem = (const int*)d_in[3];

  CArgs ca;
  int coff[43];
  int nf = 0;
  long long off = 0;
  for (int i = 0; i < 43; ++i){
    if (i == 3){ coff[i] = -1; continue; }
    coff[i] = (int)off;
    ca.src[nf] = d_in[i];
    ca.n[nf]   = in_sizes[i];
    ca.off[nf] = (int)off;
    ++nf;
    off += (long long)((in_sizes[i] + 7) & ~7);
  }
  char* ws = (char*)d_ws;
  bf16* canon = (bf16*)ws;
  long long canonBytes = ((off*2 + 255)/256)*256;
  int* flag = (int*)(ws + canonBytes);
  long long base = canonBytes + 256;

  #define C(i) (canon + coff[i])
  const bf16* A_norm = C(1);
  const bf16* Hinc   = C(2);
  const bf16* Wp  = C(4);  const bf16* bp  = C(5);
  const bf16* g_p = C(6);  const bf16* b_p = C(7);
  const bf16* Wqkv= C(8);  const bf16* bqkv= C(9);
  const bf16* Wo  = C(10); const bf16* bo  = C(11);
  const bf16* g_a = C(12); const bf16* b_a = C(13);
  const bf16* Wih_f = C(14); const bf16* Whh_f = C(15);
  const bf16* bih_f = C(16); const bf16* bhh_f = C(17);
  const bf16* Wih_b = C(18);
  const bf16* bih_b = C(20); const bf16* bhh_b = C(21);
  const bf16* Wtp = C(22); const bf16* btp = C(23);
  const bf16* Wn  = C(24); const bf16* bn_ = C(25);
  const bf16* We  = C(26); const bf16* be  = C(27);
  const bf16* Wa  = C(28); const bf16* ba  = C(29);
  const bf16* g_g = C(30); const bf16* b_g = C(31);
  const bf16* Remb= C(32);
  const bf16* Wg  = C(33); const bf16* bg  = C(34);
  const bf16* Wf  = C(35); const bf16* bff = C(36);
  const bf16* g_f = C(37); const bf16* b_f = C(38);
  const bf16* W1  = C(39); const bf16* b1  = C(40);
  const bf16* W2  = C(41); const bf16* b2  = C(42);
  const bf16* xc  = C(0);
  #undef C

  bf16*  outb = (bf16*)d_out;
  float* outf = (float*)d_out;
  bf16*  h1    = (bf16*)(ws + base);
  bf16*  h0    = (bf16*)(ws + base + 39321600LL);
  bf16*  attno = (bf16*)(ws + base + 78643200LL);
  bf16*  xpart = (bf16*)(ws + base + 39321600LL);   // overlaps h0+attno (phase 2)
  float* y_f   = (float*)(ws + base + 196608000LL);
  float* htb   = (float*)(ws + base + 197427200LL);
  float* npj   = (float*)(ws + base + 198246400LL);
  float* ee    = (float*)(ws + base + 199065600LL);
  float* scE   = (float*)(ws + base + 199196672LL);
  float* hb2   = (float*)(ws + base + 199197696LL);
  float* hsp   = (float*)(ws + base + 200016896LL);

  k_detect<<<1, 256, 0, stream>>>((const unsigned int*)d_in[0], flag);
  k_canon <<<dim3(64, nf), 256, 0, stream>>>(ca, flag, canon);
  k_inproj<<<19200, 128, 0, stream>>>(xc, Wp, bp, g_p, b_p, h0);
  k_attn  <<<1600,  256, 0, stream>>>(h0, Wqkv, bqkv, attno);
  k_oproj <<<1200,  256, 0, stream>>>(attno, h0, Wo, bo, g_a, b_a, h1);
  k_xpart <<<4800,  256, 0, stream>>>(h1, Wih_f, bih_f, bhh_f, xpart);
  k_lstm  <<<100,   256, 0, stream>>>(Whh_f, xpart, y_f);
  k_bwdtp <<<1600,  128, 0, stream>>>(h1, Wih_b, bih_b, bhh_b, y_f, Wtp, btp, htb,
                                      flag, outb, outf);
  k_npj   <<<1600,  128, 0, stream>>>(htb, Wn, bn_, npj);
  k_edge  <<<256,   128, 0, stream>>>(npj, Hinc, We, be, Wa, ba, ee, scE);
  k_node  <<<1600,  128, 0, stream>>>(htb, ee, scE, Hinc, g_g, b_g, hb2);
  k_gcn   <<<1600,  128, 0, stream>>>(hb2, A_norm, Wg, bg, Remb, mem, hsp,
                                      flag, outb, outf);
  k_fuse  <<<1600,  128, 0, stream>>>(htb, hsp, Wf, bff, g_f, b_f, W1, b1, W2, b2,
                                      flag, outb, outf);
}

// Round 6
// 680.982 us; speedup vs baseline: 5.8836x; 1.1471x over previous
//
#include <hip/hip_runtime.h>
#include <hip/hip_bf16.h>

typedef __hip_bfloat16 bf16;
typedef __attribute__((ext_vector_type(8))) short bf8v;   // 8 bf16 (4 VGPRs)
typedef __attribute__((ext_vector_type(4))) short s4v;
typedef __attribute__((ext_vector_type(4))) float f4v;

#define DEV __device__ __forceinline__

DEV float b2f(bf16 v){ return __bfloat162float(v); }
DEV bf16 f2b(float v){ return __float2bfloat16(v); }
DEV short f2bs(float v){ bf16 t = __float2bfloat16(v); return *reinterpret_cast<short*>(&t); }
DEV float s2f(short s){ return __uint_as_float(((unsigned int)(unsigned short)s) << 16); }
DEV float blo(unsigned int u){ return __uint_as_float(u << 16); }
DEV float bhi(unsigned int u){ return __uint_as_float(u & 0xffff0000u); }
DEV float sigf(float x){ return 1.0f/(1.0f + __expf(-x)); }
DEV float tanhfast(float x){
  x = fminf(fmaxf(x, -15.0f), 15.0f);
  float e = __expf(2.0f*x);
  return (e - 1.0f)/(e + 1.0f);
}

DEV f4v mfma16(bf8v a, bf8v b, f4v c){
  return __builtin_amdgcn_mfma_f32_16x16x32_bf16(a, b, c, 0, 0, 0);
}

// LayerNorm across 128 threads (block=128, 2 waves). red = shared float[4].
DEV float ln128(float s, int tid, const bf16* g, const bf16* b, float* red){
  float sum = s, sq = s*s;
  #pragma unroll
  for (int off = 32; off; off >>= 1){
    sum += __shfl_down(sum, off);
    sq  += __shfl_down(sq,  off);
  }
  if ((tid & 63) == 0){ red[(tid>>6)*2] = sum; red[(tid>>6)*2+1] = sq; }
  __syncthreads();
  float S = red[0] + red[2], Q = red[1] + red[3];
  float m  = S * (1.0f/128.0f);
  float var = fmaxf(Q * (1.0f/128.0f) - m*m, 0.0f);
  float rs = rsqrtf(var + 1e-5f);
  float y = (s - m)*rs*b2f(g[tid]) + b2f(b[tid]);
  __syncthreads();
  return y;
}

// ---------------------------------------------------------------------------
// K0a: dtype detector (fp32 vs bf16 inputs). flag[0]=1 -> bf16, 0 -> fp32.
// ---------------------------------------------------------------------------
__global__ void k_detect(const unsigned int* __restrict__ xw, int* __restrict__ flag){
  __shared__ int found;
  if (threadIdx.x == 0) found = 0;
  __syncthreads();
  int local = 0;
  for (int i = threadIdx.x; i < 4096; i += 256){
    unsigned int u = xw[i];
    unsigned int e = (u >> 7) & 0xFF;
    if (e >= 0x90) local = 1;
  }
  if (local) atomicOr(&found, 1);
  __syncthreads();
  if (threadIdx.x == 0) flag[0] = found ? 0 : 1;
}

// ---------------------------------------------------------------------------
// K0b: canonicalize all float inputs into a bf16 region in ws.
// ---------------------------------------------------------------------------
struct CArgs {
  const void* src[44];
  int n[44];
  int off[44];
};

__global__ void k_canon(CArgs a, const int* __restrict__ flag, bf16* __restrict__ dst){
  int id = blockIdx.y;
  int n = a.n[id];
  const void* s = a.src[id];
  bf16* d = dst + a.off[id];
  int stride = gridDim.x * blockDim.x;
  int i0 = blockIdx.x * blockDim.x + threadIdx.x;
  if (flag[0]){
    const bf16* sb = (const bf16*)s;
    for (int i = i0; i < n; i += stride) d[i] = sb[i];
  } else {
    const float* sf = (const float*)s;
    for (int i = i0; i < n; i += stride) d[i] = f2b(sf[i]);
  }
}

// ---------------------------------------------------------------------------
// K1: input projection + LN + relu.  grid = 19200 (8 rows/block), block = 128
// ---------------------------------------------------------------------------
__global__ void k_inproj(const bf16* __restrict__ x, const bf16* __restrict__ Wp,
                         const bf16* __restrict__ bp, const bf16* __restrict__ gp,
                         const bf16* __restrict__ bbp, bf16* __restrict__ h0){
  int row0 = blockIdx.x*8, tid = threadIdx.x;
  __shared__ float xs[8*26];
  __shared__ float red[4];
  float wreg[26];
  #pragma unroll
  for (int f = 0; f < 26; ++f) wreg[f] = b2f(Wp[tid*26 + f]);
  float bias = b2f(bp[tid]);
  for (int i = tid; i < 208; i += 128) xs[i] = b2f(x[row0*26 + i]);
  __syncthreads();
  for (int r = 0; r < 8; ++r){
    float s = bias;
    #pragma unroll
    for (int f = 0; f < 26; ++f) s += xs[r*26 + f]*wreg[f];
    float y = fmaxf(ln128(s, tid, gp, bbp, red), 0.0f);
    h0[(row0 + r)*128 + tid] = f2b(y);
  }
}

// ---------------------------------------------------------------------------
// K2: attention, MFMA flash-style. grid = 1600 (one block per bn), block=256.
// ---------------------------------------------------------------------------
__global__ __launch_bounds__(256,1) void k_attn(const bf16* __restrict__ h0,
    const bf16* __restrict__ Wqkv, const bf16* __restrict__ bqkv,
    bf16* __restrict__ attno){
  int bn = blockIdx.x;
  int tid = threadIdx.x;
  int w = tid >> 6;            // wave = head
  int lane = tid & 63;
  int l15 = lane & 15, quad = lane >> 4;

  __shared__ __align__(16) short h0s[96*136];    // 26112 B; reused as P panels
  __shared__ __align__(16) short q_sh[4][96*40];
  __shared__ __align__(16) short k_sh[4][96*40];
  __shared__ __align__(16) short v_sh[4][32*104];

  {
    const uint4* src = (const uint4*)(h0 + bn*12288);
    uint4* dst = (uint4*)h0s;
    for (int u = tid; u < 1536; u += 256){
      int r = u >> 4, c = u & 15;
      dst[r*17 + c] = src[u];
    }
  }
  __syncthreads();

  short* qp = q_sh[w];
  short* kp = k_sh[w];
  short* vp = v_sh[w];
  const float scl = 0.17677669529663687f;  // 1/sqrt(32), folded into Q

  #pragma unroll
  for (int pan = 0; pan < 3; ++pan){
    for (int n0 = 0; n0 < 32; n0 += 16){
      int rq = pan*128 + w*32 + n0 + l15;
      bf8v b[4];
      #pragma unroll
      for (int ksi = 0; ksi < 4; ++ksi)
        b[ksi] = *reinterpret_cast<const bf8v*>(Wqkv + rq*128 + ksi*32 + quad*8);
      float bias = b2f(bqkv[rq]);
      for (int m = 0; m < 6; ++m){
        f4v acc = {0.f,0.f,0.f,0.f};
        #pragma unroll
        for (int ksi = 0; ksi < 4; ++ksi){
          bf8v a = *reinterpret_cast<const bf8v*>(h0s + (m*16 + l15)*136 + ksi*32 + quad*8);
          acc = mfma16(a, b[ksi], acc);
        }
        if (pan == 0){
          #pragma unroll
          for (int r = 0; r < 4; ++r)
            qp[(m*16 + quad*4 + r)*40 + n0 + l15] = f2bs((acc[r] + bias)*scl);
        } else if (pan == 1){
          #pragma unroll
          for (int r = 0; r < 4; ++r)
            kp[(m*16 + quad*4 + r)*40 + n0 + l15] = f2bs(acc[r] + bias);
        } else {
          s4v vs;
          #pragma unroll
          for (int r = 0; r < 4; ++r) vs[r] = f2bs(acc[r] + bias);
          *reinterpret_cast<s4v*>(vp + (n0 + l15)*104 + m*16 + quad*4) = vs;
        }
      }
    }
  }
  __syncthreads();   // h0s now dead -> reuse as per-wave P panels

  short* pp = h0s + w*1664;   // 16 x 104 bf16 P panel per wave

  for (int m = 0; m < 6; ++m){
    bf8v aq = *reinterpret_cast<const bf8v*>(qp + (m*16 + l15)*40 + quad*8);
    f4v s[6];
    #pragma unroll
    for (int n = 0; n < 6; ++n){
      bf8v bk = *reinterpret_cast<const bf8v*>(kp + (n*16 + l15)*40 + quad*8);
      f4v z = {0.f,0.f,0.f,0.f};
      s[n] = mfma16(aq, bk, z);
    }
    float mr[4], sr[4];
    #pragma unroll
    for (int r = 0; r < 4; ++r){
      float m0 = fmaxf(fmaxf(s[0][r], s[1][r]), fmaxf(s[2][r], s[3][r]));
      mr[r] = fmaxf(m0, fmaxf(s[4][r], s[5][r]));
    }
    #pragma unroll
    for (int mask = 1; mask < 16; mask <<= 1)
      #pragma unroll
      for (int r = 0; r < 4; ++r) mr[r] = fmaxf(mr[r], __shfl_xor(mr[r], mask));
    #pragma unroll
    for (int r = 0; r < 4; ++r) sr[r] = 0.0f;
    #pragma unroll
    for (int n = 0; n < 6; ++n)
      #pragma unroll
      for (int r = 0; r < 4; ++r){
        float p = __expf(s[n][r] - mr[r]);
        s[n][r] = p;
        sr[r] += p;
      }
    #pragma unroll
    for (int mask = 1; mask < 16; mask <<= 1)
      #pragma unroll
      for (int r = 0; r < 4; ++r) sr[r] += __shfl_xor(sr[r], mask);
    #pragma unroll
    for (int n = 0; n < 6; ++n)
      #pragma unroll
      for (int r = 0; r < 4; ++r)
        pp[(quad*4 + r)*104 + n*16 + l15] = f2bs(s[n][r]);
    asm volatile("s_waitcnt lgkmcnt(0)" ::: "memory");
    f4v o0 = {0.f,0.f,0.f,0.f}, o1 = {0.f,0.f,0.f,0.f};
    #pragma unroll
    for (int ksi = 0; ksi < 3; ++ksi){
      bf8v ap  = *reinterpret_cast<const bf8v*>(pp + l15*104 + ksi*32 + quad*8);
      bf8v bv0 = *reinterpret_cast<const bf8v*>(vp + l15*104 + ksi*32 + quad*8);
      bf8v bv1 = *reinterpret_cast<const bf8v*>(vp + (16 + l15)*104 + ksi*32 + quad*8);
      o0 = mfma16(ap, bv0, o0);
      o1 = mfma16(ap, bv1, o1);
    }
    #pragma unroll
    for (int r = 0; r < 4; ++r){
      float inv = 1.0f/sr[r];
      int row = bn*96 + m*16 + quad*4 + r;
      attno[row*128 + w*32 + l15]      = f2b(o0[r]*inv);
      attno[row*128 + w*32 + 16 + l15] = f2b(o1[r]*inv);
    }
  }
}

// ---------------------------------------------------------------------------
// K3: out-proj + residual + LN, MFMA. grid = 1200 (128 rows each), block=256.
// ---------------------------------------------------------------------------
__global__ __launch_bounds__(256,1) void k_oproj(const bf16* __restrict__ attno,
    const bf16* __restrict__ h0, const bf16* __restrict__ Wo,
    const bf16* __restrict__ bo, const bf16* __restrict__ ga,
    const bf16* __restrict__ ba_, bf16* __restrict__ h1){
  int rt = blockIdx.x;
  int tid = threadIdx.x;
  int w = tid >> 6, lane = tid & 63;
  int l15 = lane & 15, quad = lane >> 4;
  __shared__ __align__(16) short atile[128*136];
  {
    const uint4* src = (const uint4*)(attno + rt*16384);
    uint4* dst = (uint4*)atile;
    for (int u = tid; u < 2048; u += 256){
      int r = u >> 4, c = u & 15;
      dst[r*17 + c] = src[u];
    }
  }
  __syncthreads();
  int m0 = w*32;
  bf8v a[2][4];
  #pragma unroll
  for (int m = 0; m < 2; ++m)
    #pragma unroll
    for (int ksi = 0; ksi < 4; ++ksi)
      a[m][ksi] = *reinterpret_cast<const bf8v*>(atile + (m0 + m*16 + l15)*136 + ksi*32 + quad*8);
  f4v acc[2][8];
  #pragma unroll
  for (int m = 0; m < 2; ++m)
    #pragma unroll
    for (int n = 0; n < 8; ++n) acc[m][n] = (f4v){0.f,0.f,0.f,0.f};
  for (int n = 0; n < 8; ++n){
    int G = n*16 + l15;
    bf8v b[4];
    #pragma unroll
    for (int ksi = 0; ksi < 4; ++ksi)
      b[ksi] = *reinterpret_cast<const bf8v*>(Wo + G*128 + ksi*32 + quad*8);
    #pragma unroll
    for (int m = 0; m < 2; ++m)
      #pragma unroll
      for (int ksi = 0; ksi < 4; ++ksi)
        acc[m][n] = mfma16(a[m][ksi], b[ksi], acc[m][n]);
  }
  #pragma unroll
  for (int m = 0; m < 2; ++m){
    int rowbase = rt*128 + m0 + m*16;
    #pragma unroll
    for (int n = 0; n < 8; ++n){
      int col = n*16 + l15;
      float bia = b2f(bo[col]);
      #pragma unroll
      for (int r = 0; r < 4; ++r)
        acc[m][n][r] += bia + b2f(h0[(rowbase + quad*4 + r)*128 + col]);
    }
    float sm[4], sq[4];
    #pragma unroll
    for (int r = 0; r < 4; ++r){ sm[r] = 0.f; sq[r] = 0.f; }
    #pragma unroll
    for (int n = 0; n < 8; ++n)
      #pragma unroll
      for (int r = 0; r < 4; ++r){
        float v = acc[m][n][r];
        sm[r] += v; sq[r] += v*v;
      }
    #pragma unroll
    for (int mask = 1; mask < 16; mask <<= 1)
      #pragma unroll
      for (int r = 0; r < 4; ++r){
        sm[r] += __shfl_xor(sm[r], mask);
        sq[r] += __shfl_xor(sq[r], mask);
      }
    float mean[4], rs[4];
    #pragma unroll
    for (int r = 0; r < 4; ++r){
      mean[r] = sm[r]*(1.0f/128.0f);
      float var = fmaxf(sq[r]*(1.0f/128.0f) - mean[r]*mean[r], 0.0f);
      rs[r] = rsqrtf(var + 1e-5f);
    }
    #pragma unroll
    for (int n = 0; n < 8; ++n){
      int col = n*16 + l15;
      float gv = b2f(ga[col]), bv = b2f(ba_[col]);
      #pragma unroll
      for (int r = 0; r < 4; ++r){
        float y = (acc[m][n][r] - mean[r])*rs[r]*gv + bv;
        h1[(rowbase + quad*4 + r)*128 + col] = f2b(y);
      }
    }
  }
}

// ---------------------------------------------------------------------------
// K5: fused forward LSTM (x-part GEMM + recurrence), MFMA.
// grid = 100 (16 samples/block), block = 256, 1 block/CU.
// Wih AND Whh B-fragments live in registers (unified VGPR/AGPR file, 1 wave/
// SIMD). Per step: x_t (16x128) staged coalesced into double-buffered LDS,
// gates = x_t@Wih^T + h_{t-1}@Whh^T + bias, all fp32 in C-layout registers.
// Wave w owns gate columns [32w,32w+32) for all four gate roles -> activation
// is wave-local. Single barrier per step (double-buffered h/x tiles).
// ---------------------------------------------------------------------------
__global__ __launch_bounds__(256,1) void k_lstm(const bf16* __restrict__ Whh,
    const bf16* __restrict__ Wih, const bf16* __restrict__ bih,
    const bf16* __restrict__ bhh, const bf16* __restrict__ h1,
    float* __restrict__ y_f){
  int bn0 = blockIdx.x * 16;
  int tid = threadIdx.x;
  int w = tid >> 6, lane = tid & 63;
  int l15 = lane & 15, quad = lane >> 4;
  __shared__ __align__(16) short hbuf[2][16*136];
  __shared__ __align__(16) short xbuf[2][16*136];

  // B fragments: [role][db][ktile], gate col G = role*128 + (2w+db)*16 + l15
  bf8v whh[4][2][4], wih[4][2][4];
  float bias[4][2];
  #pragma unroll
  for (int role = 0; role < 4; ++role)
    #pragma unroll
    for (int db = 0; db < 2; ++db){
      int G = role*128 + (2*w + db)*16 + l15;
      #pragma unroll
      for (int kt = 0; kt < 4; ++kt){
        whh[role][db][kt] = *reinterpret_cast<const bf8v*>(Whh + G*128 + kt*32 + quad*8);
        wih[role][db][kt] = *reinterpret_cast<const bf8v*>(Wih + G*128 + kt*32 + quad*8);
      }
      bias[role][db] = b2f(bih[G]) + b2f(bhh[G]);
    }
  // zero h state, stage x_0
  for (int i = tid; i < 16*136; i += 256) hbuf[0][i] = 0;
  {
    const uint4* h1u4 = (const uint4*)h1;
    int row = (bn0 + (tid >> 4))*96 + 0;
    ((uint4*)xbuf[0])[(tid >> 4)*17 + (tid & 15)] = h1u4[row*16 + (tid & 15)];
  }
  f4v c0 = {0.f,0.f,0.f,0.f}, c1 = {0.f,0.f,0.f,0.f};
  __syncthreads();

  for (int t = 0; t < 96; ++t){
    int cur = t & 1, nxt = cur ^ 1;
    // issue coalesced prefetch of x_{t+1}
    uint4 xpre;
    if (t < 95){
      const uint4* h1u4 = (const uint4*)h1;
      int row = (bn0 + (tid >> 4))*96 + t + 1;
      xpre = h1u4[row*16 + (tid & 15)];
    }
    // A fragments
    bf8v ah[4], ax[4];
    #pragma unroll
    for (int kt = 0; kt < 4; ++kt){
      ah[kt] = *reinterpret_cast<const bf8v*>(hbuf[cur] + l15*136 + kt*32 + quad*8);
      ax[kt] = *reinterpret_cast<const bf8v*>(xbuf[cur] + l15*136 + kt*32 + quad*8);
    }
    // gates = x@Wih^T + h@Whh^T
    f4v acc[4][2];
    #pragma unroll
    for (int role = 0; role < 4; ++role)
      #pragma unroll
      for (int db = 0; db < 2; ++db){
        f4v z = {0.f,0.f,0.f,0.f};
        #pragma unroll
        for (int kt = 0; kt < 4; ++kt) z = mfma16(ax[kt], wih[role][db][kt], z);
        #pragma unroll
        for (int kt = 0; kt < 4; ++kt) z = mfma16(ah[kt], whh[role][db][kt], z);
        acc[role][db] = z;
      }
    // activation (wave-local)
    float hreg[2][4];
    #pragma unroll
    for (int db = 0; db < 2; ++db)
      #pragma unroll
      for (int r = 0; r < 4; ++r){
        float i_ = acc[0][db][r] + bias[0][db];
        float f_ = acc[1][db][r] + bias[1][db];
        float g_ = acc[2][db][r] + bias[2][db];
        float o_ = acc[3][db][r] + bias[3][db];
        float cs = (db == 0) ? c0[r] : c1[r];
        float c  = sigf(f_)*cs + sigf(i_)*tanhfast(g_);
        float h  = sigf(o_)*tanhfast(c);
        if (db == 0) c0[r] = c; else c1[r] = c;
        hreg[db][r] = h;
      }
    // write h_t and x_{t+1} into the other buffers (no WAR vs cur reads)
    #pragma unroll
    for (int db = 0; db < 2; ++db)
      #pragma unroll
      for (int r = 0; r < 4; ++r)
        hbuf[nxt][(quad*4 + r)*136 + (2*w + db)*16 + l15] = f2bs(hreg[db][r]);
    if (t < 95)
      ((uint4*)xbuf[nxt])[(tid >> 4)*17 + (tid & 15)] = xpre;
    __syncthreads();
  }
  // h_95 ended in hbuf[0] (96 even)
  for (int idx = tid; idx < 2048; idx += 256){
    int r = idx >> 7, d = idx & 127;
    y_f[(bn0 + r)*128 + d] = s2f(hbuf[0][r*136 + d]);
  }
}

// ---------------------------------------------------------------------------
// K6: backward LSTM (single step at t=T-1, zero state) + temporal proj Wtp.
// ---------------------------------------------------------------------------
__global__ void k_bwdtp(const bf16* __restrict__ h1, const bf16* __restrict__ Wihb,
                        const bf16* __restrict__ bihb, const bf16* __restrict__ bhhb,
                        const float* __restrict__ y_f, const bf16* __restrict__ Wtp,
                        const bf16* __restrict__ btp, float* __restrict__ ht,
                        const int* __restrict__ flag, bf16* __restrict__ outb,
                        float* __restrict__ outf){
  int bn = blockIdx.x, tid = threadIdx.x;
  __shared__ __align__(16) float xr[128];
  __shared__ float gates[512];
  __shared__ __align__(16) float ycat[256];
  xr[tid] = b2f(h1[(bn*96 + 95)*128 + tid]);
  __syncthreads();
  const float2* xf2 = (const float2*)xr;
  for (int g = tid; g < 512; g += 128){
    const unsigned int* w = (const unsigned int*)(Wihb + g*128);
    float s = b2f(bihb[g]) + b2f(bhhb[g]);
    #pragma unroll 8
    for (int kp = 0; kp < 64; ++kp){
      float2 a = xf2[kp]; unsigned int u = w[kp];
      s += a.x*blo(u) + a.y*bhi(u);
    }
    gates[g] = s;
  }
  __syncthreads();
  float ii = gates[tid], gg = gates[256 + tid], oo = gates[384 + tid];
  float c  = sigf(ii)*tanhfast(gg);
  float yb = sigf(oo)*tanhfast(c);
  ycat[tid]       = y_f[bn*128 + tid];
  ycat[128 + tid] = yb;
  __syncthreads();
  const float2* yf2 = (const float2*)ycat;
  const unsigned int* w = (const unsigned int*)(Wtp + tid*256);
  float s = b2f(btp[tid]);
  #pragma unroll 8
  for (int kp = 0; kp < 128; ++kp){
    float2 a = yf2[kp]; unsigned int u = w[kp];
    s += a.x*blo(u) + a.y*bhi(u);
  }
  ht[bn*128 + tid] = s;
  int oi = 206400 + bn*128 + tid;
  if (flag[0]) outb[oi] = f2b(s); else outf[oi] = s;
}

// ---------------------------------------------------------------------------
// K7: npj = h_temporal @ Wn.T + bn
// ---------------------------------------------------------------------------
__global__ void k_npj(const float* __restrict__ ht, const bf16* __restrict__ Wn,
                      const bf16* __restrict__ bn_, float* __restrict__ npj){
  int bn = blockIdx.x, tid = threadIdx.x;
  __shared__ __align__(16) float row[128];
  row[tid] = ht[bn*128 + tid];
  __syncthreads();
  const float2* rf2 = (const float2*)row;
  const unsigned int* w = (const unsigned int*)(Wn + tid*128);
  float s = b2f(bn_[tid]);
  #pragma unroll 8
  for (int kp = 0; kp < 64; ++kp){
    float2 a = rf2[kp]; unsigned int u = w[kp];
    s += a.x*blo(u) + a.y*bhi(u);
  }
  npj[bn*128 + tid] = s;
}

// ---------------------------------------------------------------------------
// K8: hyperedge features + attention logits.  grid = B*E = 256, block = 128
// ---------------------------------------------------------------------------
__global__ void k_edge(const float* __restrict__ npj, const bf16* __restrict__ Hinc,
                       const bf16* __restrict__ We, const bf16* __restrict__ be,
                       const bf16* __restrict__ Wa, const bf16* __restrict__ ba,
                       float* __restrict__ ee, float* __restrict__ scE){
  int b = blockIdx.x >> 4, e = blockIdx.x & 15, tid = threadIdx.x;
  float acc = 0.0f, deg = 0.0f;
  for (int n = 0; n < 100; ++n){
    float w = b2f(Hinc[n*16 + e]);
    deg += w;
    acc += w * npj[(b*100 + n)*128 + tid];
  }
  __shared__ __align__(16) float eep[128];
  eep[tid] = acc/(deg + 1e-8f);
  __syncthreads();
  const float2* ef2 = (const float2*)eep;
  const unsigned int* w = (const unsigned int*)(We + tid*128);
  float s = b2f(be[tid]);
  #pragma unroll 8
  for (int kp = 0; kp < 64; ++kp){
    float2 a = ef2[kp]; unsigned int u = w[kp];
    s += a.x*blo(u) + a.y*bhi(u);
  }
  ee[(b*16 + e)*128 + tid] = s;
  float p = s * b2f(Wa[tid]);
  #pragma unroll
  for (int off = 32; off; off >>= 1) p += __shfl_down(p, off);
  __shared__ float r2[2];
  if ((tid & 63) == 0) r2[tid>>6] = p;
  __syncthreads();
  if (tid == 0) scE[b*16 + e] = r2[0] + r2[1] + b2f(ba[0]);
}

// ---------------------------------------------------------------------------
// K9: per-node segment softmax over edges + aggregate + residual + LN
// ---------------------------------------------------------------------------
__global__ void k_node(const float* __restrict__ ht, const float* __restrict__ ee,
                       const float* __restrict__ scE, const bf16* __restrict__ Hinc,
                       const bf16* __restrict__ gg_, const bf16* __restrict__ bg_,
                       float* __restrict__ hb2){
  int blk = blockIdx.x; int b = blk/100, n = blk%100; int tid = threadIdx.x;
  __shared__ float wts[16];
  __shared__ float red[4];
  if (tid == 0){
    float sc[16]; float mx = -1e30f;
    for (int e = 0; e < 16; ++e){
      float m_ = b2f(Hinc[n*16 + e]);
      sc[e] = (m_ > 0.0f) ? scE[b*16 + e] : -1e30f;
      mx = fmaxf(mx, sc[e]);
    }
    float tmp[16]; float sum = 0.0f;
    for (int e = 0; e < 16; ++e){
      tmp[e] = (sc[e] > -1e29f) ? __expf(sc[e] - mx) : 0.0f;
      sum += tmp[e];
    }
    float inv = (sum > 0.0f) ? 1.0f/sum : 0.0f;
    for (int e = 0; e < 16; ++e) wts[e] = tmp[e]*inv;
  }
  __syncthreads();
  float s = ht[(b*100 + n)*128 + tid];
  for (int e = 0; e < 16; ++e) s += wts[e] * ee[(b*16 + e)*128 + tid];
  float y = ln128(s, tid, gg_, bg_, red);
  hb2[(b*100 + n)*128 + tid] = y;
}

// ---------------------------------------------------------------------------
// K10: GCN pass + region embedding; writes h_spatial
// ---------------------------------------------------------------------------
__global__ void k_gcn(const float* __restrict__ hb2, const bf16* __restrict__ An,
                      const bf16* __restrict__ Wg, const bf16* __restrict__ bg_,
                      const bf16* __restrict__ Remb, const int* __restrict__ mem,
                      float* __restrict__ hsp, const int* __restrict__ flag,
                      bf16* __restrict__ outb, float* __restrict__ outf){
  int blk = blockIdx.x; int b = blk/100, n = blk%100; int tid = threadIdx.x;
  float acc = 0.0f;
  for (int m = 0; m < 100; ++m){
    float a = b2f(An[n*100 + m]);
    acc += a * hb2[(b*100 + m)*128 + tid];
  }
  __shared__ __align__(16) float as_[128];
  as_[tid] = acc;
  __syncthreads();
  const float2* af2 = (const float2*)as_;
  const unsigned int* w = (const unsigned int*)(Wg + tid*128);
  float s = b2f(bg_[tid]);
  #pragma unroll 8
  for (int kp = 0; kp < 64; ++kp){
    float2 a = af2[kp]; unsigned int u = w[kp];
    s += a.x*blo(u) + a.y*bhi(u);
  }
  s = fmaxf(s, 0.0f);
  float out = hb2[(b*100 + n)*128 + tid] + s + b2f(Remb[mem[n]*128 + tid]);
  hsp[(b*100 + n)*128 + tid] = out;
  int oi = 1600 + (b*100 + n)*128 + tid;
  if (flag[0]) outb[oi] = f2b(out); else outf[oi] = out;
}

// ---------------------------------------------------------------------------
// K11: fusion + LN + relu + MLP head -> pred.  grid = 1600, block = 128
// ---------------------------------------------------------------------------
__global__ void k_fuse(const float* __restrict__ ht, const float* __restrict__ hsp,
                       const bf16* __restrict__ Wf, const bf16* __restrict__ bf_,
                       const bf16* __restrict__ gf, const bf16* __restrict__ b_f,
                       const bf16* __restrict__ W1, const bf16* __restrict__ b1,
                       const bf16* __restrict__ W2, const bf16* __restrict__ b2,
                       const int* __restrict__ flag, bf16* __restrict__ outb,
                       float* __restrict__ outf){
  int bn = blockIdx.x, tid = threadIdx.x;
  __shared__ __align__(16) float cat[256];
  __shared__ __align__(16) float hf[128];
  __shared__ float red[4];
  cat[tid]       = ht[bn*128 + tid];
  cat[128 + tid] = hsp[bn*128 + tid];
  __syncthreads();
  const float2* cf2 = (const float2*)cat;
  const unsigned int* w = (const unsigned int*)(Wf + tid*256);
  float s = b2f(bf_[tid]);
  #pragma unroll 8
  for (int kp = 0; kp < 128; ++kp){
    float2 a = cf2[kp]; unsigned int u = w[kp];
    s += a.x*blo(u) + a.y*bhi(u);
  }
  float y = fmaxf(ln128(s, tid, gf, b_f, red), 0.0f);
  hf[tid] = y;
  __syncthreads();
  if (tid < 64){
    const float2* hf2 = (const float2*)hf;
    const unsigned int* w1 = (const unsigned int*)(W1 + tid*128);
    float z = b2f(b1[tid]);
    #pragma unroll 8
    for (int kp = 0; kp < 64; ++kp){
      float2 a = hf2[kp]; unsigned int u = w1[kp];
      z += a.x*blo(u) + a.y*bhi(u);
    }
    z = fmaxf(z, 0.0f);
    float p = z * b2f(W2[tid]);
    #pragma unroll
    for (int off = 32; off; off >>= 1) p += __shfl_down(p, off);
    if (tid == 0){
      float pr = p + b2f(b2[0]);
      if (flag[0]) outb[bn] = f2b(pr); else outf[bn] = pr;
    }
  }
}

// ---------------------------------------------------------------------------

extern "C" void kernel_launch(void* const* d_in, const int* in_sizes, int n_in,
                              void* d_out, int out_size, void* d_ws, size_t ws_size,
                              hipStream_t stream){
  (void)n_in; (void)out_size; (void)ws_size;
  const int* mem = (const int*)d_in[3];

  CArgs ca;
  int coff[43];
  int nf = 0;
  long long off = 0;
  for (int i = 0; i < 43; ++i){
    if (i == 3){ coff[i] = -1; continue; }
    coff[i] = (int)off;
    ca.src[nf] = d_in[i];
    ca.n[nf]   = in_sizes[i];
    ca.off[nf] = (int)off;
    ++nf;
    off += (long long)((in_sizes[i] + 7) & ~7);
  }
  char* ws = (char*)d_ws;
  bf16* canon = (bf16*)ws;
  long long canonBytes = ((off*2 + 255)/256)*256;
  int* flag = (int*)(ws + canonBytes);
  long long base = canonBytes + 256;

  #define C(i) (canon + coff[i])
  const bf16* A_norm = C(1);
  const bf16* Hinc   = C(2);
  const bf16* Wp  = C(4);  const bf16* bp  = C(5);
  const bf16* g_p = C(6);  const bf16* b_p = C(7);
  const bf16* Wqkv= C(8);  const bf16* bqkv= C(9);
  const bf16* Wo  = C(10); const bf16* bo  = C(11);
  const bf16* g_a = C(12); const bf16* b_a = C(13);
  const bf16* Wih_f = C(14); const bf16* Whh_f = C(15);
  const bf16* bih_f = C(16); const bf16* bhh_f = C(17);
  const bf16* Wih_b = C(18);
  const bf16* bih_b = C(20); const bf16* bhh_b = C(21);
  const bf16* Wtp = C(22); const bf16* btp = C(23);
  const bf16* Wn  = C(24); const bf16* bn_ = C(25);
  const bf16* We  = C(26); const bf16* be  = C(27);
  const bf16* Wa  = C(28); const bf16* ba  = C(29);
  const bf16* g_g = C(30); const bf16* b_g = C(31);
  const bf16* Remb= C(32);
  const bf16* Wg  = C(33); const bf16* bg  = C(34);
  const bf16* Wf  = C(35); const bf16* bff = C(36);
  const bf16* g_f = C(37); const bf16* b_f = C(38);
  const bf16* W1  = C(39); const bf16* b1  = C(40);
  const bf16* W2  = C(41); const bf16* b2  = C(42);
  const bf16* xc  = C(0);
  #undef C

  bf16*  outb = (bf16*)d_out;
  float* outf = (float*)d_out;
  bf16*  h1    = (bf16*)(ws + base);
  bf16*  h0    = (bf16*)(ws + base + 39321600LL);
  bf16*  attno = (bf16*)(ws + base + 78643200LL);
  float* y_f   = (float*)(ws + base + 196608000LL);
  float* htb   = (float*)(ws + base + 197427200LL);
  float* npj   = (float*)(ws + base + 198246400LL);
  float* ee    = (float*)(ws + base + 199065600LL);
  float* scE   = (float*)(ws + base + 199196672LL);
  float* hb2   = (float*)(ws + base + 199197696LL);
  float* hsp   = (float*)(ws + base + 200016896LL);

  k_detect<<<1, 256, 0, stream>>>((const unsigned int*)d_in[0], flag);
  k_canon <<<dim3(64, nf), 256, 0, stream>>>(ca, flag, canon);
  k_inproj<<<19200, 128, 0, stream>>>(xc, Wp, bp, g_p, b_p, h0);
  k_attn  <<<1600,  256, 0, stream>>>(h0, Wqkv, bqkv, attno);
  k_oproj <<<1200,  256, 0, stream>>>(attno, h0, Wo, bo, g_a, b_a, h1);
  k_lstm  <<<100,   256, 0, stream>>>(Whh_f, Wih_f, bih_f, bhh_f, h1, y_f);
  k_bwdtp <<<1600,  128, 0, stream>>>(h1, Wih_b, bih_b, bhh_b, y_f, Wtp, btp, htb,
                                      flag, outb, outf);
  k_npj   <<<1600,  128, 0, stream>>>(htb, Wn, bn_, npj);
  k_edge  <<<256,   128, 0, stream>>>(npj, Hinc, We, be, Wa, ba, ee, scE);
  k_node  <<<1600,  128, 0, stream>>>(htb, ee, scE, Hinc, g_g, b_g, hb2);
  k_gcn   <<<1600,  128, 0, stream>>>(hb2, A_norm, Wg, bg, Remb, mem, hsp,
                                      flag, outb, outf);
  k_fuse  <<<1600,  128, 0, stream>>>(htb, hsp, Wf, bff, g_f, b_f, W1, b1, W2, b2,
                                      flag, outb, outf);
}

// Round 7
// 585.573 us; speedup vs baseline: 6.8422x; 1.1629x over previous
//
#include <hip/hip_runtime.h>
#include <hip/hip_bf16.h>

typedef __hip_bfloat16 bf16;
typedef __attribute__((ext_vector_type(8))) short bf8v;   // 8 bf16 (4 VGPRs)
typedef __attribute__((ext_vector_type(4))) short s4v;
typedef __attribute__((ext_vector_type(4))) float f4v;

#define DEV __device__ __forceinline__

DEV float b2f(bf16 v){ return __bfloat162float(v); }
DEV bf16 f2b(float v){ return __float2bfloat16(v); }
DEV short f2bs(float v){ bf16 t = __float2bfloat16(v); return *reinterpret_cast<short*>(&t); }
DEV float s2f(short s){ return __uint_as_float(((unsigned int)(unsigned short)s) << 16); }
DEV float blo(unsigned int u){ return __uint_as_float(u << 16); }
DEV float bhi(unsigned int u){ return __uint_as_float(u & 0xffff0000u); }
// fast activations: hardware rcp instead of full-precision division
DEV float rcpf_(float x){ return __builtin_amdgcn_rcpf(x); }
DEV float sigf(float x){ return rcpf_(1.0f + __expf(-x)); }          // inf-safe
DEV float tanhfast(float x){
  x = fminf(fmaxf(x, -15.0f), 15.0f);
  float e = __expf(-2.0f*x);
  return (1.0f - e)*rcpf_(1.0f + e);
}

DEV f4v mfma16(bf8v a, bf8v b, f4v c){
  return __builtin_amdgcn_mfma_f32_16x16x32_bf16(a, b, c, 0, 0, 0);
}

// LayerNorm across 128 threads (block=128, 2 waves). red = shared float[4].
DEV float ln128(float s, int tid, const bf16* g, const bf16* b, float* red){
  float sum = s, sq = s*s;
  #pragma unroll
  for (int off = 32; off; off >>= 1){
    sum += __shfl_down(sum, off);
    sq  += __shfl_down(sq,  off);
  }
  if ((tid & 63) == 0){ red[(tid>>6)*2] = sum; red[(tid>>6)*2+1] = sq; }
  __syncthreads();
  float S = red[0] + red[2], Q = red[1] + red[3];
  float m  = S * (1.0f/128.0f);
  float var = fmaxf(Q * (1.0f/128.0f) - m*m, 0.0f);
  float rs = rsqrtf(var + 1e-5f);
  float y = (s - m)*rs*b2f(g[tid]) + b2f(b[tid]);
  __syncthreads();
  return y;
}

// ---------------------------------------------------------------------------
// K0a: dtype detector (fp32 vs bf16 inputs). flag[0]=1 -> bf16, 0 -> fp32.
// ---------------------------------------------------------------------------
__global__ void k_detect(const unsigned int* __restrict__ xw, int* __restrict__ flag){
  __shared__ int found;
  if (threadIdx.x == 0) found = 0;
  __syncthreads();
  int local = 0;
  for (int i = threadIdx.x; i < 4096; i += 256){
    unsigned int u = xw[i];
    unsigned int e = (u >> 7) & 0xFF;
    if (e >= 0x90) local = 1;
  }
  if (local) atomicOr(&found, 1);
  __syncthreads();
  if (threadIdx.x == 0) flag[0] = found ? 0 : 1;
}

// ---------------------------------------------------------------------------
// K0b: canonicalize all float inputs into a bf16 region in ws.
// ---------------------------------------------------------------------------
struct CArgs {
  const void* src[44];
  int n[44];
  int off[44];
};

__global__ void k_canon(CArgs a, const int* __restrict__ flag, bf16* __restrict__ dst){
  int id = blockIdx.y;
  int n = a.n[id];
  const void* s = a.src[id];
  bf16* d = dst + a.off[id];
  int stride = gridDim.x * blockDim.x;
  int i0 = blockIdx.x * blockDim.x + threadIdx.x;
  if (flag[0]){
    const bf16* sb = (const bf16*)s;
    for (int i = i0; i < n; i += stride) d[i] = sb[i];
  } else {
    const float* sf = (const float*)s;
    for (int i = i0; i < n; i += stride) d[i] = f2b(sf[i]);
  }
}

// ---------------------------------------------------------------------------
// K1: input projection + LN + relu.  grid = 19200 (8 rows/block), block = 128
// ---------------------------------------------------------------------------
__global__ void k_inproj(const bf16* __restrict__ x, const bf16* __restrict__ Wp,
                         const bf16* __restrict__ bp, const bf16* __restrict__ gp,
                         const bf16* __restrict__ bbp, bf16* __restrict__ h0){
  int row0 = blockIdx.x*8, tid = threadIdx.x;
  __shared__ float xs[8*26];
  __shared__ float red[4];
  float wreg[26];
  #pragma unroll
  for (int f = 0; f < 26; ++f) wreg[f] = b2f(Wp[tid*26 + f]);
  float bias = b2f(bp[tid]);
  for (int i = tid; i < 208; i += 128) xs[i] = b2f(x[row0*26 + i]);
  __syncthreads();
  for (int r = 0; r < 8; ++r){
    float s = bias;
    #pragma unroll
    for (int f = 0; f < 26; ++f) s += xs[r*26 + f]*wreg[f];
    float y = fmaxf(ln128(s, tid, gp, bbp, red), 0.0f);
    h0[(row0 + r)*128 + tid] = f2b(y);
  }
}

// ---------------------------------------------------------------------------
// K2: attention, MFMA flash-style. grid = 1600 (one block per bn), block=256.
// ---------------------------------------------------------------------------
__global__ __launch_bounds__(256,1) void k_attn(const bf16* __restrict__ h0,
    const bf16* __restrict__ Wqkv, const bf16* __restrict__ bqkv,
    bf16* __restrict__ attno){
  int bn = blockIdx.x;
  int tid = threadIdx.x;
  int w = tid >> 6;            // wave = head
  int lane = tid & 63;
  int l15 = lane & 15, quad = lane >> 4;

  __shared__ __align__(16) short h0s[96*136];    // 26112 B; reused as P panels
  __shared__ __align__(16) short q_sh[4][96*40];
  __shared__ __align__(16) short k_sh[4][96*40];
  __shared__ __align__(16) short v_sh[4][32*104];

  {
    const uint4* src = (const uint4*)(h0 + bn*12288);
    uint4* dst = (uint4*)h0s;
    for (int u = tid; u < 1536; u += 256){
      int r = u >> 4, c = u & 15;
      dst[r*17 + c] = src[u];
    }
  }
  __syncthreads();

  short* qp = q_sh[w];
  short* kp = k_sh[w];
  short* vp = v_sh[w];
  const float scl = 0.17677669529663687f;  // 1/sqrt(32), folded into Q

  #pragma unroll
  for (int pan = 0; pan < 3; ++pan){
    for (int n0 = 0; n0 < 32; n0 += 16){
      int rq = pan*128 + w*32 + n0 + l15;
      bf8v b[4];
      #pragma unroll
      for (int ksi = 0; ksi < 4; ++ksi)
        b[ksi] = *reinterpret_cast<const bf8v*>(Wqkv + rq*128 + ksi*32 + quad*8);
      float bias = b2f(bqkv[rq]);
      for (int m = 0; m < 6; ++m){
        f4v acc = {0.f,0.f,0.f,0.f};
        #pragma unroll
        for (int ksi = 0; ksi < 4; ++ksi){
          bf8v a = *reinterpret_cast<const bf8v*>(h0s + (m*16 + l15)*136 + ksi*32 + quad*8);
          acc = mfma16(a, b[ksi], acc);
        }
        if (pan == 0){
          #pragma unroll
          for (int r = 0; r < 4; ++r)
            qp[(m*16 + quad*4 + r)*40 + n0 + l15] = f2bs((acc[r] + bias)*scl);
        } else if (pan == 1){
          #pragma unroll
          for (int r = 0; r < 4; ++r)
            kp[(m*16 + quad*4 + r)*40 + n0 + l15] = f2bs(acc[r] + bias);
        } else {
          s4v vs;
          #pragma unroll
          for (int r = 0; r < 4; ++r) vs[r] = f2bs(acc[r] + bias);
          *reinterpret_cast<s4v*>(vp + (n0 + l15)*104 + m*16 + quad*4) = vs;
        }
      }
    }
  }
  __syncthreads();   // h0s now dead -> reuse as per-wave P panels

  short* pp = h0s + w*1664;   // 16 x 104 bf16 P panel per wave

  for (int m = 0; m < 6; ++m){
    bf8v aq = *reinterpret_cast<const bf8v*>(qp + (m*16 + l15)*40 + quad*8);
    f4v s[6];
    #pragma unroll
    for (int n = 0; n < 6; ++n){
      bf8v bk = *reinterpret_cast<const bf8v*>(kp + (n*16 + l15)*40 + quad*8);
      f4v z = {0.f,0.f,0.f,0.f};
      s[n] = mfma16(aq, bk, z);
    }
    float mr[4], sr[4];
    #pragma unroll
    for (int r = 0; r < 4; ++r){
      float m0 = fmaxf(fmaxf(s[0][r], s[1][r]), fmaxf(s[2][r], s[3][r]));
      mr[r] = fmaxf(m0, fmaxf(s[4][r], s[5][r]));
    }
    #pragma unroll
    for (int mask = 1; mask < 16; mask <<= 1)
      #pragma unroll
      for (int r = 0; r < 4; ++r) mr[r] = fmaxf(mr[r], __shfl_xor(mr[r], mask));
    #pragma unroll
    for (int r = 0; r < 4; ++r) sr[r] = 0.0f;
    #pragma unroll
    for (int n = 0; n < 6; ++n)
      #pragma unroll
      for (int r = 0; r < 4; ++r){
        float p = __expf(s[n][r] - mr[r]);
        s[n][r] = p;
        sr[r] += p;
      }
    #pragma unroll
    for (int mask = 1; mask < 16; mask <<= 1)
      #pragma unroll
      for (int r = 0; r < 4; ++r) sr[r] += __shfl_xor(sr[r], mask);
    #pragma unroll
    for (int n = 0; n < 6; ++n)
      #pragma unroll
      for (int r = 0; r < 4; ++r)
        pp[(quad*4 + r)*104 + n*16 + l15] = f2bs(s[n][r]);
    asm volatile("s_waitcnt lgkmcnt(0)" ::: "memory");
    f4v o0 = {0.f,0.f,0.f,0.f}, o1 = {0.f,0.f,0.f,0.f};
    #pragma unroll
    for (int ksi = 0; ksi < 3; ++ksi){
      bf8v ap  = *reinterpret_cast<const bf8v*>(pp + l15*104 + ksi*32 + quad*8);
      bf8v bv0 = *reinterpret_cast<const bf8v*>(vp + l15*104 + ksi*32 + quad*8);
      bf8v bv1 = *reinterpret_cast<const bf8v*>(vp + (16 + l15)*104 + ksi*32 + quad*8);
      o0 = mfma16(ap, bv0, o0);
      o1 = mfma16(ap, bv1, o1);
    }
    #pragma unroll
    for (int r = 0; r < 4; ++r){
      float inv = 1.0f/sr[r];
      int row = bn*96 + m*16 + quad*4 + r;
      attno[row*128 + w*32 + l15]      = f2b(o0[r]*inv);
      attno[row*128 + w*32 + 16 + l15] = f2b(o1[r]*inv);
    }
  }
}

// ---------------------------------------------------------------------------
// K3: out-proj + residual + LN, MFMA. grid = 1200 (128 rows each), block=256.
// ---------------------------------------------------------------------------
__global__ __launch_bounds__(256,1) void k_oproj(const bf16* __restrict__ attno,
    const bf16* __restrict__ h0, const bf16* __restrict__ Wo,
    const bf16* __restrict__ bo, const bf16* __restrict__ ga,
    const bf16* __restrict__ ba_, bf16* __restrict__ h1){
  int rt = blockIdx.x;
  int tid = threadIdx.x;
  int w = tid >> 6, lane = tid & 63;
  int l15 = lane & 15, quad = lane >> 4;
  __shared__ __align__(16) short atile[128*136];
  {
    const uint4* src = (const uint4*)(attno + rt*16384);
    uint4* dst = (uint4*)atile;
    for (int u = tid; u < 2048; u += 256){
      int r = u >> 4, c = u & 15;
      dst[r*17 + c] = src[u];
    }
  }
  __syncthreads();
  int m0 = w*32;
  bf8v a[2][4];
  #pragma unroll
  for (int m = 0; m < 2; ++m)
    #pragma unroll
    for (int ksi = 0; ksi < 4; ++ksi)
      a[m][ksi] = *reinterpret_cast<const bf8v*>(atile + (m0 + m*16 + l15)*136 + ksi*32 + quad*8);
  f4v acc[2][8];
  #pragma unroll
  for (int m = 0; m < 2; ++m)
    #pragma unroll
    for (int n = 0; n < 8; ++n) acc[m][n] = (f4v){0.f,0.f,0.f,0.f};
  for (int n = 0; n < 8; ++n){
    int G = n*16 + l15;
    bf8v b[4];
    #pragma unroll
    for (int ksi = 0; ksi < 4; ++ksi)
      b[ksi] = *reinterpret_cast<const bf8v*>(Wo + G*128 + ksi*32 + quad*8);
    #pragma unroll
    for (int m = 0; m < 2; ++m)
      #pragma unroll
      for (int ksi = 0; ksi < 4; ++ksi)
        acc[m][n] = mfma16(a[m][ksi], b[ksi], acc[m][n]);
  }
  #pragma unroll
  for (int m = 0; m < 2; ++m){
    int rowbase = rt*128 + m0 + m*16;
    #pragma unroll
    for (int n = 0; n < 8; ++n){
      int col = n*16 + l15;
      float bia = b2f(bo[col]);
      #pragma unroll
      for (int r = 0; r < 4; ++r)
        acc[m][n][r] += bia + b2f(h0[(rowbase + quad*4 + r)*128 + col]);
    }
    float sm[4], sq[4];
    #pragma unroll
    for (int r = 0; r < 4; ++r){ sm[r] = 0.f; sq[r] = 0.f; }
    #pragma unroll
    for (int n = 0; n < 8; ++n)
      #pragma unroll
      for (int r = 0; r < 4; ++r){
        float v = acc[m][n][r];
        sm[r] += v; sq[r] += v*v;
      }
    #pragma unroll
    for (int mask = 1; mask < 16; mask <<= 1)
      #pragma unroll
      for (int r = 0; r < 4; ++r){
        sm[r] += __shfl_xor(sm[r], mask);
        sq[r] += __shfl_xor(sq[r], mask);
      }
    float mean[4], rs[4];
    #pragma unroll
    for (int r = 0; r < 4; ++r){
      mean[r] = sm[r]*(1.0f/128.0f);
      float var = fmaxf(sq[r]*(1.0f/128.0f) - mean[r]*mean[r], 0.0f);
      rs[r] = rsqrtf(var + 1e-5f);
    }
    #pragma unroll
    for (int n = 0; n < 8; ++n){
      int col = n*16 + l15;
      float gv = b2f(ga[col]), bv = b2f(ba_[col]);
      #pragma unroll
      for (int r = 0; r < 4; ++r){
        float y = (acc[m][n][r] - mean[r])*rs[r]*gv + bv;
        h1[(rowbase + quad*4 + r)*128 + col] = f2b(y);
      }
    }
  }
}

// ---------------------------------------------------------------------------
// K5: fused forward LSTM (x-part GEMM + recurrence), MFMA.
// grid = 100 (16 samples/block), block = 512 (8 waves, 2/SIMD).
// Wave w owns gate columns [16w,16w+16) for all four gate roles -> 32 MFMA
// and 4 activation elements per thread per step. Wih+Whh B-frags in regs.
// Fast rcp-based sigmoid/tanh (no fp32 division on the critical path).
// ---------------------------------------------------------------------------
__global__ __launch_bounds__(512,1) void k_lstm(const bf16* __restrict__ Whh,
    const bf16* __restrict__ Wih, const bf16* __restrict__ bih,
    const bf16* __restrict__ bhh, const bf16* __restrict__ h1,
    float* __restrict__ y_f){
  int bn0 = blockIdx.x * 16;
  int tid = threadIdx.x;
  int w = tid >> 6, lane = tid & 63;
  int l15 = lane & 15, quad = lane >> 4;
  __shared__ __align__(16) short hbuf[2][16*136];
  __shared__ __align__(16) short xbuf[2][16*136];

  // B fragments: [role][ktile], gate col G = role*128 + w*16 + l15
  bf8v whh[4][4], wih[4][4];
  float bias[4];
  #pragma unroll
  for (int role = 0; role < 4; ++role){
    int G = role*128 + w*16 + l15;
    #pragma unroll
    for (int kt = 0; kt < 4; ++kt){
      whh[role][kt] = *reinterpret_cast<const bf8v*>(Whh + G*128 + kt*32 + quad*8);
      wih[role][kt] = *reinterpret_cast<const bf8v*>(Wih + G*128 + kt*32 + quad*8);
    }
    bias[role] = b2f(bih[G]) + b2f(bhh[G]);
  }
  // zero h state, stage x_0
  for (int i = tid; i < 16*136; i += 512) hbuf[0][i] = 0;
  if (tid < 256){
    const uint4* h1u4 = (const uint4*)h1;
    int row = (bn0 + (tid >> 4))*96 + 0;
    ((uint4*)xbuf[0])[(tid >> 4)*17 + (tid & 15)] = h1u4[row*16 + (tid & 15)];
  }
  f4v c0 = {0.f,0.f,0.f,0.f};
  __syncthreads();

  for (int t = 0; t < 96; ++t){
    int cur = t & 1, nxt = cur ^ 1;
    // issue coalesced prefetch of x_{t+1}
    uint4 xpre;
    if (t < 95 && tid < 256){
      const uint4* h1u4 = (const uint4*)h1;
      int row = (bn0 + (tid >> 4))*96 + t + 1;
      xpre = h1u4[row*16 + (tid & 15)];
    }
    // A fragments
    bf8v ah[4], ax[4];
    #pragma unroll
    for (int kt = 0; kt < 4; ++kt){
      ah[kt] = *reinterpret_cast<const bf8v*>(hbuf[cur] + l15*136 + kt*32 + quad*8);
      ax[kt] = *reinterpret_cast<const bf8v*>(xbuf[cur] + l15*136 + kt*32 + quad*8);
    }
    // gates = x@Wih^T + h@Whh^T
    f4v acc[4];
    #pragma unroll
    for (int role = 0; role < 4; ++role){
      f4v z = {0.f,0.f,0.f,0.f};
      #pragma unroll
      for (int kt = 0; kt < 4; ++kt) z = mfma16(ax[kt], wih[role][kt], z);
      #pragma unroll
      for (int kt = 0; kt < 4; ++kt) z = mfma16(ah[kt], whh[role][kt], z);
      acc[role] = z;
    }
    // activation (wave-local)
    float hreg[4];
    #pragma unroll
    for (int r = 0; r < 4; ++r){
      float i_ = acc[0][r] + bias[0];
      float f_ = acc[1][r] + bias[1];
      float g_ = acc[2][r] + bias[2];
      float o_ = acc[3][r] + bias[3];
      float c  = sigf(f_)*c0[r] + sigf(i_)*tanhfast(g_);
      hreg[r]  = sigf(o_)*tanhfast(c);
      c0[r] = c;
    }
    // write h_t and x_{t+1} into the other buffers (no WAR vs cur reads)
    #pragma unroll
    for (int r = 0; r < 4; ++r)
      hbuf[nxt][(quad*4 + r)*136 + w*16 + l15] = f2bs(hreg[r]);
    if (t < 95 && tid < 256)
      ((uint4*)xbuf[nxt])[(tid >> 4)*17 + (tid & 15)] = xpre;
    __syncthreads();
  }
  // h_95 ended in hbuf[0] (96 even)
  for (int idx = tid; idx < 2048; idx += 512){
    int r = idx >> 7, d = idx & 127;
    y_f[(bn0 + r)*128 + d] = s2f(hbuf[0][r*136 + d]);
  }
}

// ---------------------------------------------------------------------------
// K6: backward LSTM (single step at t=T-1, zero state) + temporal proj Wtp.
// ---------------------------------------------------------------------------
__global__ void k_bwdtp(const bf16* __restrict__ h1, const bf16* __restrict__ Wihb,
                        const bf16* __restrict__ bihb, const bf16* __restrict__ bhhb,
                        const float* __restrict__ y_f, const bf16* __restrict__ Wtp,
                        const bf16* __restrict__ btp, float* __restrict__ ht,
                        const int* __restrict__ flag, bf16* __restrict__ outb,
                        float* __restrict__ outf){
  int bn = blockIdx.x, tid = threadIdx.x;
  __shared__ __align__(16) float xr[128];
  __shared__ float gates[512];
  __shared__ __align__(16) float ycat[256];
  xr[tid] = b2f(h1[(bn*96 + 95)*128 + tid]);
  __syncthreads();
  const float2* xf2 = (const float2*)xr;
  for (int g = tid; g < 512; g += 128){
    const unsigned int* w = (const unsigned int*)(Wihb + g*128);
    float s = b2f(bihb[g]) + b2f(bhhb[g]);
    #pragma unroll 8
    for (int kp = 0; kp < 64; ++kp){
      float2 a = xf2[kp]; unsigned int u = w[kp];
      s += a.x*blo(u) + a.y*bhi(u);
    }
    gates[g] = s;
  }
  __syncthreads();
  float ii = gates[tid], gg = gates[256 + tid], oo = gates[384 + tid];
  float c  = sigf(ii)*tanhfast(gg);
  float yb = sigf(oo)*tanhfast(c);
  ycat[tid]       = y_f[bn*128 + tid];
  ycat[128 + tid] = yb;
  __syncthreads();
  const float2* yf2 = (const float2*)ycat;
  const unsigned int* w = (const unsigned int*)(Wtp + tid*256);
  float s = b2f(btp[tid]);
  #pragma unroll 8
  for (int kp = 0; kp < 128; ++kp){
    float2 a = yf2[kp]; unsigned int u = w[kp];
    s += a.x*blo(u) + a.y*bhi(u);
  }
  ht[bn*128 + tid] = s;
  int oi = 206400 + bn*128 + tid;
  if (flag[0]) outb[oi] = f2b(s); else outf[oi] = s;
}

// ---------------------------------------------------------------------------
// K7: npj = h_temporal @ Wn.T + bn
// ---------------------------------------------------------------------------
__global__ void k_npj(const float* __restrict__ ht, const bf16* __restrict__ Wn,
                      const bf16* __restrict__ bn_, float* __restrict__ npj){
  int bn = blockIdx.x, tid = threadIdx.x;
  __shared__ __align__(16) float row[128];
  row[tid] = ht[bn*128 + tid];
  __syncthreads();
  const float2* rf2 = (const float2*)row;
  const unsigned int* w = (const unsigned int*)(Wn + tid*128);
  float s = b2f(bn_[tid]);
  #pragma unroll 8
  for (int kp = 0; kp < 64; ++kp){
    float2 a = rf2[kp]; unsigned int u = w[kp];
    s += a.x*blo(u) + a.y*bhi(u);
  }
  npj[bn*128 + tid] = s;
}

// ---------------------------------------------------------------------------
// K8: hyperedge features + attention logits.  grid = B*E = 256, block = 128
// ---------------------------------------------------------------------------
__global__ void k_edge(const float* __restrict__ npj, const bf16* __restrict__ Hinc,
                       const bf16* __restrict__ We, const bf16* __restrict__ be,
                       const bf16* __restrict__ Wa, const bf16* __restrict__ ba,
                       float* __restrict__ ee, float* __restrict__ scE){
  int b = blockIdx.x >> 4, e = blockIdx.x & 15, tid = threadIdx.x;
  float acc = 0.0f, deg = 0.0f;
  for (int n = 0; n < 100; ++n){
    float w = b2f(Hinc[n*16 + e]);
    deg += w;
    acc += w * npj[(b*100 + n)*128 + tid];
  }
  __shared__ __align__(16) float eep[128];
  eep[tid] = acc/(deg + 1e-8f);
  __syncthreads();
  const float2* ef2 = (const float2*)eep;
  const unsigned int* w = (const unsigned int*)(We + tid*128);
  float s = b2f(be[tid]);
  #pragma unroll 8
  for (int kp = 0; kp < 64; ++kp){
    float2 a = ef2[kp]; unsigned int u = w[kp];
    s += a.x*blo(u) + a.y*bhi(u);
  }
  ee[(b*16 + e)*128 + tid] = s;
  float p = s * b2f(Wa[tid]);
  #pragma unroll
  for (int off = 32; off; off >>= 1) p += __shfl_down(p, off);
  __shared__ float r2[2];
  if ((tid & 63) == 0) r2[tid>>6] = p;
  __syncthreads();
  if (tid == 0) scE[b*16 + e] = r2[0] + r2[1] + b2f(ba[0]);
}

// ---------------------------------------------------------------------------
// K9: per-node segment softmax over edges + aggregate + residual + LN
// ---------------------------------------------------------------------------
__global__ void k_node(const float* __restrict__ ht, const float* __restrict__ ee,
                       const float* __restrict__ scE, const bf16* __restrict__ Hinc,
                       const bf16* __restrict__ gg_, const bf16* __restrict__ bg_,
                       float* __restrict__ hb2){
  int blk = blockIdx.x; int b = blk/100, n = blk%100; int tid = threadIdx.x;
  __shared__ float wts[16];
  __shared__ float red[4];
  if (tid == 0){
    float sc[16]; float mx = -1e30f;
    for (int e = 0; e < 16; ++e){
      float m_ = b2f(Hinc[n*16 + e]);
      sc[e] = (m_ > 0.0f) ? scE[b*16 + e] : -1e30f;
      mx = fmaxf(mx, sc[e]);
    }
    float tmp[16]; float sum = 0.0f;
    for (int e = 0; e < 16; ++e){
      tmp[e] = (sc[e] > -1e29f) ? __expf(sc[e] - mx) : 0.0f;
      sum += tmp[e];
    }
    float inv = (sum > 0.0f) ? 1.0f/sum : 0.0f;
    for (int e = 0; e < 16; ++e) wts[e] = tmp[e]*inv;
  }
  __syncthreads();
  float s = ht[(b*100 + n)*128 + tid];
  for (int e = 0; e < 16; ++e) s += wts[e] * ee[(b*16 + e)*128 + tid];
  float y = ln128(s, tid, gg_, bg_, red);
  hb2[(b*100 + n)*128 + tid] = y;
}

// ---------------------------------------------------------------------------
// K10: GCN pass + region embedding; writes h_spatial
// ---------------------------------------------------------------------------
__global__ void k_gcn(const float* __restrict__ hb2, const bf16* __restrict__ An,
                      const bf16* __restrict__ Wg, const bf16* __restrict__ bg_,
                      const bf16* __restrict__ Remb, const int* __restrict__ mem,
                      float* __restrict__ hsp, const int* __restrict__ flag,
                      bf16* __restrict__ outb, float* __restrict__ outf){
  int blk = blockIdx.x; int b = blk/100, n = blk%100; int tid = threadIdx.x;
  float acc = 0.0f;
  for (int m = 0; m < 100; ++m){
    float a = b2f(An[n*100 + m]);
    acc += a * hb2[(b*100 + m)*128 + tid];
  }
  __shared__ __align__(16) float as_[128];
  as_[tid] = acc;
  __syncthreads();
  const float2* af2 = (const float2*)as_;
  const unsigned int* w = (const unsigned int*)(Wg + tid*128);
  float s = b2f(bg_[tid]);
  #pragma unroll 8
  for (int kp = 0; kp < 64; ++kp){
    float2 a = af2[kp]; unsigned int u = w[kp];
    s += a.x*blo(u) + a.y*bhi(u);
  }
  s = fmaxf(s, 0.0f);
  float out = hb2[(b*100 + n)*128 + tid] + s + b2f(Remb[mem[n]*128 + tid]);
  hsp[(b*100 + n)*128 + tid] = out;
  int oi = 1600 + (b*100 + n)*128 + tid;
  if (flag[0]) outb[oi] = f2b(out); else outf[oi] = out;
}

// ---------------------------------------------------------------------------
// K11: fusion + LN + relu + MLP head -> pred.  grid = 1600, block = 128
// ---------------------------------------------------------------------------
__global__ void k_fuse(const float* __restrict__ ht, const float* __restrict__ hsp,
                       const bf16* __restrict__ Wf, const bf16* __restrict__ bf_,
                       const bf16* __restrict__ gf, const bf16* __restrict__ b_f,
                       const bf16* __restrict__ W1, const bf16* __restrict__ b1,
                       const bf16* __restrict__ W2, const bf16* __restrict__ b2,
                       const int* __restrict__ flag, bf16* __restrict__ outb,
                       float* __restrict__ outf){
  int bn = blockIdx.x, tid = threadIdx.x;
  __shared__ __align__(16) float cat[256];
  __shared__ __align__(16) float hf[128];
  __shared__ float red[4];
  cat[tid]       = ht[bn*128 + tid];
  cat[128 + tid] = hsp[bn*128 + tid];
  __syncthreads();
  const float2* cf2 = (const float2*)cat;
  const unsigned int* w = (const unsigned int*)(Wf + tid*256);
  float s = b2f(bf_[tid]);
  #pragma unroll 8
  for (int kp = 0; kp < 128; ++kp){
    float2 a = cf2[kp]; unsigned int u = w[kp];
    s += a.x*blo(u) + a.y*bhi(u);
  }
  float y = fmaxf(ln128(s, tid, gf, b_f, red), 0.0f);
  hf[tid] = y;
  __syncthreads();
  if (tid < 64){
    const float2* hf2 = (const float2*)hf;
    const unsigned int* w1 = (const unsigned int*)(W1 + tid*128);
    float z = b2f(b1[tid]);
    #pragma unroll 8
    for (int kp = 0; kp < 64; ++kp){
      float2 a = hf2[kp]; unsigned int u = w1[kp];
      z += a.x*blo(u) + a.y*bhi(u);
    }
    z = fmaxf(z, 0.0f);
    float p = z * b2f(W2[tid]);
    #pragma unroll
    for (int off = 32; off; off >>= 1) p += __shfl_down(p, off);
    if (tid == 0){
      float pr = p + b2f(b2[0]);
      if (flag[0]) outb[bn] = f2b(pr); else outf[bn] = pr;
    }
  }
}

// ---------------------------------------------------------------------------

extern "C" void kernel_launch(void* const* d_in, const int* in_sizes, int n_in,
                              void* d_out, int out_size, void* d_ws, size_t ws_size,
                              hipStream_t stream){
  (void)n_in; (void)out_size; (void)ws_size;
  const int* mem = (const int*)d_in[3];

  CArgs ca;
  int coff[43];
  int nf = 0;
  long long off = 0;
  for (int i = 0; i < 43; ++i){
    if (i == 3){ coff[i] = -1; continue; }
    coff[i] = (int)off;
    ca.src[nf] = d_in[i];
    ca.n[nf]   = in_sizes[i];
    ca.off[nf] = (int)off;
    ++nf;
    off += (long long)((in_sizes[i] + 7) & ~7);
  }
  char* ws = (char*)d_ws;
  bf16* canon = (bf16*)ws;
  long long canonBytes = ((off*2 + 255)/256)*256;
  int* flag = (int*)(ws + canonBytes);
  long long base = canonBytes + 256;

  #define C(i) (canon + coff[i])
  const bf16* A_norm = C(1);
  const bf16* Hinc   = C(2);
  const bf16* Wp  = C(4);  const bf16* bp  = C(5);
  const bf16* g_p = C(6);  const bf16* b_p = C(7);
  const bf16* Wqkv= C(8);  const bf16* bqkv= C(9);
  const bf16* Wo  = C(10); const bf16* bo  = C(11);
  const bf16* g_a = C(12); const bf16* b_a = C(13);
  const bf16* Wih_f = C(14); const bf16* Whh_f = C(15);
  const bf16* bih_f = C(16); const bf16* bhh_f = C(17);
  const bf16* Wih_b = C(18);
  const bf16* bih_b = C(20); const bf16* bhh_b = C(21);
  const bf16* Wtp = C(22); const bf16* btp = C(23);
  const bf16* Wn  = C(24); const bf16* bn_ = C(25);
  const bf16* We  = C(26); const bf16* be  = C(27);
  const bf16* Wa  = C(28); const bf16* ba  = C(29);
  const bf16* g_g = C(30); const bf16* b_g = C(31);
  const bf16* Remb= C(32);
  const bf16* Wg  = C(33); const bf16* bg  = C(34);
  const bf16* Wf  = C(35); const bf16* bff = C(36);
  const bf16* g_f = C(37); const bf16* b_f = C(38);
  const bf16* W1  = C(39); const bf16* b1  = C(40);
  const bf16* W2  = C(41); const bf16* b2  = C(42);
  const bf16* xc  = C(0);
  #undef C

  bf16*  outb = (bf16*)d_out;
  float* outf = (float*)d_out;
  bf16*  h1    = (bf16*)(ws + base);
  bf16*  h0    = (bf16*)(ws + base + 39321600LL);
  bf16*  attno = (bf16*)(ws + base + 78643200LL);
  float* y_f   = (float*)(ws + base + 196608000LL);
  float* htb   = (float*)(ws + base + 197427200LL);
  float* npj   = (float*)(ws + base + 198246400LL);
  float* ee    = (float*)(ws + base + 199065600LL);
  float* scE   = (float*)(ws + base + 199196672LL);
  float* hb2   = (float*)(ws + base + 199197696LL);
  float* hsp   = (float*)(ws + base + 200016896LL);

  k_detect<<<1, 256, 0, stream>>>((const unsigned int*)d_in[0], flag);
  k_canon <<<dim3(64, nf), 256, 0, stream>>>(ca, flag, canon);
  k_inproj<<<19200, 128, 0, stream>>>(xc, Wp, bp, g_p, b_p, h0);
  k_attn  <<<1600,  256, 0, stream>>>(h0, Wqkv, bqkv, attno);
  k_oproj <<<1200,  256, 0, stream>>>(attno, h0, Wo, bo, g_a, b_a, h1);
  k_lstm  <<<100,   512, 0, stream>>>(Whh_f, Wih_f, bih_f, bhh_f, h1, y_f);
  k_bwdtp <<<1600,  128, 0, stream>>>(h1, Wih_b, bih_b, bhh_b, y_f, Wtp, btp, htb,
                                      flag, outb, outf);
  k_npj   <<<1600,  128, 0, stream>>>(htb, Wn, bn_, npj);
  k_edge  <<<256,   128, 0, stream>>>(npj, Hinc, We, be, Wa, ba, ee, scE);
  k_node  <<<1600,  128, 0, stream>>>(htb, ee, scE, Hinc, g_g, b_g, hb2);
  k_gcn   <<<1600,  128, 0, stream>>>(hb2, A_norm, Wg, bg, Remb, mem, hsp,
                                      flag, outb, outf);
  k_fuse  <<<1600,  128, 0, stream>>>(htb, hsp, Wf, bff, g_f, b_f, W1, b1, W2, b2,
                                      flag, outb, outf);
}

// Round 8
// 574.302 us; speedup vs baseline: 6.9765x; 1.0196x over previous
//
#include <hip/hip_runtime.h>
#include <hip/hip_bf16.h>

typedef __hip_bfloat16 bf16;
typedef __attribute__((ext_vector_type(8))) short bf8v;   // 8 bf16 (4 VGPRs)
typedef __attribute__((ext_vector_type(4))) short s4v;
typedef __attribute__((ext_vector_type(4))) float f4v;

#define DEV __device__ __forceinline__

DEV float b2f(bf16 v){ return __bfloat162float(v); }
DEV bf16 f2b(float v){ return __float2bfloat16(v); }
DEV short f2bs(float v){ bf16 t = __float2bfloat16(v); return *reinterpret_cast<short*>(&t); }
DEV float s2f(short s){ return __uint_as_float(((unsigned int)(unsigned short)s) << 16); }
DEV float blo(unsigned int u){ return __uint_as_float(u << 16); }
DEV float bhi(unsigned int u){ return __uint_as_float(u & 0xffff0000u); }
// fast activations: hardware rcp instead of full-precision division
DEV float rcpf_(float x){ return __builtin_amdgcn_rcpf(x); }
DEV float sigf(float x){ return rcpf_(1.0f + __expf(-x)); }
DEV float tanhfast(float x){
  x = fminf(fmaxf(x, -15.0f), 15.0f);
  float e = __expf(-2.0f*x);
  return (1.0f - e)*rcpf_(1.0f + e);
}

DEV f4v mfma16(bf8v a, bf8v b, f4v c){
  return __builtin_amdgcn_mfma_f32_16x16x32_bf16(a, b, c, 0, 0, 0);
}

// LayerNorm across 128 threads (block=128, 2 waves). red = shared float[4].
DEV float ln128(float s, int tid, const bf16* g, const bf16* b, float* red){
  float sum = s, sq = s*s;
  #pragma unroll
  for (int off = 32; off; off >>= 1){
    sum += __shfl_down(sum, off);
    sq  += __shfl_down(sq,  off);
  }
  if ((tid & 63) == 0){ red[(tid>>6)*2] = sum; red[(tid>>6)*2+1] = sq; }
  __syncthreads();
  float S = red[0] + red[2], Q = red[1] + red[3];
  float m  = S * (1.0f/128.0f);
  float var = fmaxf(Q * (1.0f/128.0f) - m*m, 0.0f);
  float rs = rsqrtf(var + 1e-5f);
  float y = (s - m)*rs*b2f(g[tid]) + b2f(b[tid]);
  __syncthreads();
  return y;
}

// ---------------------------------------------------------------------------
// K0a: dtype detector (fp32 vs bf16 inputs). flag[0]=1 -> bf16, 0 -> fp32.
// ---------------------------------------------------------------------------
__global__ void k_detect(const unsigned int* __restrict__ xw, int* __restrict__ flag){
  __shared__ int found;
  if (threadIdx.x == 0) found = 0;
  __syncthreads();
  int local = 0;
  for (int i = threadIdx.x; i < 4096; i += 256){
    unsigned int u = xw[i];
    unsigned int e = (u >> 7) & 0xFF;
    if (e >= 0x90) local = 1;
  }
  if (local) atomicOr(&found, 1);
  __syncthreads();
  if (threadIdx.x == 0) flag[0] = found ? 0 : 1;
}

// ---------------------------------------------------------------------------
// K0b: canonicalize all float inputs into a bf16 region in ws.
// ---------------------------------------------------------------------------
struct CArgs {
  const void* src[44];
  int n[44];
  int off[44];
};

__global__ void k_canon(CArgs a, const int* __restrict__ flag, bf16* __restrict__ dst){
  int id = blockIdx.y;
  int n = a.n[id];
  const void* s = a.src[id];
  bf16* d = dst + a.off[id];
  int stride = gridDim.x * blockDim.x;
  int i0 = blockIdx.x * blockDim.x + threadIdx.x;
  if (flag[0]){
    const bf16* sb = (const bf16*)s;
    for (int i = i0; i < n; i += stride) d[i] = sb[i];
  } else {
    const float* sf = (const float*)s;
    for (int i = i0; i < n; i += stride) d[i] = f2b(sf[i]);
  }
}

// ---------------------------------------------------------------------------
// K1: input projection + LN + relu.  grid = 19200 (8 rows/block), block = 128
// ---------------------------------------------------------------------------
__global__ void k_inproj(const bf16* __restrict__ x, const bf16* __restrict__ Wp,
                         const bf16* __restrict__ bp, const bf16* __restrict__ gp,
                         const bf16* __restrict__ bbp, bf16* __restrict__ h0){
  int row0 = blockIdx.x*8, tid = threadIdx.x;
  __shared__ float xs[8*26];
  __shared__ float red[4];
  float wreg[26];
  #pragma unroll
  for (int f = 0; f < 26; ++f) wreg[f] = b2f(Wp[tid*26 + f]);
  float bias = b2f(bp[tid]);
  for (int i = tid; i < 208; i += 128) xs[i] = b2f(x[row0*26 + i]);
  __syncthreads();
  for (int r = 0; r < 8; ++r){
    float s = bias;
    #pragma unroll
    for (int f = 0; f < 26; ++f) s += xs[r*26 + f]*wreg[f];
    float y = fmaxf(ln128(s, tid, gp, bbp, red), 0.0f);
    h0[(row0 + r)*128 + tid] = f2b(y);
  }
}

// ---------------------------------------------------------------------------
// K2: attention, MFMA flash-style. grid = 1600, block = 256 (wave = head).
// Q,K panels live in REGISTERS (A/B-frags) via per-wave transient LDS
// transpose; LDS = h0s 26112 + v 26624 + scr 5120 = 57856 B -> 2 blocks/CU.
// ---------------------------------------------------------------------------
__global__ __launch_bounds__(256) void k_attn(const bf16* __restrict__ h0,
    const bf16* __restrict__ Wqkv, const bf16* __restrict__ bqkv,
    bf16* __restrict__ attno){
  int bn = blockIdx.x;
  int tid = threadIdx.x;
  int w = tid >> 6;            // wave = head
  int lane = tid & 63;
  int l15 = lane & 15, quad = lane >> 4;

  __shared__ __align__(16) short h0s[96*136];    // reused as P panels later
  __shared__ __align__(16) short v_sh[4][32*104];// per-head V^T (dim x seq)
  __shared__ __align__(16) short scr[4][16*40];  // per-wave transpose scratch

  {
    const uint4* src = (const uint4*)(h0 + bn*12288);
    uint4* dst = (uint4*)h0s;
    for (int u = tid; u < 1536; u += 256){
      int r = u >> 4, c = u & 15;
      dst[r*17 + c] = src[u];
    }
  }
  __syncthreads();

  short* vp = v_sh[w];
  short* sw = scr[w];
  const float scl = 0.17677669529663687f;  // 1/sqrt(32), folded into Q

  bf8v aq[6], bk[6];
  // Phase 1a: Q panels -> registers (C-layout -> scratch -> A-frag)
  for (int m = 0; m < 6; ++m){
    bf8v a[4];
    #pragma unroll
    for (int kt = 0; kt < 4; ++kt)
      a[kt] = *reinterpret_cast<const bf8v*>(h0s + (m*16 + l15)*136 + kt*32 + quad*8);
    #pragma unroll
    for (int n0 = 0; n0 < 32; n0 += 16){
      int rq = w*32 + n0 + l15;
      bf8v b[4];
      #pragma unroll
      for (int kt = 0; kt < 4; ++kt)
        b[kt] = *reinterpret_cast<const bf8v*>(Wqkv + rq*128 + kt*32 + quad*8);
      float bias = b2f(bqkv[rq]);
      f4v acc = {0.f,0.f,0.f,0.f};
      #pragma unroll
      for (int kt = 0; kt < 4; ++kt) acc = mfma16(a[kt], b[kt], acc);
      #pragma unroll
      for (int r = 0; r < 4; ++r)
        sw[(quad*4 + r)*40 + n0 + l15] = f2bs((acc[r] + bias)*scl);
    }
    asm volatile("s_waitcnt lgkmcnt(0)" ::: "memory");
    aq[m] = *reinterpret_cast<const bf8v*>(sw + l15*40 + quad*8);
  }
  // Phase 1b: K panels -> registers (B-frags)
  for (int m = 0; m < 6; ++m){
    bf8v a[4];
    #pragma unroll
    for (int kt = 0; kt < 4; ++kt)
      a[kt] = *reinterpret_cast<const bf8v*>(h0s + (m*16 + l15)*136 + kt*32 + quad*8);
    #pragma unroll
    for (int n0 = 0; n0 < 32; n0 += 16){
      int rq = 128 + w*32 + n0 + l15;
      bf8v b[4];
      #pragma unroll
      for (int kt = 0; kt < 4; ++kt)
        b[kt] = *reinterpret_cast<const bf8v*>(Wqkv + rq*128 + kt*32 + quad*8);
      float bias = b2f(bqkv[rq]);
      f4v acc = {0.f,0.f,0.f,0.f};
      #pragma unroll
      for (int kt = 0; kt < 4; ++kt) acc = mfma16(a[kt], b[kt], acc);
      #pragma unroll
      for (int r = 0; r < 4; ++r)
        sw[(quad*4 + r)*40 + n0 + l15] = f2bs(acc[r] + bias);
    }
    asm volatile("s_waitcnt lgkmcnt(0)" ::: "memory");
    bk[m] = *reinterpret_cast<const bf8v*>(sw + l15*40 + quad*8);
  }
  // Phase 1c: V -> LDS transposed (dim x seq)
  for (int m = 0; m < 6; ++m){
    bf8v a[4];
    #pragma unroll
    for (int kt = 0; kt < 4; ++kt)
      a[kt] = *reinterpret_cast<const bf8v*>(h0s + (m*16 + l15)*136 + kt*32 + quad*8);
    #pragma unroll
    for (int n0 = 0; n0 < 32; n0 += 16){
      int rq = 256 + w*32 + n0 + l15;
      bf8v b[4];
      #pragma unroll
      for (int kt = 0; kt < 4; ++kt)
        b[kt] = *reinterpret_cast<const bf8v*>(Wqkv + rq*128 + kt*32 + quad*8);
      float bias = b2f(bqkv[rq]);
      f4v acc = {0.f,0.f,0.f,0.f};
      #pragma unroll
      for (int kt = 0; kt < 4; ++kt) acc = mfma16(a[kt], b[kt], acc);
      s4v vs;
      #pragma unroll
      for (int r = 0; r < 4; ++r) vs[r] = f2bs(acc[r] + bias);
      *reinterpret_cast<s4v*>(vp + (n0 + l15)*104 + m*16 + quad*4) = vs;
    }
  }
  __syncthreads();   // h0s now dead -> reuse as per-wave P panels

  short* pp = h0s + w*1664;   // 16 x 104 bf16 P panel per wave

  // Phase 2: per m-tile: S = Q K^T (regs), softmax, P V
  for (int m = 0; m < 6; ++m){
    f4v s[6];
    #pragma unroll
    for (int n = 0; n < 6; ++n){
      f4v z = {0.f,0.f,0.f,0.f};
      s[n] = mfma16(aq[m], bk[n], z);
    }
    float mr[4], sr[4];
    #pragma unroll
    for (int r = 0; r < 4; ++r){
      float m0 = fmaxf(fmaxf(s[0][r], s[1][r]), fmaxf(s[2][r], s[3][r]));
      mr[r] = fmaxf(m0, fmaxf(s[4][r], s[5][r]));
    }
    #pragma unroll
    for (int mask = 1; mask < 16; mask <<= 1)
      #pragma unroll
      for (int r = 0; r < 4; ++r) mr[r] = fmaxf(mr[r], __shfl_xor(mr[r], mask));
    #pragma unroll
    for (int r = 0; r < 4; ++r) sr[r] = 0.0f;
    #pragma unroll
    for (int n = 0; n < 6; ++n)
      #pragma unroll
      for (int r = 0; r < 4; ++r){
        float p = __expf(s[n][r] - mr[r]);
        s[n][r] = p;
        sr[r] += p;
      }
    #pragma unroll
    for (int mask = 1; mask < 16; mask <<= 1)
      #pragma unroll
      for (int r = 0; r < 4; ++r) sr[r] += __shfl_xor(sr[r], mask);
    #pragma unroll
    for (int n = 0; n < 6; ++n)
      #pragma unroll
      for (int r = 0; r < 4; ++r)
        pp[(quad*4 + r)*104 + n*16 + l15] = f2bs(s[n][r]);
    asm volatile("s_waitcnt lgkmcnt(0)" ::: "memory");
    f4v o0 = {0.f,0.f,0.f,0.f}, o1 = {0.f,0.f,0.f,0.f};
    #pragma unroll
    for (int ksi = 0; ksi < 3; ++ksi){
      bf8v ap  = *reinterpret_cast<const bf8v*>(pp + l15*104 + ksi*32 + quad*8);
      bf8v bv0 = *reinterpret_cast<const bf8v*>(vp + l15*104 + ksi*32 + quad*8);
      bf8v bv1 = *reinterpret_cast<const bf8v*>(vp + (16 + l15)*104 + ksi*32 + quad*8);
      o0 = mfma16(ap, bv0, o0);
      o1 = mfma16(ap, bv1, o1);
    }
    #pragma unroll
    for (int r = 0; r < 4; ++r){
      float inv = 1.0f/sr[r];
      int row = bn*96 + m*16 + quad*4 + r;
      attno[row*128 + w*32 + l15]      = f2b(o0[r]*inv);
      attno[row*128 + w*32 + 16 + l15] = f2b(o1[r]*inv);
    }
  }
}

// ---------------------------------------------------------------------------
// K3: out-proj + residual + LN, MFMA. grid = 1200 (128 rows each), block=256.
// ---------------------------------------------------------------------------
__global__ __launch_bounds__(256) void k_oproj(const bf16* __restrict__ attno,
    const bf16* __restrict__ h0, const bf16* __restrict__ Wo,
    const bf16* __restrict__ bo, const bf16* __restrict__ ga,
    const bf16* __restrict__ ba_, bf16* __restrict__ h1){
  int rt = blockIdx.x;
  int tid = threadIdx.x;
  int w = tid >> 6, lane = tid & 63;
  int l15 = lane & 15, quad = lane >> 4;
  __shared__ __align__(16) short atile[128*136];
  {
    const uint4* src = (const uint4*)(attno + rt*16384);
    uint4* dst = (uint4*)atile;
    for (int u = tid; u < 2048; u += 256){
      int r = u >> 4, c = u & 15;
      dst[r*17 + c] = src[u];
    }
  }
  __syncthreads();
  int m0 = w*32;
  bf8v a[2][4];
  #pragma unroll
  for (int m = 0; m < 2; ++m)
    #pragma unroll
    for (int ksi = 0; ksi < 4; ++ksi)
      a[m][ksi] = *reinterpret_cast<const bf8v*>(atile + (m0 + m*16 + l15)*136 + ksi*32 + quad*8);
  f4v acc[2][8];
  #pragma unroll
  for (int m = 0; m < 2; ++m)
    #pragma unroll
    for (int n = 0; n < 8; ++n) acc[m][n] = (f4v){0.f,0.f,0.f,0.f};
  for (int n = 0; n < 8; ++n){
    int G = n*16 + l15;
    bf8v b[4];
    #pragma unroll
    for (int ksi = 0; ksi < 4; ++ksi)
      b[ksi] = *reinterpret_cast<const bf8v*>(Wo + G*128 + ksi*32 + quad*8);
    #pragma unroll
    for (int m = 0; m < 2; ++m)
      #pragma unroll
      for (int ksi = 0; ksi < 4; ++ksi)
        acc[m][n] = mfma16(a[m][ksi], b[ksi], acc[m][n]);
  }
  #pragma unroll
  for (int m = 0; m < 2; ++m){
    int rowbase = rt*128 + m0 + m*16;
    #pragma unroll
    for (int n = 0; n < 8; ++n){
      int col = n*16 + l15;
      float bia = b2f(bo[col]);
      #pragma unroll
      for (int r = 0; r < 4; ++r)
        acc[m][n][r] += bia + b2f(h0[(rowbase + quad*4 + r)*128 + col]);
    }
    float sm[4], sq[4];
    #pragma unroll
    for (int r = 0; r < 4; ++r){ sm[r] = 0.f; sq[r] = 0.f; }
    #pragma unroll
    for (int n = 0; n < 8; ++n)
      #pragma unroll
      for (int r = 0; r < 4; ++r){
        float v = acc[m][n][r];
        sm[r] += v; sq[r] += v*v;
      }
    #pragma unroll
    for (int mask = 1; mask < 16; mask <<= 1)
      #pragma unroll
      for (int r = 0; r < 4; ++r){
        sm[r] += __shfl_xor(sm[r], mask);
        sq[r] += __shfl_xor(sq[r], mask);
      }
    float mean[4], rs[4];
    #pragma unroll
    for (int r = 0; r < 4; ++r){
      mean[r] = sm[r]*(1.0f/128.0f);
      float var = fmaxf(sq[r]*(1.0f/128.0f) - mean[r]*mean[r], 0.0f);
      rs[r] = rsqrtf(var + 1e-5f);
    }
    #pragma unroll
    for (int n = 0; n < 8; ++n){
      int col = n*16 + l15;
      float gv = b2f(ga[col]), bv = b2f(ba_[col]);
      #pragma unroll
      for (int r = 0; r < 4; ++r){
        float y = (acc[m][n][r] - mean[r])*rs[r]*gv + bv;
        h1[(rowbase + quad*4 + r)*128 + col] = f2b(y);
      }
    }
  }
}

// ---------------------------------------------------------------------------
// K5: fused forward LSTM, MFMA, software-pipelined x-part.
// grid = 100 (16 samples/block), block = 512 (8 waves, 2/SIMD).
// accx (x_t @ Wih^T) is computed during step t-1, so the per-step serial
// chain is only: barrier -> ds_read h -> 4-deep h-MFMA chain -> act -> write.
// The 16 x-MFMAs for t+1 overlap with the activation VALU.
// ---------------------------------------------------------------------------
__global__ __launch_bounds__(512,1) void k_lstm(const bf16* __restrict__ Whh,
    const bf16* __restrict__ Wih, const bf16* __restrict__ bih,
    const bf16* __restrict__ bhh, const bf16* __restrict__ h1,
    float* __restrict__ y_f){
  int bn0 = blockIdx.x * 16;
  int tid = threadIdx.x;
  int w = tid >> 6, lane = tid & 63;
  int l15 = lane & 15, quad = lane >> 4;
  __shared__ __align__(16) short hbuf[2][16*136];
  __shared__ __align__(16) short xbuf[2][16*136];

  // B fragments: [role][ktile], gate col G = role*128 + w*16 + l15
  bf8v whh[4][4], wih[4][4];
  float bias[4];
  #pragma unroll
  for (int role = 0; role < 4; ++role){
    int G = role*128 + w*16 + l15;
    #pragma unroll
    for (int kt = 0; kt < 4; ++kt){
      whh[role][kt] = *reinterpret_cast<const bf8v*>(Whh + G*128 + kt*32 + quad*8);
      wih[role][kt] = *reinterpret_cast<const bf8v*>(Wih + G*128 + kt*32 + quad*8);
    }
    bias[role] = b2f(bih[G]) + b2f(bhh[G]);
  }
  const uint4* h1u4 = (const uint4*)h1;
  int srow = tid >> 4, scol = tid & 15;   // staging coords (tid < 256)

  // zero h state, stage x_0
  for (int i = tid; i < 16*136; i += 512) hbuf[0][i] = 0;
  if (tid < 256)
    ((uint4*)xbuf[0])[srow*17 + scol] = h1u4[((bn0 + srow)*96 + 0)*16 + scol];
  f4v c0 = {0.f,0.f,0.f,0.f};
  uint4 xpre;
  if (tid < 256) xpre = h1u4[((bn0 + srow)*96 + 1)*16 + scol];   // x_1
  __syncthreads();

  // accx for t = 0
  f4v accx[4];
  {
    bf8v ax[4];
    #pragma unroll
    for (int kt = 0; kt < 4; ++kt)
      ax[kt] = *reinterpret_cast<const bf8v*>(xbuf[0] + l15*136 + kt*32 + quad*8);
    #pragma unroll
    for (int role = 0; role < 4; ++role){
      f4v z = {0.f,0.f,0.f,0.f};
      #pragma unroll
      for (int kt = 0; kt < 4; ++kt) z = mfma16(ax[kt], wih[role][kt], z);
      accx[role] = z;
    }
  }
  if (tid < 256) ((uint4*)xbuf[1])[srow*17 + scol] = xpre;       // x_1 -> buf
  if (tid < 256) xpre = h1u4[((bn0 + srow)*96 + 2)*16 + scol];   // x_2
  __syncthreads();

  for (int t = 0; t < 96; ++t){
    int cur = t & 1, nxt = cur ^ 1;
    // A fragments: h_{t-1} (chain) and x_{t+1} (pipeline)
    bf8v ah[4], axn[4];
    #pragma unroll
    for (int kt = 0; kt < 4; ++kt){
      ah[kt]  = *reinterpret_cast<const bf8v*>(hbuf[cur] + l15*136 + kt*32 + quad*8);
      axn[kt] = *reinterpret_cast<const bf8v*>(xbuf[nxt] + l15*136 + kt*32 + quad*8);
    }
    // gates = accx + h@Whh^T   (critical chain: 4-deep per role)
    f4v acc[4];
    #pragma unroll
    for (int role = 0; role < 4; ++role){
      f4v z = accx[role];
      #pragma unroll
      for (int kt = 0; kt < 4; ++kt) z = mfma16(ah[kt], whh[role][kt], z);
      acc[role] = z;
    }
    // x-part for t+1 (independent of activation; overlaps VALU)
    #pragma unroll
    for (int role = 0; role < 4; ++role){
      f4v z = {0.f,0.f,0.f,0.f};
      #pragma unroll
      for (int kt = 0; kt < 4; ++kt) z = mfma16(axn[kt], wih[role][kt], z);
      accx[role] = z;
    }
    // activation (wave-local)
    float hreg[4];
    #pragma unroll
    for (int r = 0; r < 4; ++r){
      float i_ = acc[0][r] + bias[0];
      float f_ = acc[1][r] + bias[1];
      float g_ = acc[2][r] + bias[2];
      float o_ = acc[3][r] + bias[3];
      float c  = sigf(f_)*c0[r] + sigf(i_)*tanhfast(g_);
      hreg[r]  = sigf(o_)*tanhfast(c);
      c0[r] = c;
    }
    #pragma unroll
    for (int r = 0; r < 4; ++r)
      hbuf[nxt][(quad*4 + r)*136 + w*16 + l15] = f2bs(hreg[r]);
    // store x_{t+2} into xbuf[cur] (x_t is dead); load x_{t+3}
    if (tid < 256){
      ((uint4*)xbuf[cur])[srow*17 + scol] = xpre;
      int tl = (t + 3 < 96) ? t + 3 : 95;
      xpre = h1u4[((bn0 + srow)*96 + tl)*16 + scol];
    }
    __syncthreads();
  }
  // h_95 ended in hbuf[0] (96 even)
  for (int idx = tid; idx < 2048; idx += 512){
    int r = idx >> 7, d = idx & 127;
    y_f[(bn0 + r)*128 + d] = s2f(hbuf[0][r*136 + d]);
  }
}

// ---------------------------------------------------------------------------
// K6: backward LSTM (single step at t=T-1, zero state) + temporal proj Wtp.
// ---------------------------------------------------------------------------
__global__ void k_bwdtp(const bf16* __restrict__ h1, const bf16* __restrict__ Wihb,
                        const bf16* __restrict__ bihb, const bf16* __restrict__ bhhb,
                        const float* __restrict__ y_f, const bf16* __restrict__ Wtp,
                        const bf16* __restrict__ btp, float* __restrict__ ht,
                        const int* __restrict__ flag, bf16* __restrict__ outb,
                        float* __restrict__ outf){
  int bn = blockIdx.x, tid = threadIdx.x;
  __shared__ __align__(16) float xr[128];
  __shared__ float gates[512];
  __shared__ __align__(16) float ycat[256];
  xr[tid] = b2f(h1[(bn*96 + 95)*128 + tid]);
  __syncthreads();
  const float2* xf2 = (const float2*)xr;
  for (int g = tid; g < 512; g += 128){
    const unsigned int* w = (const unsigned int*)(Wihb + g*128);
    float s = b2f(bihb[g]) + b2f(bhhb[g]);
    #pragma unroll 8
    for (int kp = 0; kp < 64; ++kp){
      float2 a = xf2[kp]; unsigned int u = w[kp];
      s += a.x*blo(u) + a.y*bhi(u);
    }
    gates[g] = s;
  }
  __syncthreads();
  float ii = gates[tid], gg = gates[256 + tid], oo = gates[384 + tid];
  float c  = sigf(ii)*tanhfast(gg);
  float yb = sigf(oo)*tanhfast(c);
  ycat[tid]       = y_f[bn*128 + tid];
  ycat[128 + tid] = yb;
  __syncthreads();
  const float2* yf2 = (const float2*)ycat;
  const unsigned int* w = (const unsigned int*)(Wtp + tid*256);
  float s = b2f(btp[tid]);
  #pragma unroll 8
  for (int kp = 0; kp < 128; ++kp){
    float2 a = yf2[kp]; unsigned int u = w[kp];
    s += a.x*blo(u) + a.y*bhi(u);
  }
  ht[bn*128 + tid] = s;
  int oi = 206400 + bn*128 + tid;
  if (flag[0]) outb[oi] = f2b(s); else outf[oi] = s;
}

// ---------------------------------------------------------------------------
// K7: npj = h_temporal @ Wn.T + bn
// ---------------------------------------------------------------------------
__global__ void k_npj(const float* __restrict__ ht, const bf16* __restrict__ Wn,
                      const bf16* __restrict__ bn_, float* __restrict__ npj){
  int bn = blockIdx.x, tid = threadIdx.x;
  __shared__ __align__(16) float row[128];
  row[tid] = ht[bn*128 + tid];
  __syncthreads();
  const float2* rf2 = (const float2*)row;
  const unsigned int* w = (const unsigned int*)(Wn + tid*128);
  float s = b2f(bn_[tid]);
  #pragma unroll 8
  for (int kp = 0; kp < 64; ++kp){
    float2 a = rf2[kp]; unsigned int u = w[kp];
    s += a.x*blo(u) + a.y*bhi(u);
  }
  npj[bn*128 + tid] = s;
}

// ---------------------------------------------------------------------------
// K8: hyperedge features + attention logits.  grid = B*E = 256, block = 128
// ---------------------------------------------------------------------------
__global__ void k_edge(const float* __restrict__ npj, const bf16* __restrict__ Hinc,
                       const bf16* __restrict__ We, const bf16* __restrict__ be,
                       const bf16* __restrict__ Wa, const bf16* __restrict__ ba,
                       float* __restrict__ ee, float* __restrict__ scE){
  int b = blockIdx.x >> 4, e = blockIdx.x & 15, tid = threadIdx.x;
  float acc = 0.0f, deg = 0.0f;
  for (int n = 0; n < 100; ++n){
    float w = b2f(Hinc[n*16 + e]);
    deg += w;
    acc += w * npj[(b*100 + n)*128 + tid];
  }
  __shared__ __align__(16) float eep[128];
  eep[tid] = acc/(deg + 1e-8f);
  __syncthreads();
  const float2* ef2 = (const float2*)eep;
  const unsigned int* w = (const unsigned int*)(We + tid*128);
  float s = b2f(be[tid]);
  #pragma unroll 8
  for (int kp = 0; kp < 64; ++kp){
    float2 a = ef2[kp]; unsigned int u = w[kp];
    s += a.x*blo(u) + a.y*bhi(u);
  }
  ee[(b*16 + e)*128 + tid] = s;
  float p = s * b2f(Wa[tid]);
  #pragma unroll
  for (int off = 32; off; off >>= 1) p += __shfl_down(p, off);
  __shared__ float r2[2];
  if ((tid & 63) == 0) r2[tid>>6] = p;
  __syncthreads();
  if (tid == 0) scE[b*16 + e] = r2[0] + r2[1] + b2f(ba[0]);
}

// ---------------------------------------------------------------------------
// K9: per-node segment softmax over edges + aggregate + residual + LN
// ---------------------------------------------------------------------------
__global__ void k_node(const float* __restrict__ ht, const float* __restrict__ ee,
                       const float* __restrict__ scE, const bf16* __restrict__ Hinc,
                       const bf16* __restrict__ gg_, const bf16* __restrict__ bg_,
                       float* __restrict__ hb2){
  int blk = blockIdx.x; int b = blk/100, n = blk%100; int tid = threadIdx.x;
  __shared__ float wts[16];
  __shared__ float red[4];
  if (tid == 0){
    float sc[16]; float mx = -1e30f;
    for (int e = 0; e < 16; ++e){
      float m_ = b2f(Hinc[n*16 + e]);
      sc[e] = (m_ > 0.0f) ? scE[b*16 + e] : -1e30f;
      mx = fmaxf(mx, sc[e]);
    }
    float tmp[16]; float sum = 0.0f;
    for (int e = 0; e < 16; ++e){
      tmp[e] = (sc[e] > -1e29f) ? __expf(sc[e] - mx) : 0.0f;
      sum += tmp[e];
    }
    float inv = (sum > 0.0f) ? 1.0f/sum : 0.0f;
    for (int e = 0; e < 16; ++e) wts[e] = tmp[e]*inv;
  }
  __syncthreads();
  float s = ht[(b*100 + n)*128 + tid];
  for (int e = 0; e < 16; ++e) s += wts[e] * ee[(b*16 + e)*128 + tid];
  float y = ln128(s, tid, gg_, bg_, red);
  hb2[(b*100 + n)*128 + tid] = y;
}

// ---------------------------------------------------------------------------
// K10: GCN pass + region embedding; writes h_spatial
// ---------------------------------------------------------------------------
__global__ void k_gcn(const float* __restrict__ hb2, const bf16* __restrict__ An,
                      const bf16* __restrict__ Wg, const bf16* __restrict__ bg_,
                      const bf16* __restrict__ Remb, const int* __restrict__ mem,
                      float* __restrict__ hsp, const int* __restrict__ flag,
                      bf16* __restrict__ outb, float* __restrict__ outf){
  int blk = blockIdx.x; int b = blk/100, n = blk%100; int tid = threadIdx.x;
  float acc = 0.0f;
  for (int m = 0; m < 100; ++m){
    float a = b2f(An[n*100 + m]);
    acc += a * hb2[(b*100 + m)*128 + tid];
  }
  __shared__ __align__(16) float as_[128];
  as_[tid] = acc;
  __syncthreads();
  const float2* af2 = (const float2*)as_;
  const unsigned int* w = (const unsigned int*)(Wg + tid*128);
  float s = b2f(bg_[tid]);
  #pragma unroll 8
  for (int kp = 0; kp < 64; ++kp){
    float2 a = af2[kp]; unsigned int u = w[kp];
    s += a.x*blo(u) + a.y*bhi(u);
  }
  s = fmaxf(s, 0.0f);
  float out = hb2[(b*100 + n)*128 + tid] + s + b2f(Remb[mem[n]*128 + tid]);
  hsp[(b*100 + n)*128 + tid] = out;
  int oi = 1600 + (b*100 + n)*128 + tid;
  if (flag[0]) outb[oi] = f2b(out); else outf[oi] = out;
}

// ---------------------------------------------------------------------------
// K11: fusion + LN + relu + MLP head -> pred.  grid = 1600, block = 128
// ---------------------------------------------------------------------------
__global__ void k_fuse(const float* __restrict__ ht, const float* __restrict__ hsp,
                       const bf16* __restrict__ Wf, const bf16* __restrict__ bf_,
                       const bf16* __restrict__ gf, const bf16* __restrict__ b_f,
                       const bf16* __restrict__ W1, const bf16* __restrict__ b1,
                       const bf16* __restrict__ W2, const bf16* __restrict__ b2,
                       const int* __restrict__ flag, bf16* __restrict__ outb,
                       float* __restrict__ outf){
  int bn = blockIdx.x, tid = threadIdx.x;
  __shared__ __align__(16) float cat[256];
  __shared__ __align__(16) float hf[128];
  __shared__ float red[4];
  cat[tid]       = ht[bn*128 + tid];
  cat[128 + tid] = hsp[bn*128 + tid];
  __syncthreads();
  const float2* cf2 = (const float2*)cat;
  const unsigned int* w = (const unsigned int*)(Wf + tid*256);
  float s = b2f(bf_[tid]);
  #pragma unroll 8
  for (int kp = 0; kp < 128; ++kp){
    float2 a = cf2[kp]; unsigned int u = w[kp];
    s += a.x*blo(u) + a.y*bhi(u);
  }
  float y = fmaxf(ln128(s, tid, gf, b_f, red), 0.0f);
  hf[tid] = y;
  __syncthreads();
  if (tid < 64){
    const float2* hf2 = (const float2*)hf;
    const unsigned int* w1 = (const unsigned int*)(W1 + tid*128);
    float z = b2f(b1[tid]);
    #pragma unroll 8
    for (int kp = 0; kp < 64; ++kp){
      float2 a = hf2[kp]; unsigned int u = w1[kp];
      z += a.x*blo(u) + a.y*bhi(u);
    }
    z = fmaxf(z, 0.0f);
    float p = z * b2f(W2[tid]);
    #pragma unroll
    for (int off = 32; off; off >>= 1) p += __shfl_down(p, off);
    if (tid == 0){
      float pr = p + b2f(b2[0]);
      if (flag[0]) outb[bn] = f2b(pr); else outf[bn] = pr;
    }
  }
}

// ---------------------------------------------------------------------------

extern "C" void kernel_launch(void* const* d_in, const int* in_sizes, int n_in,
                              void* d_out, int out_size, void* d_ws, size_t ws_size,
                              hipStream_t stream){
  (void)n_in; (void)out_size; (void)ws_size;
  const int* mem = (const int*)d_in[3];

  CArgs ca;
  int coff[43];
  int nf = 0;
  long long off = 0;
  for (int i = 0; i < 43; ++i){
    if (i == 3){ coff[i] = -1; continue; }
    coff[i] = (int)off;
    ca.src[nf] = d_in[i];
    ca.n[nf]   = in_sizes[i];
    ca.off[nf] = (int)off;
    ++nf;
    off += (long long)((in_sizes[i] + 7) & ~7);
  }
  char* ws = (char*)d_ws;
  bf16* canon = (bf16*)ws;
  long long canonBytes = ((off*2 + 255)/256)*256;
  int* flag = (int*)(ws + canonBytes);
  long long base = canonBytes + 256;

  #define C(i) (canon + coff[i])
  const bf16* A_norm = C(1);
  const bf16* Hinc   = C(2);
  const bf16* Wp  = C(4);  const bf16* bp  = C(5);
  const bf16* g_p = C(6);  const bf16* b_p = C(7);
  const bf16* Wqkv= C(8);  const bf16* bqkv= C(9);
  const bf16* Wo  = C(10); const bf16* bo  = C(11);
  const bf16* g_a = C(12); const bf16* b_a = C(13);
  const bf16* Wih_f = C(14); const bf16* Whh_f = C(15);
  const bf16* bih_f = C(16); const bf16* bhh_f = C(17);
  const bf16* Wih_b = C(18);
  const bf16* bih_b = C(20); const bf16* bhh_b = C(21);
  const bf16* Wtp = C(22); const bf16* btp = C(23);
  const bf16* Wn  = C(24); const bf16* bn_ = C(25);
  const bf16* We  = C(26); const bf16* be  = C(27);
  const bf16* Wa  = C(28); const bf16* ba  = C(29);
  const bf16* g_g = C(30); const bf16* b_g = C(31);
  const bf16* Remb= C(32);
  const bf16* Wg  = C(33); const bf16* bg  = C(34);
  const bf16* Wf  = C(35); const bf16* bff = C(36);
  const bf16* g_f = C(37); const bf16* b_f = C(38);
  const bf16* W1  = C(39); const bf16* b1  = C(40);
  const bf16* W2  = C(41); const bf16* b2  = C(42);
  const bf16* xc  = C(0);
  #undef C

  bf16*  outb = (bf16*)d_out;
  float* outf = (float*)d_out;
  bf16*  h1    = (bf16*)(ws + base);
  bf16*  h0    = (bf16*)(ws + base + 39321600LL);
  bf16*  attno = (bf16*)(ws + base + 78643200LL);
  float* y_f   = (float*)(ws + base + 196608000LL);
  float* htb   = (float*)(ws + base + 197427200LL);
  float* npj   = (float*)(ws + base + 198246400LL);
  float* ee    = (float*)(ws + base + 199065600LL);
  float* scE   = (float*)(ws + base + 199196672LL);
  float* hb2   = (float*)(ws + base + 199197696LL);
  float* hsp   = (float*)(ws + base + 200016896LL);

  k_detect<<<1, 256, 0, stream>>>((const unsigned int*)d_in[0], flag);
  k_canon <<<dim3(64, nf), 256, 0, stream>>>(ca, flag, canon);
  k_inproj<<<19200, 128, 0, stream>>>(xc, Wp, bp, g_p, b_p, h0);
  k_attn  <<<1600,  256, 0, stream>>>(h0, Wqkv, bqkv, attno);
  k_oproj <<<1200,  256, 0, stream>>>(attno, h0, Wo, bo, g_a, b_a, h1);
  k_lstm  <<<100,   512, 0, stream>>>(Whh_f, Wih_f, bih_f, bhh_f, h1, y_f);
  k_bwdtp <<<1600,  128, 0, stream>>>(h1, Wih_b, bih_b, bhh_b, y_f, Wtp, btp, htb,
                                      flag, outb, outf);
  k_npj   <<<1600,  128, 0, stream>>>(htb, Wn, bn_, npj);
  k_edge  <<<256,   128, 0, stream>>>(npj, Hinc, We, be, Wa, ba, ee, scE);
  k_node  <<<1600,  128, 0, stream>>>(htb, ee, scE, Hinc, g_g, b_g, hb2);
  k_gcn   <<<1600,  128, 0, stream>>>(hb2, A_norm, Wg, bg, Remb, mem, hsp,
                                      flag, outb, outf);
  k_fuse  <<<1600,  128, 0, stream>>>(htb, hsp, Wf, bff, g_f, b_f, W1, b1, W2, b2,
                                      flag, outb, outf);
}

// Round 10
// 514.703 us; speedup vs baseline: 7.7843x; 1.1158x over previous
//
#include <hip/hip_runtime.h>
#include <hip/hip_bf16.h>

typedef __hip_bfloat16 bf16;
typedef __attribute__((ext_vector_type(8))) short bf8v;   // 8 bf16 (4 VGPRs)
typedef __attribute__((ext_vector_type(4))) short s4v;
typedef __attribute__((ext_vector_type(4))) float f4v;

#define DEV __device__ __forceinline__

DEV float b2f(bf16 v){ return __bfloat162float(v); }
DEV bf16 f2b(float v){ return __float2bfloat16(v); }
DEV short f2bs(float v){ bf16 t = __float2bfloat16(v); return *reinterpret_cast<short*>(&t); }
DEV float s2f(short s){ return __uint_as_float(((unsigned int)(unsigned short)s) << 16); }
DEV float rcpf_(float x){ return __builtin_amdgcn_rcpf(x); }
DEV float sigf(float x){ return rcpf_(1.0f + __expf(-x)); }
DEV float tanhfast(float x){
  x = fminf(fmaxf(x, -15.0f), 15.0f);
  float e = __expf(-2.0f*x);
  return (1.0f - e)*rcpf_(1.0f + e);
}

DEV f4v mfma16(bf8v a, bf8v b, f4v c){
  return __builtin_amdgcn_mfma_f32_16x16x32_bf16(a, b, c, 0, 0, 0);
}

// ---------------------------------------------------------------------------
// K0a: dtype detector (fp32 vs bf16 inputs). flag[0]=1 -> bf16, 0 -> fp32.
// ---------------------------------------------------------------------------
__global__ void k_detect(const unsigned int* __restrict__ xw, int* __restrict__ flag){
  __shared__ int found;
  if (threadIdx.x == 0) found = 0;
  __syncthreads();
  int local = 0;
  for (int i = threadIdx.x; i < 4096; i += 256){
    unsigned int u = xw[i];
    unsigned int e = (u >> 7) & 0xFF;
    if (e >= 0x90) local = 1;
  }
  if (local) atomicOr(&found, 1);
  __syncthreads();
  if (threadIdx.x == 0) flag[0] = found ? 0 : 1;
}

// ---------------------------------------------------------------------------
// K0b: canonicalize all float inputs into a bf16 region in ws.
// ---------------------------------------------------------------------------
struct CArgs {
  const void* src[44];
  int n[44];
  int off[44];
};

__global__ void k_canon(CArgs a, const int* __restrict__ flag, bf16* __restrict__ dst){
  int id = blockIdx.y;
  int n = a.n[id];
  const void* s = a.src[id];
  bf16* d = dst + a.off[id];
  int stride = gridDim.x * blockDim.x;
  int i0 = blockIdx.x * blockDim.x + threadIdx.x;
  if (flag[0]){
    const bf16* sb = (const bf16*)s;
    for (int i = i0; i < n; i += stride) d[i] = sb[i];
  } else {
    const float* sf = (const float*)s;
    for (int i = i0; i < n; i += stride) d[i] = f2b(sf[i]);
  }
}

// ---------------------------------------------------------------------------
// K0c: prep padded operands: Wp->Wpp (128x32), A_norm->Anp (112x128),
// zero ht_pad (16x112x128) and hb2_pad (16x112x128).
// ---------------------------------------------------------------------------
__global__ void k_prep(const bf16* __restrict__ Wp, const bf16* __restrict__ An,
                       bf16* __restrict__ Wpp, bf16* __restrict__ Anp,
                       bf16* __restrict__ htp, bf16* __restrict__ hb2p){
  int stride = gridDim.x * blockDim.x;
  bf16 zero = f2b(0.0f);
  for (int i = blockIdx.x*blockDim.x + threadIdx.x; i < 477184; i += stride){
    if (i < 4096){
      int row = i >> 5, col = i & 31;
      Wpp[i] = (col < 26) ? Wp[row*26 + col] : zero;
    } else if (i < 18432){
      int j = i - 4096;
      int row = j >> 7, col = j & 127;
      Anp[j] = (row < 100 && col < 100) ? An[row*100 + col] : zero;
    } else if (i < 247808){
      htp[i - 18432] = zero;
    } else {
      hb2p[i - 247808] = zero;
    }
  }
}

// ---------------------------------------------------------------------------
// K1: input projection + LN + relu, MFMA (K=32 padded). grid=1200, block=256.
// ---------------------------------------------------------------------------
__global__ __launch_bounds__(256) void k_inproj(const bf16* __restrict__ x,
    const bf16* __restrict__ Wpp, const bf16* __restrict__ bp,
    const bf16* __restrict__ gp, const bf16* __restrict__ bbp,
    bf16* __restrict__ h0){
  int blk = blockIdx.x, tid = threadIdx.x;
  int w = tid >> 6, lane = tid & 63, l15 = lane & 15, quad = lane >> 4;
  __shared__ __align__(16) short flat[3328];
  __shared__ __align__(16) short xt[128*40];
  {
    const uint4* src = (const uint4*)(x + blk*3328);
    uint4* dst = (uint4*)flat;
    for (int u = tid; u < 416; u += 256) dst[u] = src[u];
  }
  __syncthreads();
  for (int i = tid; i < 5120; i += 256){
    int row = i/40, col = i - row*40;
    xt[i] = (col < 26) ? flat[row*26 + col] : (short)0;
  }
  __syncthreads();
  int m0 = w*32;
  bf8v a[2];
  #pragma unroll
  for (int m = 0; m < 2; ++m)
    a[m] = *reinterpret_cast<const bf8v*>(xt + (m0 + m*16 + l15)*40 + quad*8);
  f4v acc[2][8];
  for (int n = 0; n < 8; ++n){
    bf8v bb = *reinterpret_cast<const bf8v*>(Wpp + (n*16 + l15)*32 + quad*8);
    #pragma unroll
    for (int m = 0; m < 2; ++m){
      f4v z = {0.f,0.f,0.f,0.f};
      acc[m][n] = mfma16(a[m], bb, z);
    }
  }
  #pragma unroll
  for (int m = 0; m < 2; ++m){
    int rowbase = blk*128 + m0 + m*16;
    float sm[4], sq[4];
    #pragma unroll
    for (int r = 0; r < 4; ++r){ sm[r] = 0.f; sq[r] = 0.f; }
    #pragma unroll
    for (int n = 0; n < 8; ++n){
      int col = n*16 + l15;
      float bv = b2f(bp[col]);
      #pragma unroll
      for (int r = 0; r < 4; ++r){
        float v = acc[m][n][r] + bv;
        acc[m][n][r] = v;
        sm[r] += v; sq[r] += v*v;
      }
    }
    #pragma unroll
    for (int mask = 1; mask < 16; mask <<= 1)
      #pragma unroll
      for (int r = 0; r < 4; ++r){
        sm[r] += __shfl_xor(sm[r], mask);
        sq[r] += __shfl_xor(sq[r], mask);
      }
    float mean[4], rs[4];
    #pragma unroll
    for (int r = 0; r < 4; ++r){
      mean[r] = sm[r]*(1.0f/128.0f);
      float var = fmaxf(sq[r]*(1.0f/128.0f) - mean[r]*mean[r], 0.0f);
      rs[r] = rsqrtf(var + 1e-5f);
    }
    #pragma unroll
    for (int n = 0; n < 8; ++n){
      int col = n*16 + l15;
      float gv = b2f(gp[col]), bv = b2f(bbp[col]);
      #pragma unroll
      for (int r = 0; r < 4; ++r){
        float y = fmaxf((acc[m][n][r] - mean[r])*rs[r]*gv + bv, 0.0f);
        h0[(rowbase + quad*4 + r)*128 + col] = f2b(y);
      }
    }
  }
}

// ---------------------------------------------------------------------------
// K2: attention, MFMA flash-style. grid = 1600, block = 256 (wave = head).
// ---------------------------------------------------------------------------
__global__ __launch_bounds__(256) void k_attn(const bf16* __restrict__ h0,
    const bf16* __restrict__ Wqkv, const bf16* __restrict__ bqkv,
    bf16* __restrict__ attno){
  int bn = blockIdx.x;
  int tid = threadIdx.x;
  int w = tid >> 6;
  int lane = tid & 63;
  int l15 = lane & 15, quad = lane >> 4;

  __shared__ __align__(16) short h0s[96*136];
  __shared__ __align__(16) short v_sh[4][32*104];
  __shared__ __align__(16) short scr[4][16*40];

  {
    const uint4* src = (const uint4*)(h0 + bn*12288);
    uint4* dst = (uint4*)h0s;
    for (int u = tid; u < 1536; u += 256){
      int r = u >> 4, c = u & 15;
      dst[r*17 + c] = src[u];
    }
  }
  __syncthreads();

  short* vp = v_sh[w];
  short* sw = scr[w];
  const float scl = 0.17677669529663687f;

  bf8v aq[6], bk[6];
  for (int m = 0; m < 6; ++m){
    bf8v a[4];
    #pragma unroll
    for (int kt = 0; kt < 4; ++kt)
      a[kt] = *reinterpret_cast<const bf8v*>(h0s + (m*16 + l15)*136 + kt*32 + quad*8);
    #pragma unroll
    for (int n0 = 0; n0 < 32; n0 += 16){
      int rq = w*32 + n0 + l15;
      bf8v b[4];
      #pragma unroll
      for (int kt = 0; kt < 4; ++kt)
        b[kt] = *reinterpret_cast<const bf8v*>(Wqkv + rq*128 + kt*32 + quad*8);
      float bias = b2f(bqkv[rq]);
      f4v acc = {0.f,0.f,0.f,0.f};
      #pragma unroll
      for (int kt = 0; kt < 4; ++kt) acc = mfma16(a[kt], b[kt], acc);
      #pragma unroll
      for (int r = 0; r < 4; ++r)
        sw[(quad*4 + r)*40 + n0 + l15] = f2bs((acc[r] + bias)*scl);
    }
    asm volatile("s_waitcnt lgkmcnt(0)" ::: "memory");
    aq[m] = *reinterpret_cast<const bf8v*>(sw + l15*40 + quad*8);
  }
  for (int m = 0; m < 6; ++m){
    bf8v a[4];
    #pragma unroll
    for (int kt = 0; kt < 4; ++kt)
      a[kt] = *reinterpret_cast<const bf8v*>(h0s + (m*16 + l15)*136 + kt*32 + quad*8);
    #pragma unroll
    for (int n0 = 0; n0 < 32; n0 += 16){
      int rq = 128 + w*32 + n0 + l15;
      bf8v b[4];
      #pragma unroll
      for (int kt = 0; kt < 4; ++kt)
        b[kt] = *reinterpret_cast<const bf8v*>(Wqkv + rq*128 + kt*32 + quad*8);
      float bias = b2f(bqkv[rq]);
      f4v acc = {0.f,0.f,0.f,0.f};
      #pragma unroll
      for (int kt = 0; kt < 4; ++kt) acc = mfma16(a[kt], b[kt], acc);
      #pragma unroll
      for (int r = 0; r < 4; ++r)
        sw[(quad*4 + r)*40 + n0 + l15] = f2bs(acc[r] + bias);
    }
    asm volatile("s_waitcnt lgkmcnt(0)" ::: "memory");
    bk[m] = *reinterpret_cast<const bf8v*>(sw + l15*40 + quad*8);
  }
  for (int m = 0; m < 6; ++m){
    bf8v a[4];
    #pragma unroll
    for (int kt = 0; kt < 4; ++kt)
      a[kt] = *reinterpret_cast<const bf8v*>(h0s + (m*16 + l15)*136 + kt*32 + quad*8);
    #pragma unroll
    for (int n0 = 0; n0 < 32; n0 += 16){
      int rq = 256 + w*32 + n0 + l15;
      bf8v b[4];
      #pragma unroll
      for (int kt = 0; kt < 4; ++kt)
        b[kt] = *reinterpret_cast<const bf8v*>(Wqkv + rq*128 + kt*32 + quad*8);
      float bias = b2f(bqkv[rq]);
      f4v acc = {0.f,0.f,0.f,0.f};
      #pragma unroll
      for (int kt = 0; kt < 4; ++kt) acc = mfma16(a[kt], b[kt], acc);
      s4v vs;
      #pragma unroll
      for (int r = 0; r < 4; ++r) vs[r] = f2bs(acc[r] + bias);
      *reinterpret_cast<s4v*>(vp + (n0 + l15)*104 + m*16 + quad*4) = vs;
    }
  }
  __syncthreads();

  short* pp = h0s + w*1664;

  for (int m = 0; m < 6; ++m){
    f4v s[6];
    #pragma unroll
    for (int n = 0; n < 6; ++n){
      f4v z = {0.f,0.f,0.f,0.f};
      s[n] = mfma16(aq[m], bk[n], z);
    }
    float mr[4], sr[4];
    #pragma unroll
    for (int r = 0; r < 4; ++r){
      float m0 = fmaxf(fmaxf(s[0][r], s[1][r]), fmaxf(s[2][r], s[3][r]));
      mr[r] = fmaxf(m0, fmaxf(s[4][r], s[5][r]));
    }
    #pragma unroll
    for (int mask = 1; mask < 16; mask <<= 1)
      #pragma unroll
      for (int r = 0; r < 4; ++r) mr[r] = fmaxf(mr[r], __shfl_xor(mr[r], mask));
    #pragma unroll
    for (int r = 0; r < 4; ++r) sr[r] = 0.0f;
    #pragma unroll
    for (int n = 0; n < 6; ++n)
      #pragma unroll
      for (int r = 0; r < 4; ++r){
        float p = __expf(s[n][r] - mr[r]);
        s[n][r] = p;
        sr[r] += p;
      }
    #pragma unroll
    for (int mask = 1; mask < 16; mask <<= 1)
      #pragma unroll
      for (int r = 0; r < 4; ++r) sr[r] += __shfl_xor(sr[r], mask);
    #pragma unroll
    for (int n = 0; n < 6; ++n)
      #pragma unroll
      for (int r = 0; r < 4; ++r)
        pp[(quad*4 + r)*104 + n*16 + l15] = f2bs(s[n][r]);
    asm volatile("s_waitcnt lgkmcnt(0)" ::: "memory");
    f4v o0 = {0.f,0.f,0.f,0.f}, o1 = {0.f,0.f,0.f,0.f};
    #pragma unroll
    for (int ksi = 0; ksi < 3; ++ksi){
      bf8v ap  = *reinterpret_cast<const bf8v*>(pp + l15*104 + ksi*32 + quad*8);
      bf8v bv0 = *reinterpret_cast<const bf8v*>(vp + l15*104 + ksi*32 + quad*8);
      bf8v bv1 = *reinterpret_cast<const bf8v*>(vp + (16 + l15)*104 + ksi*32 + quad*8);
      o0 = mfma16(ap, bv0, o0);
      o1 = mfma16(ap, bv1, o1);
    }
    #pragma unroll
    for (int r = 0; r < 4; ++r){
      float inv = 1.0f/sr[r];
      int row = bn*96 + m*16 + quad*4 + r;
      attno[row*128 + w*32 + l15]      = f2b(o0[r]*inv);
      attno[row*128 + w*32 + 16 + l15] = f2b(o1[r]*inv);
    }
  }
}

// ---------------------------------------------------------------------------
// K3: out-proj + residual + LN, MFMA. grid = 1200, block = 256.
// ---------------------------------------------------------------------------
__global__ __launch_bounds__(256) void k_oproj(const bf16* __restrict__ attno,
    const bf16* __restrict__ h0, const bf16* __restrict__ Wo,
    const bf16* __restrict__ bo, const bf16* __restrict__ ga,
    const bf16* __restrict__ ba_, bf16* __restrict__ h1){
  int rt = blockIdx.x;
  int tid = threadIdx.x;
  int w = tid >> 6, lane = tid & 63;
  int l15 = lane & 15, quad = lane >> 4;
  __shared__ __align__(16) short atile[128*136];
  {
    const uint4* src = (const uint4*)(attno + rt*16384);
    uint4* dst = (uint4*)atile;
    for (int u = tid; u < 2048; u += 256){
      int r = u >> 4, c = u & 15;
      dst[r*17 + c] = src[u];
    }
  }
  __syncthreads();
  int m0 = w*32;
  bf8v a[2][4];
  #pragma unroll
  for (int m = 0; m < 2; ++m)
    #pragma unroll
    for (int ksi = 0; ksi < 4; ++ksi)
      a[m][ksi] = *reinterpret_cast<const bf8v*>(atile + (m0 + m*16 + l15)*136 + ksi*32 + quad*8);
  f4v acc[2][8];
  #pragma unroll
  for (int m = 0; m < 2; ++m)
    #pragma unroll
    for (int n = 0; n < 8; ++n) acc[m][n] = (f4v){0.f,0.f,0.f,0.f};
  for (int n = 0; n < 8; ++n){
    int G = n*16 + l15;
    bf8v b[4];
    #pragma unroll
    for (int ksi = 0; ksi < 4; ++ksi)
      b[ksi] = *reinterpret_cast<const bf8v*>(Wo + G*128 + ksi*32 + quad*8);
    #pragma unroll
    for (int m = 0; m < 2; ++m)
      #pragma unroll
      for (int ksi = 0; ksi < 4; ++ksi)
        acc[m][n] = mfma16(a[m][ksi], b[ksi], acc[m][n]);
  }
  #pragma unroll
  for (int m = 0; m < 2; ++m){
    int rowbase = rt*128 + m0 + m*16;
    #pragma unroll
    for (int n = 0; n < 8; ++n){
      int col = n*16 + l15;
      float bia = b2f(bo[col]);
      #pragma unroll
      for (int r = 0; r < 4; ++r)
        acc[m][n][r] += bia + b2f(h0[(rowbase + quad*4 + r)*128 + col]);
    }
    float sm[4], sq[4];
    #pragma unroll
    for (int r = 0; r < 4; ++r){ sm[r] = 0.f; sq[r] = 0.f; }
    #pragma unroll
    for (int n = 0; n < 8; ++n)
      #pragma unroll
      for (int r = 0; r < 4; ++r){
        float v = acc[m][n][r];
        sm[r] += v; sq[r] += v*v;
      }
    #pragma unroll
    for (int mask = 1; mask < 16; mask <<= 1)
      #pragma unroll
      for (int r = 0; r < 4; ++r){
        sm[r] += __shfl_xor(sm[r], mask);
        sq[r] += __shfl_xor(sq[r], mask);
      }
    float mean[4], rs[4];
    #pragma unroll
    for (int r = 0; r < 4; ++r){
      mean[r] = sm[r]*(1.0f/128.0f);
      float var = fmaxf(sq[r]*(1.0f/128.0f) - mean[r]*mean[r], 0.0f);
      rs[r] = rsqrtf(var + 1e-5f);
    }
    #pragma unroll
    for (int n = 0; n < 8; ++n){
      int col = n*16 + l15;
      float gv = b2f(ga[col]), bv = b2f(ba_[col]);
      #pragma unroll
      for (int r = 0; r < 4; ++r){
        float y = (acc[m][n][r] - mean[r])*rs[r]*gv + bv;
        h1[(rowbase + quad*4 + r)*128 + col] = f2b(y);
      }
    }
  }
}

// ---------------------------------------------------------------------------
// K5: fused forward LSTM + backward single-step + temporal projection.
// grid = 100 (16 samples/block), block = 512 (8 waves).
// ---------------------------------------------------------------------------
__global__ __launch_bounds__(512,1) void k_lstm(const bf16* __restrict__ Whh,
    const bf16* __restrict__ Wih, const bf16* __restrict__ bih,
    const bf16* __restrict__ bhh, const bf16* __restrict__ h1,
    const bf16* __restrict__ Wihb, const bf16* __restrict__ bihb,
    const bf16* __restrict__ bhhb, const bf16* __restrict__ Wtp,
    const bf16* __restrict__ btp, bf16* __restrict__ ht_pad,
    const int* __restrict__ flag, bf16* __restrict__ outb,
    float* __restrict__ outf){
  int bn0 = blockIdx.x * 16;
  int tid = threadIdx.x;
  int w = tid >> 6, lane = tid & 63;
  int l15 = lane & 15, quad = lane >> 4;
  __shared__ __align__(16) short hbuf[2][16*136];
  __shared__ __align__(16) short xbuf[2][16*136];
  __shared__ __align__(16) short ycat[16*264];

  bf8v whh[4][4], wih[4][4];
  float bias[4];
  #pragma unroll
  for (int role = 0; role < 4; ++role){
    int G = role*128 + w*16 + l15;
    #pragma unroll
    for (int kt = 0; kt < 4; ++kt){
      whh[role][kt] = *reinterpret_cast<const bf8v*>(Whh + G*128 + kt*32 + quad*8);
      wih[role][kt] = *reinterpret_cast<const bf8v*>(Wih + G*128 + kt*32 + quad*8);
    }
    bias[role] = b2f(bih[G]) + b2f(bhh[G]);
  }
  const uint4* h1u4 = (const uint4*)h1;
  int srow = tid >> 4, scol = tid & 15;

  for (int i = tid; i < 16*136; i += 512) hbuf[0][i] = 0;
  if (tid < 256)
    ((uint4*)xbuf[0])[srow*17 + scol] = h1u4[((bn0 + srow)*96 + 0)*16 + scol];
  f4v c0 = {0.f,0.f,0.f,0.f};
  uint4 xpre;
  if (tid < 256) xpre = h1u4[((bn0 + srow)*96 + 1)*16 + scol];
  __syncthreads();

  f4v accx[4];
  {
    bf8v ax[4];
    #pragma unroll
    for (int kt = 0; kt < 4; ++kt)
      ax[kt] = *reinterpret_cast<const bf8v*>(xbuf[0] + l15*136 + kt*32 + quad*8);
    #pragma unroll
    for (int role = 0; role < 4; ++role){
      f4v z = {0.f,0.f,0.f,0.f};
      #pragma unroll
      for (int kt = 0; kt < 4; ++kt) z = mfma16(ax[kt], wih[role][kt], z);
      accx[role] = z;
    }
  }
  if (tid < 256) ((uint4*)xbuf[1])[srow*17 + scol] = xpre;
  if (tid < 256) xpre = h1u4[((bn0 + srow)*96 + 2)*16 + scol];
  __syncthreads();

  for (int t = 0; t < 96; ++t){
    int cur = t & 1, nxt = cur ^ 1;
    bf8v ah[4], axn[4];
    #pragma unroll
    for (int kt = 0; kt < 4; ++kt){
      ah[kt]  = *reinterpret_cast<const bf8v*>(hbuf[cur] + l15*136 + kt*32 + quad*8);
      axn[kt] = *reinterpret_cast<const bf8v*>(xbuf[nxt] + l15*136 + kt*32 + quad*8);
    }
    f4v acc[4];
    #pragma unroll
    for (int role = 0; role < 4; ++role){
      f4v z = accx[role];
      #pragma unroll
      for (int kt = 0; kt < 4; ++kt) z = mfma16(ah[kt], whh[role][kt], z);
      acc[role] = z;
    }
    #pragma unroll
    for (int role = 0; role < 4; ++role){
      f4v z = {0.f,0.f,0.f,0.f};
      #pragma unroll
      for (int kt = 0; kt < 4; ++kt) z = mfma16(axn[kt], wih[role][kt], z);
      accx[role] = z;
    }
    float hreg[4];
    #pragma unroll
    for (int r = 0; r < 4; ++r){
      float i_ = acc[0][r] + bias[0];
      float f_ = acc[1][r] + bias[1];
      float g_ = acc[2][r] + bias[2];
      float o_ = acc[3][r] + bias[3];
      float c  = sigf(f_)*c0[r] + sigf(i_)*tanhfast(g_);
      hreg[r]  = sigf(o_)*tanhfast(c);
      c0[r] = c;
    }
    #pragma unroll
    for (int r = 0; r < 4; ++r)
      hbuf[nxt][(quad*4 + r)*136 + w*16 + l15] = f2bs(hreg[r]);
    if (tid < 256){
      ((uint4*)xbuf[cur])[srow*17 + scol] = xpre;
      int tl = (t + 3 < 96) ? t + 3 : 95;
      xpre = h1u4[((bn0 + srow)*96 + tl)*16 + scol];
    }
    __syncthreads();
  }
  // ---- epilogue: bwd single-step (zero state) + Wtp projection ----
  for (int idx = tid; idx < 2048; idx += 512){
    int r = idx >> 7, d = idx & 127;
    ycat[r*264 + d] = hbuf[0][r*136 + d];
  }
  {
    bf8v ax[4];
    #pragma unroll
    for (int kt = 0; kt < 4; ++kt)
      ax[kt] = *reinterpret_cast<const bf8v*>(xbuf[0] + l15*136 + kt*32 + quad*8);
    int col = w*16 + l15;
    f4v gi = {0.f,0.f,0.f,0.f}, gg = {0.f,0.f,0.f,0.f}, go = {0.f,0.f,0.f,0.f};
    #pragma unroll
    for (int kt = 0; kt < 4; ++kt){
      gi = mfma16(ax[kt], *reinterpret_cast<const bf8v*>(Wihb + col*128 + kt*32 + quad*8), gi);
      gg = mfma16(ax[kt], *reinterpret_cast<const bf8v*>(Wihb + (256 + col)*128 + kt*32 + quad*8), gg);
      go = mfma16(ax[kt], *reinterpret_cast<const bf8v*>(Wihb + (384 + col)*128 + kt*32 + quad*8), go);
    }
    float bi = b2f(bihb[col])       + b2f(bhhb[col]);
    float bg = b2f(bihb[256 + col]) + b2f(bhhb[256 + col]);
    float bo = b2f(bihb[384 + col]) + b2f(bhhb[384 + col]);
    #pragma unroll
    for (int r = 0; r < 4; ++r){
      float c  = sigf(gi[r] + bi) * tanhfast(gg[r] + bg);
      float yb = sigf(go[r] + bo) * tanhfast(c);
      ycat[(quad*4 + r)*264 + 128 + col] = f2bs(yb);
    }
  }
  __syncthreads();
  {
    int col = w*16 + l15;
    f4v z = {0.f,0.f,0.f,0.f};
    #pragma unroll
    for (int kt = 0; kt < 8; ++kt){
      bf8v a = *reinterpret_cast<const bf8v*>(ycat + l15*264 + kt*32 + quad*8);
      bf8v bb = *reinterpret_cast<const bf8v*>(Wtp + col*256 + kt*32 + quad*8);
      z = mfma16(a, bb, z);
    }
    float bt = b2f(btp[col]);
    #pragma unroll
    for (int r = 0; r < 4; ++r){
      int rowg = bn0 + quad*4 + r;
      float v = z[r] + bt;
      int bb_ = rowg/100, nn = rowg - bb_*100;
      ht_pad[(bb_*112 + nn)*128 + col] = f2b(v);
      int oi = 206400 + rowg*128 + col;
      if (flag[0]) outb[oi] = f2b(v); else outf[oi] = v;
    }
  }
}

// ---------------------------------------------------------------------------
// K6: spatial part A (hyperedge attention + node LN). grid = 16, block = 512.
// ---------------------------------------------------------------------------
__global__ __launch_bounds__(512,1) void k_spat1(
    const bf16* __restrict__ ht_pad, const bf16* __restrict__ Hinc,
    const bf16* __restrict__ Wn, const bf16* __restrict__ bn_,
    const bf16* __restrict__ We, const bf16* __restrict__ be,
    const bf16* __restrict__ Wa, const bf16* __restrict__ ba,
    const bf16* __restrict__ gg_, const bf16* __restrict__ bg_,
    bf16* __restrict__ hb2g){
  int b = blockIdx.x, tid = threadIdx.x;
  int w = tid >> 6, lane = tid & 63, l15 = lane & 15, quad = lane >> 4;
  __shared__ __align__(16) short htb[112*136];
  __shared__ __align__(16) short mtile[16*136];
  __shared__ float HincS[1600];
  __shared__ float wts[1600];
  __shared__ float eeS[16*128];
  __shared__ float scE[16], degS[16], part[128];

  {
    const uint4* src = (const uint4*)(ht_pad + b*14336);
    uint4* dst = (uint4*)htb;
    for (int u = tid; u < 1792; u += 512){      // FIXED: 112 rows x 16 uint4
      int r = u >> 4, c = u & 15;
      dst[r*17 + c] = src[u];
    }
  }
  for (int i = tid; i < 1600; i += 512) HincS[i] = b2f(Hinc[i]);
  __syncthreads();
  if (tid < 16){
    float s = 0.0f;
    for (int n = 0; n < 100; ++n) s += HincS[n*16 + tid];
    degS[tid] = s;
  }
  __syncthreads();
  // segment sums -> mean tile (16 edges x 128 dims, bf16)
  for (int it = 0; it < 4; ++it){
    int idx = tid + it*512;
    int e = idx >> 7, d = idx & 127;
    float s = 0.0f;
    for (int n = 0; n < 100; ++n)
      s += HincS[n*16 + e] * s2f(htb[n*136 + d]);
    mtile[e*136 + d] = f2bs(s * rcpf_(degS[e] + 1e-8f));
  }
  __syncthreads();
  // epn = mean@Wn^T + bn*ratio
  {
    bf8v a[4];
    #pragma unroll
    for (int kt = 0; kt < 4; ++kt)
      a[kt] = *reinterpret_cast<const bf8v*>(mtile + l15*136 + kt*32 + quad*8);
    int col = w*16 + l15;
    f4v z = {0.f,0.f,0.f,0.f};
    #pragma unroll
    for (int kt = 0; kt < 4; ++kt)
      z = mfma16(a[kt], *reinterpret_cast<const bf8v*>(Wn + col*128 + kt*32 + quad*8), z);
    float bnv = b2f(bn_[col]);
    __syncthreads();
    #pragma unroll
    for (int r = 0; r < 4; ++r){
      int e = quad*4 + r;
      float ratio = degS[e] * rcpf_(degS[e] + 1e-8f);
      mtile[e*136 + col] = f2bs(z[r] + bnv*ratio);
    }
  }
  __syncthreads();
  // ee = epn@We^T + be -> eeS (f32)
  {
    bf8v a[4];
    #pragma unroll
    for (int kt = 0; kt < 4; ++kt)
      a[kt] = *reinterpret_cast<const bf8v*>(mtile + l15*136 + kt*32 + quad*8);
    int col = w*16 + l15;
    f4v z = {0.f,0.f,0.f,0.f};
    #pragma unroll
    for (int kt = 0; kt < 4; ++kt)
      z = mfma16(a[kt], *reinterpret_cast<const bf8v*>(We + col*128 + kt*32 + quad*8), z);
    float bev = b2f(be[col]);
    #pragma unroll
    for (int r = 0; r < 4; ++r)
      eeS[(quad*4 + r)*128 + col] = z[r] + bev;
  }
  __syncthreads();
  if (tid < 128){
    int e = tid >> 3, j = tid & 7;
    float s = 0.0f;
    for (int d = j*16; d < j*16 + 16; ++d)
      s += eeS[e*128 + d] * b2f(Wa[d]);
    part[tid] = s;
  }
  __syncthreads();
  if (tid < 16){
    float s = b2f(ba[0]);
    for (int j = 0; j < 8; ++j) s += part[tid*8 + j];
    scE[tid] = s;
  }
  __syncthreads();
  if (tid < 100){
    float sc[16], mx = -1e30f;
    for (int e = 0; e < 16; ++e){
      sc[e] = (HincS[tid*16 + e] > 0.0f) ? scE[e] : -1e30f;
      mx = fmaxf(mx, sc[e]);
    }
    float sum = 0.0f, tmp[16];
    for (int e = 0; e < 16; ++e){
      tmp[e] = (sc[e] > -1e29f) ? __expf(sc[e] - mx) : 0.0f;
      sum += tmp[e];
    }
    float inv = (sum > 0.0f) ? rcpf_(sum) : 0.0f;
    for (int e = 0; e < 16; ++e) wts[tid*16 + e] = tmp[e]*inv;
  }
  __syncthreads();
  // node: s = ht + sum_e w*ee ; LN -> hb2g   (one wave per node)
  for (int it = 0; it < 13; ++it){
    int n = it*8 + w;
    if (n < 100){
      int d0 = lane*2;
      float s0 = s2f(htb[n*136 + d0]);
      float s1 = s2f(htb[n*136 + d0 + 1]);
      for (int e = 0; e < 16; ++e){
        float wv = wts[n*16 + e];
        s0 += wv * eeS[e*128 + d0];
        s1 += wv * eeS[e*128 + d0 + 1];
      }
      float sum = s0 + s1, sq = s0*s0 + s1*s1;
      #pragma unroll
      for (int mask = 1; mask < 64; mask <<= 1){
        sum += __shfl_xor(sum, mask);
        sq  += __shfl_xor(sq, mask);
      }
      float mean = sum*(1.0f/128.0f);
      float var = fmaxf(sq*(1.0f/128.0f) - mean*mean, 0.0f);
      float rs = rsqrtf(var + 1e-5f);
      float y0 = (s0 - mean)*rs*b2f(gg_[d0])     + b2f(bg_[d0]);
      float y1 = (s1 - mean)*rs*b2f(gg_[d0 + 1]) + b2f(bg_[d0 + 1]);
      hb2g[b*14336 + n*128 + d0]     = f2b(y0);
      hb2g[b*14336 + n*128 + d0 + 1] = f2b(y1);
    }
  }
}

// ---------------------------------------------------------------------------
// K7: spatial part B (GCN + fusion + head). grid = 16, block = 512.
// ---------------------------------------------------------------------------
__global__ __launch_bounds__(512,1) void k_spat2(
    const bf16* __restrict__ hb2g, const bf16* __restrict__ Anp,
    const bf16* __restrict__ Wg, const bf16* __restrict__ bgc,
    const bf16* __restrict__ Remb, const int* __restrict__ mem,
    const bf16* __restrict__ ht_pad,
    const bf16* __restrict__ Wf, const bf16* __restrict__ bf_,
    const bf16* __restrict__ gf, const bf16* __restrict__ b_f,
    const bf16* __restrict__ W1, const bf16* __restrict__ b1,
    const bf16* __restrict__ W2, const bf16* __restrict__ b2,
    const int* __restrict__ flag, bf16* __restrict__ outb,
    float* __restrict__ outf){
  int b = blockIdx.x, tid = threadIdx.x;
  int w = tid >> 6, lane = tid & 63, l15 = lane & 15, quad = lane >> 4;
  __shared__ __align__(16) short regA[128*136];   // QT -> z tile
  __shared__ __align__(16) short regB[112*136];   // hsp tile -> z2 tile

  for (int i = tid; i < 128*136; i += 512) regA[i] = 0;
  __syncthreads();
  // MFMA1: Q = hb2@Wg^T -> QT (transposed write)
  {
    int c0 = w*16;
    bf8v bw[4];
    #pragma unroll
    for (int kt = 0; kt < 4; ++kt)
      bw[kt] = *reinterpret_cast<const bf8v*>(Wg + (c0 + l15)*128 + kt*32 + quad*8);
    for (int m = 0; m < 7; ++m){
      f4v z = {0.f,0.f,0.f,0.f};
      #pragma unroll
      for (int kt = 0; kt < 4; ++kt){
        bf8v a = *reinterpret_cast<const bf8v*>(hb2g + b*14336 + (m*16 + l15)*128 + kt*32 + quad*8);
        z = mfma16(a, bw[kt], z);
      }
      s4v vs;
      #pragma unroll
      for (int r = 0; r < 4; ++r) vs[r] = f2bs(z[r]);
      *reinterpret_cast<s4v*>(regA + (c0 + l15)*136 + m*16 + quad*4) = vs;
    }
  }
  __syncthreads();
  // MFMA2: hg = relu(A@Q + bg); hsp = hb2 + hg + Remb -> regB + out1
  {
    int c0 = w*16;
    for (int m = 0; m < 7; ++m){
      f4v z = {0.f,0.f,0.f,0.f};
      #pragma unroll
      for (int kt = 0; kt < 4; ++kt){
        bf8v a  = *reinterpret_cast<const bf8v*>(Anp + (m*16 + l15)*128 + kt*32 + quad*8);
        bf8v bb = *reinterpret_cast<const bf8v*>(regA + (c0 + l15)*136 + kt*32 + quad*8);
        z = mfma16(a, bb, z);
      }
      #pragma unroll
      for (int r = 0; r < 4; ++r){
        int row = m*16 + quad*4 + r, col = c0 + l15;
        if (row < 100){
          float v = fmaxf(z[r] + b2f(bgc[col]), 0.0f);
          float o = b2f(hb2g[b*14336 + row*128 + col]) + v
                  + b2f(Remb[mem[row]*128 + col]);
          int oi = 1600 + (b*100 + row)*128 + col;
          if (flag[0]) outb[oi] = f2b(o); else outf[oi] = o;
          regB[row*136 + col] = f2bs(o);
        } else {
          regB[row*136 + col] = 0;
        }
      }
    }
  }
  __syncthreads();
  // MFMA3: z = relu(LN([ht,hsp]@Wf^T + bf)) -> regA (QT dead)
  if (w < 7){
    int m = w;
    f4v acc[8];
    for (int n = 0; n < 8; ++n){
      f4v z = {0.f,0.f,0.f,0.f};
      #pragma unroll
      for (int kt = 0; kt < 4; ++kt){
        bf8v a  = *reinterpret_cast<const bf8v*>(ht_pad + b*14336 + (m*16 + l15)*128 + kt*32 + quad*8);
        bf8v bb = *reinterpret_cast<const bf8v*>(Wf + (n*16 + l15)*256 + kt*32 + quad*8);
        z = mfma16(a, bb, z);
      }
      #pragma unroll
      for (int kt = 0; kt < 4; ++kt){
        bf8v a  = *reinterpret_cast<const bf8v*>(regB + (m*16 + l15)*136 + kt*32 + quad*8);
        bf8v bb = *reinterpret_cast<const bf8v*>(Wf + (n*16 + l15)*256 + 128 + kt*32 + quad*8);
        z = mfma16(a, bb, z);
      }
      acc[n] = z;
    }
    float sm[4], sq[4];
    #pragma unroll
    for (int r = 0; r < 4; ++r){ sm[r] = 0.f; sq[r] = 0.f; }
    #pragma unroll
    for (int n = 0; n < 8; ++n){
      int col = n*16 + l15;
      float bv = b2f(bf_[col]);
      #pragma unroll
      for (int r = 0; r < 4; ++r){
        float v = acc[n][r] + bv;
        acc[n][r] = v;
        sm[r] += v; sq[r] += v*v;
      }
    }
    #pragma unroll
    for (int mask = 1; mask < 16; mask <<= 1)
      #pragma unroll
      for (int r = 0; r < 4; ++r){
        sm[r] += __shfl_xor(sm[r], mask);
        sq[r] += __shfl_xor(sq[r], mask);
      }
    #pragma unroll
    for (int r = 0; r < 4; ++r){
      float mean = sm[r]*(1.0f/128.0f);
      float var = fmaxf(sq[r]*(1.0f/128.0f) - mean*mean, 0.0f);
      float rs = rsqrtf(var + 1e-5f);
      #pragma unroll
      for (int n = 0; n < 8; ++n){
        int col = n*16 + l15;
        float y = fmaxf((acc[n][r] - mean)*rs*b2f(gf[col]) + b2f(b_f[col]), 0.0f);
        regA[(m*16 + quad*4 + r)*136 + col] = f2bs(y);
      }
    }
  }
  __syncthreads();
  // MFMA4: zz = relu(z@W1^T + b1) -> regB as z2 (stride 72)
  if (w < 7){
    int m = w;
    for (int n = 0; n < 4; ++n){
      f4v z = {0.f,0.f,0.f,0.f};
      #pragma unroll
      for (int kt = 0; kt < 4; ++kt){
        bf8v a  = *reinterpret_cast<const bf8v*>(regA + (m*16 + l15)*136 + kt*32 + quad*8);
        bf8v bb = *reinterpret_cast<const bf8v*>(W1 + (n*16 + l15)*128 + kt*32 + quad*8);
        z = mfma16(a, bb, z);
      }
      #pragma unroll
      for (int r = 0; r < 4; ++r){
        int row = m*16 + quad*4 + r, col = n*16 + l15;
        regB[row*72 + col] = f2bs(fmaxf(z[r] + b2f(b1[col]), 0.0f));
      }
    }
  }
  __syncthreads();
  if (tid < 100){
    float s = b2f(b2[0]);
    for (int d = 0; d < 64; ++d)
      s += s2f(regB[tid*72 + d]) * b2f(W2[d]);
    int oi = b*100 + tid;
    if (flag[0]) outb[oi] = f2b(s); else outf[oi] = s;
  }
}

// ---------------------------------------------------------------------------

extern "C" void kernel_launch(void* const* d_in, const int* in_sizes, int n_in,
                              void* d_out, int out_size, void* d_ws, size_t ws_size,
                              hipStream_t stream){
  (void)n_in; (void)out_size; (void)ws_size;
  const int* mem = (const int*)d_in[3];

  CArgs ca;
  int coff[43];
  int nf = 0;
  long long off = 0;
  for (int i = 0; i < 43; ++i){
    if (i == 3){ coff[i] = -1; continue; }
    coff[i] = (int)off;
    ca.src[nf] = d_in[i];
    ca.n[nf]   = in_sizes[i];
    ca.off[nf] = (int)off;
    ++nf;
    off += (long long)((in_sizes[i] + 7) & ~7);
  }
  char* ws = (char*)d_ws;
  bf16* canon = (bf16*)ws;
  long long canonBytes = ((off*2 + 255)/256)*256;
  int* flag = (int*)(ws + canonBytes);
  long long base = canonBytes + 256;

  #define C(i) (canon + coff[i])
  const bf16* A_norm = C(1);
  const bf16* Hinc   = C(2);
  const bf16* Wp  = C(4);  const bf16* bp  = C(5);
  const bf16* g_p = C(6);  const bf16* b_p = C(7);
  const bf16* Wqkv= C(8);  const bf16* bqkv= C(9);
  const bf16* Wo  = C(10); const bf16* bo  = C(11);
  const bf16* g_a = C(12); const bf16* b_a = C(13);
  const bf16* Wih_f = C(14); const bf16* Whh_f = C(15);
  const bf16* bih_f = C(16); const bf16* bhh_f = C(17);
  const bf16* Wih_b = C(18);
  const bf16* bih_b = C(20); const bf16* bhh_b = C(21);
  const bf16* Wtp = C(22); const bf16* btp = C(23);
  const bf16* Wn  = C(24); const bf16* bn_ = C(25);
  const bf16* We  = C(26); const bf16* be  = C(27);
  const bf16* Wa  = C(28); const bf16* ba  = C(29);
  const bf16* g_g = C(30); const bf16* b_g = C(31);
  const bf16* Remb= C(32);
  const bf16* Wg  = C(33); const bf16* bg  = C(34);
  const bf16* Wf  = C(35); const bf16* bff = C(36);
  const bf16* g_f = C(37); const bf16* b_f = C(38);
  const bf16* W1  = C(39); const bf16* b1  = C(40);
  const bf16* W2  = C(41); const bf16* b2  = C(42);
  const bf16* xc  = C(0);
  #undef C

  bf16*  outb = (bf16*)d_out;
  float* outf = (float*)d_out;
  bf16*  h1     = (bf16*)(ws + base);
  bf16*  h0     = (bf16*)(ws + base + 39321600LL);
  bf16*  attno  = (bf16*)(ws + base + 78643200LL);
  bf16*  Wpp    = (bf16*)(ws + base + 196608000LL);   // 8192 B
  bf16*  An_pad = (bf16*)(ws + base + 196616192LL);   // 28672 B
  bf16*  ht_pad = (bf16*)(ws + base + 196644864LL);   // 458752 B
  bf16*  hb2g   = (bf16*)(ws + base + 197103616LL);   // 458752 B

  k_detect<<<1, 256, 0, stream>>>((const unsigned int*)d_in[0], flag);
  k_canon <<<dim3(64, nf), 256, 0, stream>>>(ca, flag, canon);
  k_prep  <<<1024, 256, 0, stream>>>(Wp, A_norm, Wpp, An_pad, ht_pad, hb2g);
  k_inproj<<<1200, 256, 0, stream>>>(xc, Wpp, bp, g_p, b_p, h0);
  k_attn  <<<1600, 256, 0, stream>>>(h0, Wqkv, bqkv, attno);
  k_oproj <<<1200, 256, 0, stream>>>(attno, h0, Wo, bo, g_a, b_a, h1);
  k_lstm  <<<100,  512, 0, stream>>>(Whh_f, Wih_f, bih_f, bhh_f, h1,
                                     Wih_b, bih_b, bhh_b, Wtp, btp, ht_pad,
                                     flag, outb, outf);
  k_spat1 <<<16,   512, 0, stream>>>(ht_pad, Hinc, Wn, bn_, We, be, Wa, ba,
                                     g_g, b_g, hb2g);
  k_spat2 <<<16,   512, 0, stream>>>(hb2g, An_pad, Wg, bg, Remb, mem, ht_pad,
                                     Wf, bff, g_f, b_f, W1, b1, W2, b2,
                                     flag, outb, outf);
}